// Round 1
// baseline (2432.666 us; speedup 1.0000x reference)
//
#include <hip/hip_runtime.h>
#include <math.h>

// ---------------- problem constants ----------------
#define PATCH 14
#define HID   16
#define NCLS  20
#define GX    200
#define GY    200
#define GZ    16
#define NB    2          // batch
#define NCAM  6
#define PH    37
#define PW    37
#define NP    (PH*PW)    // 1369
#define TD    768
#define IMH   518
#define IMW   518
#define PL    ((size_t)GX*GY*GZ)   // 640000 per-channel plane
#define EPSF  1e-5f

// ---------------- workspace layout (floats) ----------------
#define OFF_VOL   ((size_t)0)                       // 2*16*640000 = 20,480,000
#define OFF_CNT   ((size_t)20480000)                // 2*640000   =  1,280,000
#define OFF_ST1   ((size_t)21760000)                // 64*32      =      2,048
#define OFF_ST2   ((size_t)21762048)                //                   2,048
#define ZERO_F    ((size_t)21764096)                // zeroed every call up to here
#define OFF_MATS  ((size_t)21764096)                // 12*12      =        144
#define OFF_W1T   ((size_t)21764240)                // 16*768     =     12,288
#define OFF_WT1   ((size_t)21776528)                // 17*27*16   =      7,344
#define OFF_WT2   ((size_t)21783872)                // 16*27*16   =      6,912
#define OFF_BN1   ((size_t)21790784)                // 32
#define OFF_BN2   ((size_t)21790816)                // 32
#define WS_FLOATS ((size_t)21790848)

__device__ __forceinline__ float gelu_exact(float x) {
    return 0.5f * x * (1.0f + erff(x * 0.70710678118654752f));
}

// ---------------- 3x3 / 4x4 inverse in double ----------------
__device__ void inv3d(const double* m, double* o) {
    double a=m[0],b=m[1],c=m[2],d=m[3],e=m[4],f=m[5],g=m[6],h=m[7],i=m[8];
    double A=e*i-f*h, B=-(d*i-f*g), C=d*h-e*g;
    double det=a*A+b*B+c*C, id=1.0/det;
    o[0]=A*id;            o[1]=-(b*i-c*h)*id;   o[2]=(b*f-c*e)*id;
    o[3]=B*id;            o[4]=(a*i-c*g)*id;    o[5]=-(a*f-c*d)*id;
    o[6]=C*id;            o[7]=-(a*h-b*g)*id;   o[8]=(a*e-b*d)*id;
}

__device__ void inv4d(const double* m, double* o) {
    double i0  =  m[5]*m[10]*m[15]-m[5]*m[11]*m[14]-m[9]*m[6]*m[15]+m[9]*m[7]*m[14]+m[13]*m[6]*m[11]-m[13]*m[7]*m[10];
    double i4  = -m[4]*m[10]*m[15]+m[4]*m[11]*m[14]+m[8]*m[6]*m[15]-m[8]*m[7]*m[14]-m[12]*m[6]*m[11]+m[12]*m[7]*m[10];
    double i8  =  m[4]*m[9]*m[15]-m[4]*m[11]*m[13]-m[8]*m[5]*m[15]+m[8]*m[7]*m[13]+m[12]*m[5]*m[11]-m[12]*m[7]*m[9];
    double i12 = -m[4]*m[9]*m[14]+m[4]*m[10]*m[13]+m[8]*m[5]*m[14]-m[8]*m[6]*m[13]-m[12]*m[5]*m[10]+m[12]*m[6]*m[9];
    double i1  = -m[1]*m[10]*m[15]+m[1]*m[11]*m[14]+m[9]*m[2]*m[15]-m[9]*m[3]*m[14]-m[13]*m[2]*m[11]+m[13]*m[3]*m[10];
    double i5  =  m[0]*m[10]*m[15]-m[0]*m[11]*m[14]-m[8]*m[2]*m[15]+m[8]*m[3]*m[14]+m[12]*m[2]*m[11]-m[12]*m[3]*m[10];
    double i9  = -m[0]*m[9]*m[15]+m[0]*m[11]*m[13]+m[8]*m[1]*m[15]-m[8]*m[3]*m[13]-m[12]*m[1]*m[11]+m[12]*m[3]*m[9];
    double i13 =  m[0]*m[9]*m[14]-m[0]*m[10]*m[13]-m[8]*m[1]*m[14]+m[8]*m[2]*m[13]+m[12]*m[1]*m[10]-m[12]*m[2]*m[9];
    double i2  =  m[1]*m[6]*m[15]-m[1]*m[7]*m[14]-m[5]*m[2]*m[15]+m[5]*m[3]*m[14]+m[13]*m[2]*m[7]-m[13]*m[3]*m[6];
    double i6  = -m[0]*m[6]*m[15]+m[0]*m[7]*m[14]+m[4]*m[2]*m[15]-m[4]*m[3]*m[14]-m[12]*m[2]*m[7]+m[12]*m[3]*m[6];
    double i10 =  m[0]*m[5]*m[15]-m[0]*m[7]*m[13]-m[4]*m[1]*m[15]+m[4]*m[3]*m[13]+m[12]*m[1]*m[7]-m[12]*m[3]*m[5];
    double i14 = -m[0]*m[5]*m[14]+m[0]*m[6]*m[13]+m[4]*m[1]*m[14]-m[4]*m[2]*m[13]-m[12]*m[1]*m[6]+m[12]*m[2]*m[5];
    double i3  = -m[1]*m[6]*m[11]+m[1]*m[7]*m[10]+m[5]*m[2]*m[11]-m[5]*m[3]*m[10]-m[9]*m[2]*m[7]+m[9]*m[3]*m[6];
    double i7  =  m[0]*m[6]*m[11]-m[0]*m[7]*m[10]-m[4]*m[2]*m[11]+m[4]*m[3]*m[10]+m[8]*m[2]*m[7]-m[8]*m[3]*m[6];
    double i11 = -m[0]*m[5]*m[11]+m[0]*m[7]*m[9]+m[4]*m[1]*m[11]-m[4]*m[3]*m[9]-m[8]*m[1]*m[7]+m[8]*m[3]*m[5];
    double i15 =  m[0]*m[5]*m[10]-m[0]*m[6]*m[9]-m[4]*m[1]*m[10]+m[4]*m[2]*m[9]+m[8]*m[1]*m[6]-m[8]*m[2]*m[5];
    double det = m[0]*i0+m[1]*i4+m[2]*i8+m[3]*i12;
    double id = 1.0/det;
    o[0]=i0*id; o[1]=i1*id; o[2]=i2*id; o[3]=i3*id;
    o[4]=i4*id; o[5]=i5*id; o[6]=i6*id; o[7]=i7*id;
    o[8]=i8*id; o[9]=i9*id; o[10]=i10*id; o[11]=i11*id;
    o[12]=i12*id; o[13]=i13*id; o[14]=i14*id; o[15]=i15*id;
}

// ---------------- precompute: per-cam matrices + weight transposes ----------------
__global__ void occ_prep_kernel(const float* __restrict__ intr, const float* __restrict__ c2w,
                                const float* __restrict__ l2w, const float* __restrict__ w1,
                                const float* __restrict__ cw1, const float* __restrict__ cw2,
                                float* __restrict__ mats, float* __restrict__ w1T,
                                float* __restrict__ wT1, float* __restrict__ wT2)
{
    int t = threadIdx.x;
    if (t < NB * NCAM) {
        int b = t / NCAM;
        double K[9], Ki[9], L[16], Li[16], C[16], M[16], A[9];
        #pragma unroll
        for (int i = 0; i < 9; ++i) K[i] = (double)intr[t * 9 + i];
        inv3d(K, Ki);
        #pragma unroll
        for (int i = 0; i < 16; ++i) L[i] = (double)l2w[b * 16 + i];
        inv4d(L, Li);
        #pragma unroll
        for (int i = 0; i < 16; ++i) C[i] = (double)c2w[t * 16 + i];
        #pragma unroll
        for (int r = 0; r < 4; ++r)
            #pragma unroll
            for (int c = 0; c < 4; ++c) {
                double s = 0.0;
                #pragma unroll
                for (int k = 0; k < 4; ++k) s += Li[r * 4 + k] * C[k * 4 + c];
                M[r * 4 + c] = s;
            }
        #pragma unroll
        for (int r = 0; r < 3; ++r)
            #pragma unroll
            for (int c = 0; c < 3; ++c) {
                double s = 0.0;
                #pragma unroll
                for (int k = 0; k < 3; ++k) s += M[r * 4 + k] * Ki[k * 3 + c];
                A[r * 3 + c] = s;
            }
        #pragma unroll
        for (int i = 0; i < 9; ++i) mats[t * 12 + i] = (float)A[i];
        mats[t * 12 + 9]  = (float)M[3];
        mats[t * 12 + 10] = (float)M[7];
        mats[t * 12 + 11] = (float)M[11];
    }
    // w1 (768,16) -> w1T (16,768)
    for (int i = t; i < TD * HID; i += 256) {
        int d = i >> 4, j = i & 15;
        w1T[j * TD + d] = w1[i];
    }
    // conv1_w [o][ci][k] (16,17,27) -> wT1 [(ci*27+k)*16+o]
    for (int i = t; i < 16 * 17 * 27; i += 256) {
        int o = i / (17 * 27), r = i % (17 * 27), ci = r / 27, k = r % 27;
        wT1[(ci * 27 + k) * 16 + o] = cw1[i];
    }
    // conv2_w (16,16,27) -> wT2
    for (int i = t; i < 16 * 16 * 27; i += 256) {
        int o = i / (16 * 27), r = i % (16 * 27), ci = r / 27, k = r % 27;
        wT2[(ci * 27 + k) * 16 + o] = cw2[i];
    }
}

// ---------------- token: depth pool + LN + MLP + geometry + scatter ----------------
__global__ __launch_bounds__(256) void occ_token_kernel(
    const float* __restrict__ tokens, const float* __restrict__ depth,
    const float* __restrict__ ln_g, const float* __restrict__ ln_b,
    const float* __restrict__ w1T, const float* __restrict__ b1,
    const float* __restrict__ w2, const float* __restrict__ b2,
    const float* __restrict__ mats, float* __restrict__ vol, float* __restrict__ cnt)
{
    int blk = blockIdx.x;            // b*NCAM*NP + c*NP + p
    int p = blk % NP;
    int bc = blk / NP;
    int b = bc / NCAM;
    int gy = p / PW, gx = p % PW;
    int t = threadIdx.x;

    __shared__ float red[256];
    __shared__ float red2[256];
    __shared__ float xn[TD];
    __shared__ float h1[HID];
    __shared__ float s_dm;

    // --- depth patch mean (196 pixels) ---
    float dv = 0.f;
    if (t < PATCH * PATCH) {
        int py = t / PATCH, px = t % PATCH;
        int row = gy * PATCH + py, col = gx * PATCH + px;
        dv = depth[((size_t)bc * IMH + row) * IMW + col];
    }
    red[t] = dv;
    __syncthreads();
    #pragma unroll
    for (int off = 128; off > 0; off >>= 1) {
        if (t < off) red[t] += red[t + off];
        __syncthreads();
    }
    if (t == 0) s_dm = red[0] * (1.0f / 196.0f);

    // --- LayerNorm: sums ---
    const float* tok = tokens + ((size_t)bc * NP + p) * TD;
    float x0 = tok[t], x1 = tok[t + 256], x2 = tok[t + 512];
    red[t]  = x0 + x1 + x2;
    red2[t] = x0 * x0 + x1 * x1 + x2 * x2;
    __syncthreads();
    #pragma unroll
    for (int off = 128; off > 0; off >>= 1) {
        if (t < off) { red[t] += red[t + off]; red2[t] += red2[t + off]; }
        __syncthreads();
    }
    float mu  = red[0] * (1.0f / (float)TD);
    float var = red2[0] * (1.0f / (float)TD) - mu * mu;
    float rs  = rsqrtf(var + EPSF);
    xn[t]       = (x0 - mu) * rs * ln_g[t]       + ln_b[t];
    xn[t + 256] = (x1 - mu) * rs * ln_g[t + 256] + ln_b[t + 256];
    xn[t + 512] = (x2 - mu) * rs * ln_g[t + 512] + ln_b[t + 512];
    __syncthreads();

    // --- h1 = gelu(xn @ w1 + b1): 16 groups of 16 lanes ---
    int j = t >> 4, sl = t & 15;
    float acc = 0.f;
    #pragma unroll
    for (int i = 0; i < TD / 16; ++i) {
        int d = sl + (i << 4);
        acc = fmaf(xn[d], w1T[j * TD + d], acc);
    }
    acc += __shfl_down(acc, 8, 16);
    acc += __shfl_down(acc, 4, 16);
    acc += __shfl_down(acc, 2, 16);
    acc += __shfl_down(acc, 1, 16);
    if (sl == 0) h1[j] = gelu_exact(acc + b1[j]);
    __syncthreads();

    // --- geometry + h2 + scatter: threads 0..15 (k = out channel) ---
    if (t < HID) {
        const float* M = mats + bc * 12;
        float dmr = s_dm;
        float dm = fmaxf(dmr, 0.f);
        float u = (gx + 0.5f) * (float)PATCH;
        float v = (gy + 0.5f) * (float)PATCH;
        float lx = (M[0] * u + M[1] * v + M[2]) * dm + M[9];
        float ly = (M[3] * u + M[4] * v + M[5]) * dm + M[10];
        float lz = (M[6] * u + M[7] * v + M[8]) * dm + M[11];
        int cx = (int)floorf((lx + 40.0f) / 0.4f);
        int cy = (int)floorf((ly + 40.0f) / 0.4f);
        int cz = (int)floorf((lz + 1.0f) / 0.4f);
        bool valid = (dmr > 0.001f) &&
                     (unsigned)cx < (unsigned)GX &&
                     (unsigned)cy < (unsigned)GY &&
                     (unsigned)cz < (unsigned)GZ;
        float h2 = b2[t];
        #pragma unroll
        for (int jj = 0; jj < HID; ++jj) h2 = fmaf(h1[jj], w2[jj * HID + t], h2);
        if (valid) {
            size_t sp = ((size_t)cx * GY + cy) * GZ + cz;
            atomicAdd(&vol[((size_t)b * HID + t) * PL + sp], h2);
            if (t == 0) atomicAdd(&cnt[(size_t)b * PL + sp], 1.0f);
        }
    }
}

// ---------------- conv3d 3x3x3 (direct, 16 out-ch per thread) ----------------
// MODE 0: input = vol(16ch)+cnt -> dec_in (vol/max(cnt,1), mask); CIN=17
// MODE 1: input = act (16ch) plain; CIN=16
template <int MODE>
__global__ __launch_bounds__(256) void occ_conv_kernel(
    const float* __restrict__ in, const float* __restrict__ cnt,
    const float* __restrict__ wT, const float* __restrict__ bias,
    float* __restrict__ out, float* __restrict__ stats)
{
    int b = blockIdx.y;
    int tile = blockIdx.x;
    int tx = (tile % 50) * 4, ty = (tile / 50) * 4;
    int t = threadIdx.x;
    int z = t & 15;
    int q = t >> 4;
    int x = tx + (q >> 2), y = ty + (q & 3);

    float acc[16];
    #pragma unroll
    for (int o = 0; o < 16; ++o) acc[o] = bias[o];

    const float* inb = in + (size_t)b * 16 * PL;

    int   sp_[27];
    float mul_[27];
    const float* cntb = (MODE == 0) ? (cnt + (size_t)b * PL) : nullptr;

    #pragma unroll
    for (int dx = -1; dx <= 1; ++dx) {
        int xx = x + dx;
        bool vx = (unsigned)xx < (unsigned)GX;
        int xc = min(GX - 1, max(0, xx));
        #pragma unroll
        for (int dy = -1; dy <= 1; ++dy) {
            int yy = y + dy;
            bool vxy = vx && ((unsigned)yy < (unsigned)GY);
            int yc = min(GY - 1, max(0, yy));
            #pragma unroll
            for (int dz = -1; dz <= 1; ++dz) {
                int zz = z + dz;
                bool v = vxy && ((unsigned)zz < (unsigned)GZ);
                int zc = min(GZ - 1, max(0, zz));
                int k = ((dx + 1) * 3 + (dy + 1)) * 3 + (dz + 1);
                int sp = (xc * GY + yc) * GZ + zc;
                sp_[k] = sp;
                if constexpr (MODE == 0) {
                    float cn = v ? cntb[sp] : 0.f;
                    mul_[k] = v ? (1.0f / fmaxf(cn, 1.0f)) : 0.f;
                    float msk = (cn > 0.f) ? 1.f : 0.f;
                    const float* wp = wT + (16 * 27 + k) * 16;   // mask channel ci=16
                    #pragma unroll
                    for (int o = 0; o < 16; ++o) acc[o] = fmaf(msk, wp[o], acc[o]);
                } else {
                    mul_[k] = v ? 1.f : 0.f;
                }
            }
        }
    }

    #pragma unroll 1
    for (int ci = 0; ci < 16; ++ci) {
        const float* cp = inb + (size_t)ci * PL;
        #pragma unroll
        for (int k = 0; k < 27; ++k) {
            float val = cp[sp_[k]] * mul_[k];
            const float* wp = wT + (ci * 27 + k) * 16;
            #pragma unroll
            for (int o = 0; o < 16; ++o) acc[o] = fmaf(val, wp[o], acc[o]);
        }
    }

    // store (layout [b][o][x][y][z])
    size_t ob = ((size_t)x * GY + y) * GZ + z;
    float* outb = out + (size_t)b * 16 * PL;
    #pragma unroll
    for (int o = 0; o < 16; ++o) outb[(size_t)o * PL + ob] = acc[o];

    // fused BN stats: per-channel sum & sumsq, block-reduced, bucketed atomics
    __shared__ float sred[4][32];
    int lane = t & 63, wv = t >> 6;
    #pragma unroll
    for (int o = 0; o < 16; ++o) {
        float s = acc[o], sq = acc[o] * acc[o];
        #pragma unroll
        for (int off = 32; off > 0; off >>= 1) {
            s  += __shfl_xor(s, off);
            sq += __shfl_xor(sq, off);
        }
        if (lane == 0) { sred[wv][o] = s; sred[wv][16 + o] = sq; }
    }
    __syncthreads();
    if (t < 32) {
        float v2 = sred[0][t] + sred[1][t] + sred[2][t] + sred[3][t];
        atomicAdd(&stats[(size_t)(blockIdx.x & 63) * 32 + t], v2);
    }
}

// ---------------- BN finalize: fold into scale/shift ----------------
__global__ void occ_bnfin_kernel(const float* __restrict__ stats, const float* __restrict__ g,
                                 const float* __restrict__ bb, float* __restrict__ bn)
{
    int c = threadIdx.x;
    if (c >= 16) return;
    float s = 0.f, sq = 0.f;
    for (int k = 0; k < 64; ++k) { s += stats[k * 32 + c]; sq += stats[k * 32 + 16 + c]; }
    const float N = (float)(NB * PL);
    float mean = s / N;
    float var = sq / N - mean * mean;
    float scale = g[c] * rsqrtf(var + EPSF);
    bn[c] = scale;
    bn[16 + c] = bb[c] - mean * scale;
}

// ---------------- elementwise BN affine + GELU ----------------
__global__ __launch_bounds__(256) void occ_act_kernel(const float4* __restrict__ in,
                                                      float4* __restrict__ out,
                                                      const float* __restrict__ bn)
{
    size_t i = (size_t)blockIdx.x * 256 + threadIdx.x;     // < 5,120,000 float4s
    int c = (int)((i / (PL / 4)) & 15);
    float sc = bn[c], sh = bn[16 + c];
    float4 v = in[i];
    v.x = gelu_exact(fmaf(v.x, sc, sh));
    v.y = gelu_exact(fmaf(v.y, sc, sh));
    v.z = gelu_exact(fmaf(v.z, sc, sh));
    v.w = gelu_exact(fmaf(v.w, sc, sh));
    out[i] = v;
}

// ---------------- conv3 1x1x1 (16 -> 20) ----------------
__global__ __launch_bounds__(256) void occ_conv3_kernel(const float* __restrict__ act,
                                                        const float* __restrict__ w3,
                                                        const float* __restrict__ b3,
                                                        float* __restrict__ out)
{
    size_t i = (size_t)blockIdx.x * 256 + threadIdx.x;     // < NB*PL
    size_t b = i / PL, sp = i % PL;
    const float* ap = act + b * 16 * PL + sp;
    float v[16];
    #pragma unroll
    for (int ci = 0; ci < 16; ++ci) v[ci] = ap[(size_t)ci * PL];
    float* op = out + b * NCLS * PL + sp;
    #pragma unroll
    for (int cls = 0; cls < NCLS; ++cls) {
        float a = b3[cls];
        #pragma unroll
        for (int ci = 0; ci < 16; ++ci) a = fmaf(v[ci], w3[cls * 16 + ci], a);
        op[(size_t)cls * PL] = a;
    }
}

// ---------------- launch ----------------
extern "C" void kernel_launch(void* const* d_in, const int* in_sizes, int n_in,
                              void* d_out, int out_size, void* d_ws, size_t ws_size,
                              hipStream_t stream)
{
    const float* tokens = (const float*)d_in[0];
    const float* depth  = (const float*)d_in[1];
    const float* intr   = (const float*)d_in[2];
    const float* c2w    = (const float*)d_in[3];
    const float* l2w    = (const float*)d_in[4];
    const float* ln_g   = (const float*)d_in[5];
    const float* ln_b   = (const float*)d_in[6];
    const float* w1     = (const float*)d_in[7];
    const float* b1     = (const float*)d_in[8];
    const float* w2     = (const float*)d_in[9];
    const float* b2     = (const float*)d_in[10];
    const float* cv1w   = (const float*)d_in[11];
    const float* cv1b   = (const float*)d_in[12];
    const float* bn1g   = (const float*)d_in[13];
    const float* bn1b   = (const float*)d_in[14];
    const float* cv2w   = (const float*)d_in[15];
    const float* cv2b   = (const float*)d_in[16];
    const float* bn2g   = (const float*)d_in[17];
    const float* bn2b   = (const float*)d_in[18];
    const float* cv3w   = (const float*)d_in[19];
    const float* cv3b   = (const float*)d_in[20];

    if (ws_size < WS_FLOATS * sizeof(float)) return;   // clean fail if ws too small

    float* ws   = (float*)d_ws;
    float* vol  = ws + OFF_VOL;    // later reused as act1, then act2
    float* cntp = ws + OFF_CNT;
    float* st1  = ws + OFF_ST1;
    float* st2  = ws + OFF_ST2;
    float* mats = ws + OFF_MATS;
    float* w1T  = ws + OFF_W1T;
    float* wT1  = ws + OFF_WT1;
    float* wT2  = ws + OFF_WT2;
    float* bnp1 = ws + OFF_BN1;
    float* bnp2 = ws + OFF_BN2;
    float* outp = (float*)d_out;   // also used as x1_raw / x2_raw scratch

    // zero accumulators (vol, cnt, stats)
    hipMemsetAsync(ws, 0, ZERO_F * sizeof(float), stream);

    occ_prep_kernel<<<1, 256, 0, stream>>>(intr, c2w, l2w, w1, cv1w, cv2w, mats, w1T, wT1, wT2);

    occ_token_kernel<<<NB * NCAM * NP, 256, 0, stream>>>(
        tokens, depth, ln_g, ln_b, w1T, b1, w2, b2, mats, vol, cntp);

    dim3 cgrid(2500, NB);
    // conv1: vol/cnt -> x1_raw (in d_out), stats1
    occ_conv_kernel<0><<<cgrid, 256, 0, stream>>>(vol, cntp, wT1, cv1b, outp, st1);
    occ_bnfin_kernel<<<1, 16, 0, stream>>>(st1, bn1g, bn1b, bnp1);
    // act1 = gelu(bn1(x1_raw)) -> overwrite vol region
    occ_act_kernel<<<20000, 256, 0, stream>>>((const float4*)outp, (float4*)vol, bnp1);
    // conv2: act1 -> x2_raw (in d_out), stats2
    occ_conv_kernel<1><<<cgrid, 256, 0, stream>>>(vol, nullptr, wT2, cv2b, outp, st2);
    occ_bnfin_kernel<<<1, 16, 0, stream>>>(st2, bn2g, bn2b, bnp2);
    // act2 = gelu(bn2(x2_raw)) -> vol region
    occ_act_kernel<<<20000, 256, 0, stream>>>((const float4*)outp, (float4*)vol, bnp2);
    // conv3: act2 -> final output
    occ_conv3_kernel<<<(NB * (int)PL) / 256, 256, 0, stream>>>(vol, cv3w, cv3b, outp);
}

// Round 2
// 517.580 us; speedup vs baseline: 4.7001x; 4.7001x over previous
//
#include <hip/hip_runtime.h>
#include <hip/hip_bf16.h>
#include <math.h>

// ---------------- problem constants ----------------
#define PATCH 14
#define HID   16
#define NCLS  20
#define GX    200
#define GY    200
#define GZ    16
#define NB    2
#define NCAM  6
#define PH    37
#define PW    37
#define NP    (PH*PW)
#define TD    768
#define IMH   518
#define IMW   518
#define PL    ((size_t)GX*GY*GZ)   // 640000 per-channel plane
#define EPSF  1e-5f

// ---------------- workspace layout (float units) ----------------
#define OFF_VOL   ((size_t)0)            // volf [b][sp][16] fp32 = 20,480,000 f
#define OFF_CNT   ((size_t)20480000)     // cnt  [b][sp]          1,280,000 f
#define OFF_ST1   ((size_t)21760000)     // 64*32
#define OFF_ST2   ((size_t)21762048)     // 64*32
#define ZERO_F    ((size_t)21764096)     // zeroed every call up to here
#define OFF_MATS  ((size_t)21764096)     // 144
#define OFF_W1T   ((size_t)21764240)     // 12,288
#define OFF_WB1   ((size_t)21776528)     // 13,824 bf16 = 6,912 f
#define OFF_WB2   ((size_t)21783440)     //  7,168 bf16 = 3,584 f
#define OFF_BN1   ((size_t)21787024)     // 32
#define OFF_BN2   ((size_t)21787056)     // 32
#define WS_FLOATS ((size_t)21787088)

typedef __attribute__((ext_vector_type(8))) short short8;
typedef __attribute__((ext_vector_type(4))) float floatx4;

__device__ __forceinline__ float gelu_exact(float x) {
    return 0.5f * x * (1.0f + erff(x * 0.70710678118654752f));
}
__device__ __forceinline__ unsigned short f2bf(float f) {
    __hip_bfloat16 h = __float2bfloat16(f);
    return __builtin_bit_cast(unsigned short, h);
}
__device__ __forceinline__ float bf2f(short u) {
    unsigned int b = ((unsigned int)(unsigned short)u) << 16;
    return __builtin_bit_cast(float, b);
}
__device__ __forceinline__ short8 zero8() {
    short8 z = {0,0,0,0,0,0,0,0};
    return z;
}

// ---------------- 3x3 / 4x4 inverse in double ----------------
__device__ void inv3d(const double* m, double* o) {
    double a=m[0],b=m[1],c=m[2],d=m[3],e=m[4],f=m[5],g=m[6],h=m[7],i=m[8];
    double A=e*i-f*h, B=-(d*i-f*g), C=d*h-e*g;
    double det=a*A+b*B+c*C, id=1.0/det;
    o[0]=A*id;            o[1]=-(b*i-c*h)*id;   o[2]=(b*f-c*e)*id;
    o[3]=B*id;            o[4]=(a*i-c*g)*id;    o[5]=-(a*f-c*d)*id;
    o[6]=C*id;            o[7]=-(a*h-b*g)*id;   o[8]=(a*e-b*d)*id;
}

__device__ void inv4d(const double* m, double* o) {
    double i0  =  m[5]*m[10]*m[15]-m[5]*m[11]*m[14]-m[9]*m[6]*m[15]+m[9]*m[7]*m[14]+m[13]*m[6]*m[11]-m[13]*m[7]*m[10];
    double i4  = -m[4]*m[10]*m[15]+m[4]*m[11]*m[14]+m[8]*m[6]*m[15]-m[8]*m[7]*m[14]-m[12]*m[6]*m[11]+m[12]*m[7]*m[10];
    double i8  =  m[4]*m[9]*m[15]-m[4]*m[11]*m[13]-m[8]*m[5]*m[15]+m[8]*m[7]*m[13]+m[12]*m[5]*m[11]-m[12]*m[7]*m[9];
    double i12 = -m[4]*m[9]*m[14]+m[4]*m[10]*m[13]+m[8]*m[5]*m[14]-m[8]*m[6]*m[13]-m[12]*m[5]*m[10]+m[12]*m[6]*m[9];
    double i1  = -m[1]*m[10]*m[15]+m[1]*m[11]*m[14]+m[9]*m[2]*m[15]-m[9]*m[3]*m[14]-m[13]*m[2]*m[11]+m[13]*m[3]*m[10];
    double i5  =  m[0]*m[10]*m[15]-m[0]*m[11]*m[14]-m[8]*m[2]*m[15]+m[8]*m[3]*m[14]+m[12]*m[2]*m[11]-m[12]*m[3]*m[10];
    double i9  = -m[0]*m[9]*m[15]+m[0]*m[11]*m[13]+m[8]*m[1]*m[15]-m[8]*m[3]*m[13]-m[12]*m[1]*m[11]+m[12]*m[3]*m[9];
    double i13 =  m[0]*m[9]*m[14]-m[0]*m[10]*m[13]-m[8]*m[1]*m[14]+m[8]*m[2]*m[13]+m[12]*m[1]*m[10]-m[12]*m[2]*m[9];
    double i2  =  m[1]*m[6]*m[15]-m[1]*m[7]*m[14]-m[5]*m[2]*m[15]+m[5]*m[3]*m[14]+m[13]*m[2]*m[7]-m[13]*m[3]*m[6];
    double i6  = -m[0]*m[6]*m[15]+m[0]*m[7]*m[14]+m[4]*m[2]*m[15]-m[4]*m[3]*m[14]-m[12]*m[2]*m[7]+m[12]*m[3]*m[6];
    double i10 =  m[0]*m[5]*m[15]-m[0]*m[7]*m[13]-m[4]*m[1]*m[15]+m[4]*m[3]*m[13]+m[12]*m[1]*m[7]-m[12]*m[3]*m[5];
    double i14 = -m[0]*m[5]*m[14]+m[0]*m[6]*m[13]+m[4]*m[1]*m[14]-m[4]*m[2]*m[13]-m[12]*m[1]*m[6]+m[12]*m[2]*m[5];
    double i3  = -m[1]*m[6]*m[11]+m[1]*m[7]*m[10]+m[5]*m[2]*m[11]-m[5]*m[3]*m[10]-m[9]*m[2]*m[7]+m[9]*m[3]*m[6];
    double i7  =  m[0]*m[6]*m[11]-m[0]*m[7]*m[10]-m[4]*m[2]*m[11]+m[4]*m[3]*m[10]+m[8]*m[2]*m[7]-m[8]*m[3]*m[6];
    double i11 = -m[0]*m[5]*m[11]+m[0]*m[7]*m[9]+m[4]*m[1]*m[11]-m[4]*m[3]*m[9]-m[8]*m[1]*m[7]+m[8]*m[3]*m[5];
    double i15 =  m[0]*m[5]*m[10]-m[0]*m[6]*m[9]-m[4]*m[1]*m[10]+m[4]*m[2]*m[9]+m[8]*m[1]*m[6]-m[8]*m[2]*m[5];
    double det = m[0]*i0+m[1]*i4+m[2]*i8+m[3]*i12;
    double id = 1.0/det;
    o[0]=i0*id; o[1]=i1*id; o[2]=i2*id; o[3]=i3*id;
    o[4]=i4*id; o[5]=i5*id; o[6]=i6*id; o[7]=i7*id;
    o[8]=i8*id; o[9]=i9*id; o[10]=i10*id; o[11]=i11*id;
    o[12]=i12*id; o[13]=i13*id; o[14]=i14*id; o[15]=i15*id;
}

// ---------------- precompute: matrices, w1T, MFMA B-fragment weights ----------------
__global__ void occ_prep_kernel(const float* __restrict__ intr, const float* __restrict__ c2w,
                                const float* __restrict__ l2w, const float* __restrict__ w1,
                                const float* __restrict__ cw1, const float* __restrict__ cw2,
                                float* __restrict__ mats, float* __restrict__ w1T,
                                __hip_bfloat16* __restrict__ wB1, __hip_bfloat16* __restrict__ wB2)
{
    int t = threadIdx.x;
    if (t < NB * NCAM) {
        int b = t / NCAM;
        double K[9], Ki[9], L[16], Li[16], C[16], M[16], A[9];
        #pragma unroll
        for (int i = 0; i < 9; ++i) K[i] = (double)intr[t * 9 + i];
        inv3d(K, Ki);
        #pragma unroll
        for (int i = 0; i < 16; ++i) L[i] = (double)l2w[b * 16 + i];
        inv4d(L, Li);
        #pragma unroll
        for (int i = 0; i < 16; ++i) C[i] = (double)c2w[t * 16 + i];
        #pragma unroll
        for (int r = 0; r < 4; ++r)
            #pragma unroll
            for (int c = 0; c < 4; ++c) {
                double s = 0.0;
                #pragma unroll
                for (int k = 0; k < 4; ++k) s += Li[r * 4 + k] * C[k * 4 + c];
                M[r * 4 + c] = s;
            }
        #pragma unroll
        for (int r = 0; r < 3; ++r)
            #pragma unroll
            for (int c = 0; c < 3; ++c) {
                double s = 0.0;
                #pragma unroll
                for (int k = 0; k < 3; ++k) s += M[r * 4 + k] * Ki[k * 3 + c];
                A[r * 3 + c] = s;
            }
        #pragma unroll
        for (int i = 0; i < 9; ++i) mats[t * 12 + i] = (float)A[i];
        mats[t * 12 + 9]  = (float)M[3];
        mats[t * 12 + 10] = (float)M[7];
        mats[t * 12 + 11] = (float)M[11];
    }
    // w1 (768,16) -> w1T (16,768)
    for (int i = t; i < TD * HID; i += 256) {
        int d = i >> 4, j = i & 15;
        w1T[j * TD + d] = w1[i];
    }
    // conv1 weights -> B fragments: wB1[tap][lane][8], k = 8*(lane>>4)+e, o = lane&15
    for (int i = t; i < 27 * 64 * 8; i += 256) {
        int tap = i >> 9; int r = i & 511; int ln = r >> 3; int e = r & 7;
        int k = ((ln >> 4) << 3) + e;
        int o = ln & 15;
        float val = (k < 17) ? cw1[(o * 17 + k) * 27 + tap] : 0.f;
        wB1[i] = __float2bfloat16(val);
    }
    // conv2 weights -> B fragments: wB2[t2][lane][8]; K pairs two taps:
    // tap = 2*t2 + (kg>>1), ci = 8*(kg&1)+e
    for (int i = t; i < 14 * 64 * 8; i += 256) {
        int t2 = i >> 9; int r = i & 511; int ln = r >> 3; int e = r & 7;
        int kg = ln >> 4;
        int tt = 2 * t2 + (kg >> 1);
        int ci = ((kg & 1) << 3) + e;
        int o = ln & 15;
        float val = (tt < 27) ? cw2[(o * 16 + ci) * 27 + tt] : 0.f;
        wB2[i] = __float2bfloat16(val);
    }
}

// ---------------- token: depth pool + LN + MLP + geometry + scatter ----------------
__global__ __launch_bounds__(256) void occ_token_kernel(
    const float* __restrict__ tokens, const float* __restrict__ depth,
    const float* __restrict__ ln_g, const float* __restrict__ ln_b,
    const float* __restrict__ w1T, const float* __restrict__ b1,
    const float* __restrict__ w2, const float* __restrict__ b2,
    const float* __restrict__ mats, float* __restrict__ vol, float* __restrict__ cnt)
{
    int blk = blockIdx.x;
    int p = blk % NP;
    int bc = blk / NP;
    int b = bc / NCAM;
    int gy = p / PW, gx = p % PW;
    int t = threadIdx.x;

    __shared__ float red[256];
    __shared__ float red2[256];
    __shared__ float xn[TD];
    __shared__ float h1[HID];
    __shared__ float s_dm;

    float dv = 0.f;
    if (t < PATCH * PATCH) {
        int py = t / PATCH, px = t % PATCH;
        int row = gy * PATCH + py, col = gx * PATCH + px;
        dv = depth[((size_t)bc * IMH + row) * IMW + col];
    }
    red[t] = dv;
    __syncthreads();
    #pragma unroll
    for (int off = 128; off > 0; off >>= 1) {
        if (t < off) red[t] += red[t + off];
        __syncthreads();
    }
    if (t == 0) s_dm = red[0] * (1.0f / 196.0f);

    const float* tok = tokens + ((size_t)bc * NP + p) * TD;
    float x0 = tok[t], x1 = tok[t + 256], x2 = tok[t + 512];
    red[t]  = x0 + x1 + x2;
    red2[t] = x0 * x0 + x1 * x1 + x2 * x2;
    __syncthreads();
    #pragma unroll
    for (int off = 128; off > 0; off >>= 1) {
        if (t < off) { red[t] += red[t + off]; red2[t] += red2[t + off]; }
        __syncthreads();
    }
    float mu  = red[0] * (1.0f / (float)TD);
    float var = red2[0] * (1.0f / (float)TD) - mu * mu;
    float rs  = rsqrtf(var + EPSF);
    xn[t]       = (x0 - mu) * rs * ln_g[t]       + ln_b[t];
    xn[t + 256] = (x1 - mu) * rs * ln_g[t + 256] + ln_b[t + 256];
    xn[t + 512] = (x2 - mu) * rs * ln_g[t + 512] + ln_b[t + 512];
    __syncthreads();

    int j = t >> 4, sl = t & 15;
    float acc = 0.f;
    #pragma unroll
    for (int i = 0; i < TD / 16; ++i) {
        int d = sl + (i << 4);
        acc = fmaf(xn[d], w1T[j * TD + d], acc);
    }
    acc += __shfl_down(acc, 8, 16);
    acc += __shfl_down(acc, 4, 16);
    acc += __shfl_down(acc, 2, 16);
    acc += __shfl_down(acc, 1, 16);
    if (sl == 0) h1[j] = gelu_exact(acc + b1[j]);
    __syncthreads();

    if (t < HID) {
        const float* M = mats + bc * 12;
        float dmr = s_dm;
        float dm = fmaxf(dmr, 0.f);
        float u = (gx + 0.5f) * (float)PATCH;
        float v = (gy + 0.5f) * (float)PATCH;
        float lx = (M[0] * u + M[1] * v + M[2]) * dm + M[9];
        float ly = (M[3] * u + M[4] * v + M[5]) * dm + M[10];
        float lz = (M[6] * u + M[7] * v + M[8]) * dm + M[11];
        int cx = (int)floorf((lx + 40.0f) / 0.4f);
        int cy = (int)floorf((ly + 40.0f) / 0.4f);
        int cz = (int)floorf((lz + 1.0f) / 0.4f);
        bool valid = (dmr > 0.001f) &&
                     (unsigned)cx < (unsigned)GX &&
                     (unsigned)cy < (unsigned)GY &&
                     (unsigned)cz < (unsigned)GZ;
        float h2 = b2[t];
        #pragma unroll
        for (int jj = 0; jj < HID; ++jj) h2 = fmaf(h1[jj], w2[jj * HID + t], h2);
        if (valid) {
            size_t sp = ((size_t)cx * GY + cy) * GZ + cz;
            atomicAdd(&vol[((size_t)b * PL + sp) * 16 + t], h2);
            if (t == 0) atomicAdd(&cnt[(size_t)b * PL + sp], 1.0f);
        }
    }
}

// ---------------- conv1 (17ch via K=32 MFMA; norm+mask built on the fly) ----------------
__global__ __launch_bounds__(256) void occ_conv1_kernel(
    const float* __restrict__ volf, const float* __restrict__ cnt,
    const __hip_bfloat16* __restrict__ wB, const float* __restrict__ bias,
    __hip_bfloat16* __restrict__ out, float* __restrict__ stats)
{
    int blk = blockIdx.x;                       // b*10000 + x*50 + yt
    int b = blk / (GX * 50);
    int rem = blk % (GX * 50);
    int x = rem / 50;
    int y = (rem % 50) * 4 + (threadIdx.x >> 6);
    int lane = threadIdx.x & 63;
    int z = lane & 15, kg = lane >> 4;

    float bo = bias[lane & 15];
    floatx4 acc = {bo, bo, bo, bo};

    size_t cbase[3][3];
    bool   cval[3][3];
    #pragma unroll
    for (int kd = 0; kd < 3; ++kd)
        #pragma unroll
        for (int kh = 0; kh < 3; ++kh) {
            int cx = x + kd - 1, cy = y + kh - 1;
            bool v = ((unsigned)cx < (unsigned)GX) && ((unsigned)cy < (unsigned)GY);
            int cxc = min(GX - 1, max(0, cx)), cyc = min(GY - 1, max(0, cy));
            cbase[kd][kh] = (size_t)b * PL + ((size_t)cxc * GY + cyc) * 16;
            cval[kd][kh] = v;
        }

    const short8* wp = (const short8*)wB;

    #pragma unroll
    for (int tap = 0; tap < 27; ++tap) {
        const int kd = tap / 9, kh = (tap / 3) % 3, kw = tap % 3;
        int zr = z + kw - 1;
        bool v = cval[kd][kh] && ((unsigned)zr < 16u);
        int zrc = min(15, max(0, zr));
        size_t rowidx = cbase[kd][kh] + zrc;
        short8 a;
        if (kg < 2) {
            float cn = cnt[rowidx];
            float inv = 1.0f / fmaxf(cn, 1.0f);
            const float* vp = volf + rowidx * 16 + kg * 8;
            float4 f0 = *(const float4*)vp;
            float4 f1 = *(const float4*)(vp + 4);
            a[0] = (short)f2bf(f0.x * inv); a[1] = (short)f2bf(f0.y * inv);
            a[2] = (short)f2bf(f0.z * inv); a[3] = (short)f2bf(f0.w * inv);
            a[4] = (short)f2bf(f1.x * inv); a[5] = (short)f2bf(f1.y * inv);
            a[6] = (short)f2bf(f1.z * inv); a[7] = (short)f2bf(f1.w * inv);
        } else if (kg == 2) {
            float cn = cnt[rowidx];
            a = zero8();
            a[0] = (short)f2bf(cn > 0.f ? 1.f : 0.f);   // mask channel k=16
        } else {
            a = zero8();
        }
        if (!v) a = zero8();
        short8 bf = wp[tap * 64 + lane];
        acc = __builtin_amdgcn_mfma_f32_16x16x32_bf16(a, bf, acc, 0, 0, 0);
    }

    // store D: row z = kg*4+r, col o = lane&15 ; layout [b][sp][16] bf16
    int o = lane & 15;
    size_t ocol = (size_t)b * PL + ((size_t)x * GY + y) * 16;
    #pragma unroll
    for (int r = 0; r < 4; ++r)
        out[(ocol + kg * 4 + r) * 16 + o] = __float2bfloat16(acc[r]);

    // fused BN stats
    float s  = acc[0] + acc[1] + acc[2] + acc[3];
    float sq = acc[0]*acc[0] + acc[1]*acc[1] + acc[2]*acc[2] + acc[3]*acc[3];
    s  += __shfl_xor(s, 16);  s  += __shfl_xor(s, 32);
    sq += __shfl_xor(sq, 16); sq += __shfl_xor(sq, 32);
    __shared__ float sred[4][32];
    int wv = threadIdx.x >> 6;
    if (lane < 16) { sred[wv][lane] = s; sred[wv][16 + lane] = sq; }
    __syncthreads();
    int t = threadIdx.x;
    if (t < 32) {
        float v2 = sred[0][t] + sred[1][t] + sred[2][t] + sred[3][t];
        atomicAdd(&stats[(size_t)(blockIdx.x & 63) * 32 + t], v2);
    }
}

// ---------------- conv2 (16ch; two taps per K=32 MFMA, 14 MFMAs) ----------------
__global__ __launch_bounds__(256) void occ_conv2_kernel(
    const __hip_bfloat16* __restrict__ in,
    const __hip_bfloat16* __restrict__ wB, const float* __restrict__ bias,
    __hip_bfloat16* __restrict__ out, float* __restrict__ stats)
{
    int blk = blockIdx.x;
    int b = blk / (GX * 50);
    int rem = blk % (GX * 50);
    int x = rem / 50;
    int y = (rem % 50) * 4 + (threadIdx.x >> 6);
    int lane = threadIdx.x & 63;
    int z = lane & 15, kg = lane >> 4;
    int half = kg >> 1;
    int ci0 = (kg & 1) << 3;

    float bo = bias[lane & 15];
    floatx4 acc = {bo, bo, bo, bo};

    const short8* wp = (const short8*)wB;

    #pragma unroll
    for (int t2 = 0; t2 < 14; ++t2) {
        const int ta = 2 * t2;
        const int tb = (2 * t2 + 1 > 26) ? 26 : 2 * t2 + 1;
        const int kda = ta / 9, kha = (ta / 3) % 3, kwa = ta % 3;
        const int kdb = tb / 9, khb = (tb / 3) % 3, kwb = tb % 3;
        int kd = half ? kdb : kda;
        int kh = half ? khb : kha;
        int kw = half ? kwb : kwa;
        int cx = x + kd - 1, cy = y + kh - 1, zr = z + kw - 1;
        bool v = ((unsigned)cx < (unsigned)GX) && ((unsigned)cy < (unsigned)GY) && ((unsigned)zr < 16u);
        int cxc = min(GX - 1, max(0, cx)), cyc = min(GY - 1, max(0, cy));
        int zrc = min(15, max(0, zr));
        size_t rowidx = (size_t)b * PL + ((size_t)cxc * GY + cyc) * 16 + zrc;
        short8 a = *(const short8*)(in + rowidx * 16 + ci0);
        if (!v) a = zero8();
        short8 bf = wp[t2 * 64 + lane];
        acc = __builtin_amdgcn_mfma_f32_16x16x32_bf16(a, bf, acc, 0, 0, 0);
    }

    int o = lane & 15;
    size_t ocol = (size_t)b * PL + ((size_t)x * GY + y) * 16;
    #pragma unroll
    for (int r = 0; r < 4; ++r)
        out[(ocol + kg * 4 + r) * 16 + o] = __float2bfloat16(acc[r]);

    float s  = acc[0] + acc[1] + acc[2] + acc[3];
    float sq = acc[0]*acc[0] + acc[1]*acc[1] + acc[2]*acc[2] + acc[3]*acc[3];
    s  += __shfl_xor(s, 16);  s  += __shfl_xor(s, 32);
    sq += __shfl_xor(sq, 16); sq += __shfl_xor(sq, 32);
    __shared__ float sred[4][32];
    int wv = threadIdx.x >> 6;
    if (lane < 16) { sred[wv][lane] = s; sred[wv][16 + lane] = sq; }
    __syncthreads();
    int t = threadIdx.x;
    if (t < 32) {
        float v2 = sred[0][t] + sred[1][t] + sred[2][t] + sred[3][t];
        atomicAdd(&stats[(size_t)(blockIdx.x & 63) * 32 + t], v2);
    }
}

// ---------------- BN finalize ----------------
__global__ void occ_bnfin_kernel(const float* __restrict__ stats, const float* __restrict__ g,
                                 const float* __restrict__ bb, float* __restrict__ bn)
{
    int c = threadIdx.x;
    if (c >= 16) return;
    float s = 0.f, sq = 0.f;
    for (int k = 0; k < 64; ++k) { s += stats[k * 32 + c]; sq += stats[k * 32 + 16 + c]; }
    const float N = (float)(NB * PL);
    float mean = s / N;
    float var = sq / N - mean * mean;
    float scale = g[c] * rsqrtf(var + EPSF);
    bn[c] = scale;
    bn[16 + c] = bb[c] - mean * scale;
}

// ---------------- BN affine + GELU, in-place on bf16 channels-last ----------------
__global__ __launch_bounds__(256) void occ_bnact_kernel(__hip_bfloat16* __restrict__ buf,
                                                        const float* __restrict__ bn)
{
    __shared__ float sc[16], sh[16];
    int t = threadIdx.x;
    if (t < 16) sc[t] = bn[t];
    else if (t < 32) sh[t - 16] = bn[t];
    __syncthreads();
    size_t i = (size_t)blockIdx.x * 256 + t;      // row < NB*PL
    short8* p = (short8*)(buf + i * 16);
    short8 v0 = p[0], v1 = p[1];
    #pragma unroll
    for (int e = 0; e < 8; ++e) {
        float a0 = gelu_exact(fmaf(bf2f(v0[e]), sc[e],     sh[e]));
        float a1 = gelu_exact(fmaf(bf2f(v1[e]), sc[8 + e], sh[8 + e]));
        v0[e] = (short)f2bf(a0);
        v1[e] = (short)f2bf(a1);
    }
    p[0] = v0; p[1] = v1;
}

// ---------------- conv3 1x1x1 (16 -> 20), fp32 out channels-first ----------------
__global__ __launch_bounds__(256) void occ_conv3_kernel(const __hip_bfloat16* __restrict__ act,
                                                        const float* __restrict__ w3,
                                                        const float* __restrict__ b3,
                                                        float* __restrict__ out)
{
    __shared__ float w[NCLS * 16];
    __shared__ float bb[NCLS];
    int t = threadIdx.x;
    for (int i = t; i < NCLS * 16; i += 256) w[i] = w3[i];
    if (t < NCLS) bb[t] = b3[t];
    __syncthreads();
    size_t i = (size_t)blockIdx.x * 256 + t;      // < NB*PL
    size_t b = i / PL, sp = i % PL;
    const short8* p = (const short8*)(act + i * 16);
    short8 v0 = p[0], v1 = p[1];
    float vi[16];
    #pragma unroll
    for (int e = 0; e < 8; ++e) { vi[e] = bf2f(v0[e]); vi[8 + e] = bf2f(v1[e]); }
    float* op = out + b * NCLS * PL + sp;
    #pragma unroll
    for (int cls = 0; cls < NCLS; ++cls) {
        float a = bb[cls];
        #pragma unroll
        for (int ci = 0; ci < 16; ++ci) a = fmaf(vi[ci], w[cls * 16 + ci], a);
        op[(size_t)cls * PL] = a;
    }
}

// ---------------- launch ----------------
extern "C" void kernel_launch(void* const* d_in, const int* in_sizes, int n_in,
                              void* d_out, int out_size, void* d_ws, size_t ws_size,
                              hipStream_t stream)
{
    const float* tokens = (const float*)d_in[0];
    const float* depth  = (const float*)d_in[1];
    const float* intr   = (const float*)d_in[2];
    const float* c2w    = (const float*)d_in[3];
    const float* l2w    = (const float*)d_in[4];
    const float* ln_g   = (const float*)d_in[5];
    const float* ln_b   = (const float*)d_in[6];
    const float* w1     = (const float*)d_in[7];
    const float* b1     = (const float*)d_in[8];
    const float* w2     = (const float*)d_in[9];
    const float* b2     = (const float*)d_in[10];
    const float* cv1w   = (const float*)d_in[11];
    const float* cv1b   = (const float*)d_in[12];
    const float* bn1g   = (const float*)d_in[13];
    const float* bn1b   = (const float*)d_in[14];
    const float* cv2w   = (const float*)d_in[15];
    const float* cv2b   = (const float*)d_in[16];
    const float* bn2g   = (const float*)d_in[17];
    const float* bn2b   = (const float*)d_in[18];
    const float* cv3w   = (const float*)d_in[19];
    const float* cv3b   = (const float*)d_in[20];

    if (ws_size < WS_FLOATS * sizeof(float)) return;

    float* ws   = (float*)d_ws;
    float* volf = ws + OFF_VOL;
    float* cntp = ws + OFF_CNT;
    float* st1  = ws + OFF_ST1;
    float* st2  = ws + OFF_ST2;
    float* mats = ws + OFF_MATS;
    float* w1T  = ws + OFF_W1T;
    __hip_bfloat16* wB1 = (__hip_bfloat16*)(ws + OFF_WB1);
    __hip_bfloat16* wB2 = (__hip_bfloat16*)(ws + OFF_WB2);
    float* bnp1 = ws + OFF_BN1;
    float* bnp2 = ws + OFF_BN2;

    // staged activations: conv1 out -> first 41MB of d_out (dead before conv3 writes);
    // conv2 out -> aliases volf (dead after conv1).
    __hip_bfloat16* staged2 = (__hip_bfloat16*)d_out;
    __hip_bfloat16* staged3 = (__hip_bfloat16*)(ws + OFF_VOL);
    float* outp = (float*)d_out;

    hipMemsetAsync(ws, 0, ZERO_F * sizeof(float), stream);

    occ_prep_kernel<<<1, 256, 0, stream>>>(intr, c2w, l2w, w1, cv1w, cv2w, mats, w1T, wB1, wB2);

    occ_token_kernel<<<NB * NCAM * NP, 256, 0, stream>>>(
        tokens, depth, ln_g, ln_b, w1T, b1, w2, b2, mats, volf, cntp);

    const int CGRID = NB * GX * (GY / 4);   // 20000
    occ_conv1_kernel<<<CGRID, 256, 0, stream>>>(volf, cntp, wB1, cv1b, staged2, st1);
    occ_bnfin_kernel<<<1, 16, 0, stream>>>(st1, bn1g, bn1b, bnp1);
    occ_bnact_kernel<<<5000, 256, 0, stream>>>(staged2, bnp1);

    occ_conv2_kernel<<<CGRID, 256, 0, stream>>>(staged2, wB2, cv2b, staged3, st2);
    occ_bnfin_kernel<<<1, 16, 0, stream>>>(st2, bn2g, bn2b, bnp2);
    occ_bnact_kernel<<<5000, 256, 0, stream>>>(staged3, bnp2);

    occ_conv3_kernel<<<5000, 256, 0, stream>>>(staged3, cv3w, cv3b, outp);
}

// Round 3
// 313.279 us; speedup vs baseline: 7.7652x; 1.6521x over previous
//
#include <hip/hip_runtime.h>
#include <hip/hip_bf16.h>
#include <math.h>

// ---------------- problem constants ----------------
#define PATCH 14
#define HID   16
#define NCLS  20
#define GX    200
#define GY    200
#define GZ    16
#define NB    2
#define NCAM  6
#define PH    37
#define PW    37
#define NP    (PH*PW)
#define TD    768
#define IMH   518
#define IMW   518
#define PL    ((size_t)GX*GY*GZ)   // 640000 voxels per batch
#define EPSF  1e-5f

// ---------------- workspace layout (float units) ----------------
#define OFF_VOL   ((size_t)0)            // volf [b][sp][16] fp32 (later reused as staged3 bf16)
#define OFF_CNT   ((size_t)20480000)
#define OFF_ST1   ((size_t)21760000)
#define OFF_ST2   ((size_t)21762048)
#define ZERO_F    ((size_t)21764096)     // zeroed every call up to here
#define OFF_MATS  ((size_t)21764096)     // 144
#define OFF_W1T   ((size_t)21764240)     // 12,288
#define OFF_WB1A  ((size_t)21776528)     // 14*64*8 bf16 = 3,584 f
#define OFF_WB1M  ((size_t)21780112)     // 64*8 bf16 = 256 f
#define OFF_WB2   ((size_t)21780368)     // 3,584 f
#define OFF_BN1   ((size_t)21783952)     // 32
#define OFF_BN2   ((size_t)21783984)     // 32
#define WS_FLOATS ((size_t)21784016)

// ---------------- d_out staging layout (bf16 units; all dead before conv3 writes) --
#define DO_DECN ((size_t)0)              // normalized dec_in [b][sp][16]   20,480,000
#define DO_MSK  ((size_t)20480000)       // mask plane [b][sp]               1,280,000
#define DO_ST2  ((size_t)21760000)       // conv1 output [b][sp][16]        20,480,000
                                         // total 42,240,000 <= 51,200,000 bf16 slots

typedef __attribute__((ext_vector_type(8))) short short8;
typedef __attribute__((ext_vector_type(4))) float floatx4;

__device__ __forceinline__ float gelu_exact(float x) {
    return 0.5f * x * (1.0f + erff(x * 0.70710678118654752f));
}
__device__ __forceinline__ unsigned short f2bf(float f) {
    __hip_bfloat16 h = __float2bfloat16(f);
    return __builtin_bit_cast(unsigned short, h);
}
__device__ __forceinline__ float bf2f(short u) {
    unsigned int b = ((unsigned int)(unsigned short)u) << 16;
    return __builtin_bit_cast(float, b);
}
__device__ __forceinline__ short8 zero8() {
    short8 z = {0,0,0,0,0,0,0,0};
    return z;
}

// ---------------- 3x3 / 4x4 inverse in double ----------------
__device__ void inv3d(const double* m, double* o) {
    double a=m[0],b=m[1],c=m[2],d=m[3],e=m[4],f=m[5],g=m[6],h=m[7],i=m[8];
    double A=e*i-f*h, B=-(d*i-f*g), C=d*h-e*g;
    double det=a*A+b*B+c*C, id=1.0/det;
    o[0]=A*id;            o[1]=-(b*i-c*h)*id;   o[2]=(b*f-c*e)*id;
    o[3]=B*id;            o[4]=(a*i-c*g)*id;    o[5]=-(a*f-c*d)*id;
    o[6]=C*id;            o[7]=-(a*h-b*g)*id;   o[8]=(a*e-b*d)*id;
}

__device__ void inv4d(const double* m, double* o) {
    double i0  =  m[5]*m[10]*m[15]-m[5]*m[11]*m[14]-m[9]*m[6]*m[15]+m[9]*m[7]*m[14]+m[13]*m[6]*m[11]-m[13]*m[7]*m[10];
    double i4  = -m[4]*m[10]*m[15]+m[4]*m[11]*m[14]+m[8]*m[6]*m[15]-m[8]*m[7]*m[14]-m[12]*m[6]*m[11]+m[12]*m[7]*m[10];
    double i8  =  m[4]*m[9]*m[15]-m[4]*m[11]*m[13]-m[8]*m[5]*m[15]+m[8]*m[7]*m[13]+m[12]*m[5]*m[11]-m[12]*m[7]*m[9];
    double i12 = -m[4]*m[9]*m[14]+m[4]*m[10]*m[13]+m[8]*m[5]*m[14]-m[8]*m[6]*m[13]-m[12]*m[5]*m[10]+m[12]*m[6]*m[9];
    double i1  = -m[1]*m[10]*m[15]+m[1]*m[11]*m[14]+m[9]*m[2]*m[15]-m[9]*m[3]*m[14]-m[13]*m[2]*m[11]+m[13]*m[3]*m[10];
    double i5  =  m[0]*m[10]*m[15]-m[0]*m[11]*m[14]-m[8]*m[2]*m[15]+m[8]*m[3]*m[14]+m[12]*m[2]*m[11]-m[12]*m[3]*m[10];
    double i9  = -m[0]*m[9]*m[15]+m[0]*m[11]*m[13]+m[8]*m[1]*m[15]-m[8]*m[3]*m[13]-m[12]*m[1]*m[11]+m[12]*m[3]*m[9];
    double i13 =  m[0]*m[9]*m[14]-m[0]*m[10]*m[13]-m[8]*m[1]*m[14]+m[8]*m[2]*m[13]+m[12]*m[1]*m[10]-m[12]*m[2]*m[9];
    double i2  =  m[1]*m[6]*m[15]-m[1]*m[7]*m[14]-m[5]*m[2]*m[15]+m[5]*m[3]*m[14]+m[13]*m[2]*m[7]-m[13]*m[3]*m[6];
    double i6  = -m[0]*m[6]*m[15]+m[0]*m[7]*m[14]+m[4]*m[2]*m[15]-m[4]*m[3]*m[14]-m[12]*m[2]*m[7]+m[12]*m[3]*m[6];
    double i10 =  m[0]*m[5]*m[15]-m[0]*m[7]*m[13]-m[4]*m[1]*m[15]+m[4]*m[3]*m[13]+m[12]*m[1]*m[7]-m[12]*m[3]*m[5];
    double i14 = -m[0]*m[5]*m[14]+m[0]*m[6]*m[13]+m[4]*m[1]*m[14]-m[4]*m[2]*m[13]-m[12]*m[1]*m[6]+m[12]*m[2]*m[5];
    double i3  = -m[1]*m[6]*m[11]+m[1]*m[7]*m[10]+m[5]*m[2]*m[11]-m[5]*m[3]*m[10]-m[9]*m[2]*m[7]+m[9]*m[3]*m[6];
    double i7  =  m[0]*m[6]*m[11]-m[0]*m[7]*m[10]-m[4]*m[2]*m[11]+m[4]*m[3]*m[10]+m[8]*m[2]*m[7]-m[8]*m[3]*m[6];
    double i11 = -m[0]*m[5]*m[11]+m[0]*m[7]*m[9]+m[4]*m[1]*m[11]-m[4]*m[3]*m[9]-m[8]*m[1]*m[7]+m[8]*m[3]*m[5];
    double i15 =  m[0]*m[5]*m[10]-m[0]*m[6]*m[9]-m[4]*m[1]*m[10]+m[4]*m[2]*m[9]+m[8]*m[1]*m[6]-m[8]*m[2]*m[5];
    double det = m[0]*i0+m[1]*i4+m[2]*i8+m[3]*i12;
    double id = 1.0/det;
    o[0]=i0*id; o[1]=i1*id; o[2]=i2*id; o[3]=i3*id;
    o[4]=i4*id; o[5]=i5*id; o[6]=i6*id; o[7]=i7*id;
    o[8]=i8*id; o[9]=i9*id; o[10]=i10*id; o[11]=i11*id;
    o[12]=i12*id; o[13]=i13*id; o[14]=i14*id; o[15]=i15*id;
}

// ---------------- precompute ----------------
__global__ void occ_prep_kernel(const float* __restrict__ intr, const float* __restrict__ c2w,
                                const float* __restrict__ l2w, const float* __restrict__ w1,
                                const float* __restrict__ cw1, const float* __restrict__ cw2,
                                float* __restrict__ mats, float* __restrict__ w1T,
                                __hip_bfloat16* __restrict__ wB1a, __hip_bfloat16* __restrict__ wB1m,
                                __hip_bfloat16* __restrict__ wB2)
{
    int t = threadIdx.x;
    if (t < NB * NCAM) {
        int b = t / NCAM;
        double K[9], Ki[9], L[16], Li[16], C[16], M[16], A[9];
        #pragma unroll
        for (int i = 0; i < 9; ++i) K[i] = (double)intr[t * 9 + i];
        inv3d(K, Ki);
        #pragma unroll
        for (int i = 0; i < 16; ++i) L[i] = (double)l2w[b * 16 + i];
        inv4d(L, Li);
        #pragma unroll
        for (int i = 0; i < 16; ++i) C[i] = (double)c2w[t * 16 + i];
        #pragma unroll
        for (int r = 0; r < 4; ++r)
            #pragma unroll
            for (int c = 0; c < 4; ++c) {
                double s = 0.0;
                #pragma unroll
                for (int k = 0; k < 4; ++k) s += Li[r * 4 + k] * C[k * 4 + c];
                M[r * 4 + c] = s;
            }
        #pragma unroll
        for (int r = 0; r < 3; ++r)
            #pragma unroll
            for (int c = 0; c < 3; ++c) {
                double s = 0.0;
                #pragma unroll
                for (int k = 0; k < 3; ++k) s += M[r * 4 + k] * Ki[k * 3 + c];
                A[r * 3 + c] = s;
            }
        #pragma unroll
        for (int i = 0; i < 9; ++i) mats[t * 12 + i] = (float)A[i];
        mats[t * 12 + 9]  = (float)M[3];
        mats[t * 12 + 10] = (float)M[7];
        mats[t * 12 + 11] = (float)M[11];
    }
    // w1 (768,16) -> w1T (16,768)
    for (int i = t; i < TD * HID; i += 256) {
        int d = i >> 4, j = i & 15;
        w1T[j * TD + d] = w1[i];
    }
    // conv1 main (16 vol channels): wB1a[t2][lane][8]; K packs 2 taps x 16 ch
    for (int i = t; i < 14 * 64 * 8; i += 256) {
        int t2 = i >> 9; int r = i & 511; int ln = r >> 3; int e = r & 7;
        int kg = ln >> 4;
        int tt = 2 * t2 + (kg >> 1);
        int ci = ((kg & 1) << 3) + e;
        int o = ln & 15;
        float val = (tt < 27) ? cw1[(o * 17 + ci) * 27 + tt] : 0.f;
        wB1a[i] = __float2bfloat16(val);
    }
    // conv1 mask channel (ci=16): wB1m[lane][8]; K slot = tap index
    for (int i = t; i < 64 * 8; i += 256) {
        int ln = i >> 3; int e = i & 7;
        int k = ((ln >> 4) << 3) + e;
        int o = ln & 15;
        float val = (k < 27) ? cw1[(o * 17 + 16) * 27 + k] : 0.f;
        wB1m[i] = __float2bfloat16(val);
    }
    // conv2: wB2[t2][lane][8]
    for (int i = t; i < 14 * 64 * 8; i += 256) {
        int t2 = i >> 9; int r = i & 511; int ln = r >> 3; int e = r & 7;
        int kg = ln >> 4;
        int tt = 2 * t2 + (kg >> 1);
        int ci = ((kg & 1) << 3) + e;
        int o = ln & 15;
        float val = (tt < 27) ? cw2[(o * 16 + ci) * 27 + tt] : 0.f;
        wB2[i] = __float2bfloat16(val);
    }
}

// ---------------- token: depth pool + LN + MLP + geometry + scatter ----------------
__global__ __launch_bounds__(256) void occ_token_kernel(
    const float* __restrict__ tokens, const float* __restrict__ depth,
    const float* __restrict__ ln_g, const float* __restrict__ ln_b,
    const float* __restrict__ w1T, const float* __restrict__ b1,
    const float* __restrict__ w2, const float* __restrict__ b2,
    const float* __restrict__ mats, float* __restrict__ vol, float* __restrict__ cnt)
{
    int blk = blockIdx.x;
    int p = blk % NP;
    int bc = blk / NP;
    int b = bc / NCAM;
    int gy = p / PW, gx = p % PW;
    int t = threadIdx.x;

    __shared__ float red[256];
    __shared__ float red2[256];
    __shared__ float xn[TD];
    __shared__ float h1[HID];
    __shared__ float s_dm;

    float dv = 0.f;
    if (t < PATCH * PATCH) {
        int py = t / PATCH, px = t % PATCH;
        int row = gy * PATCH + py, col = gx * PATCH + px;
        dv = depth[((size_t)bc * IMH + row) * IMW + col];
    }
    red[t] = dv;
    __syncthreads();
    #pragma unroll
    for (int off = 128; off > 0; off >>= 1) {
        if (t < off) red[t] += red[t + off];
        __syncthreads();
    }
    if (t == 0) s_dm = red[0] * (1.0f / 196.0f);

    const float* tok = tokens + ((size_t)bc * NP + p) * TD;
    float x0 = tok[t], x1 = tok[t + 256], x2 = tok[t + 512];
    red[t]  = x0 + x1 + x2;
    red2[t] = x0 * x0 + x1 * x1 + x2 * x2;
    __syncthreads();
    #pragma unroll
    for (int off = 128; off > 0; off >>= 1) {
        if (t < off) { red[t] += red[t + off]; red2[t] += red2[t + off]; }
        __syncthreads();
    }
    float mu  = red[0] * (1.0f / (float)TD);
    float var = red2[0] * (1.0f / (float)TD) - mu * mu;
    float rs  = rsqrtf(var + EPSF);
    xn[t]       = (x0 - mu) * rs * ln_g[t]       + ln_b[t];
    xn[t + 256] = (x1 - mu) * rs * ln_g[t + 256] + ln_b[t + 256];
    xn[t + 512] = (x2 - mu) * rs * ln_g[t + 512] + ln_b[t + 512];
    __syncthreads();

    int j = t >> 4, sl = t & 15;
    float acc = 0.f;
    #pragma unroll
    for (int i = 0; i < TD / 16; ++i) {
        int d = sl + (i << 4);
        acc = fmaf(xn[d], w1T[j * TD + d], acc);
    }
    acc += __shfl_down(acc, 8, 16);
    acc += __shfl_down(acc, 4, 16);
    acc += __shfl_down(acc, 2, 16);
    acc += __shfl_down(acc, 1, 16);
    if (sl == 0) h1[j] = gelu_exact(acc + b1[j]);
    __syncthreads();

    if (t < HID) {
        const float* M = mats + bc * 12;
        float dmr = s_dm;
        float dm = fmaxf(dmr, 0.f);
        float u = (gx + 0.5f) * (float)PATCH;
        float v = (gy + 0.5f) * (float)PATCH;
        float lx = (M[0] * u + M[1] * v + M[2]) * dm + M[9];
        float ly = (M[3] * u + M[4] * v + M[5]) * dm + M[10];
        float lz = (M[6] * u + M[7] * v + M[8]) * dm + M[11];
        int cx = (int)floorf((lx + 40.0f) / 0.4f);
        int cy = (int)floorf((ly + 40.0f) / 0.4f);
        int cz = (int)floorf((lz + 1.0f) / 0.4f);
        bool valid = (dmr > 0.001f) &&
                     (unsigned)cx < (unsigned)GX &&
                     (unsigned)cy < (unsigned)GY &&
                     (unsigned)cz < (unsigned)GZ;
        float h2 = b2[t];
        #pragma unroll
        for (int jj = 0; jj < HID; ++jj) h2 = fmaf(h1[jj], w2[jj * HID + t], h2);
        if (valid) {
            size_t sp = ((size_t)cx * GY + cy) * GZ + cz;
            atomicAdd(&vol[((size_t)b * PL + sp) * 16 + t], h2);
            if (t == 0) atomicAdd(&cnt[(size_t)b * PL + sp], 1.0f);
        }
    }
}

// ---------------- normalize: vol/cnt -> bf16 dec_in + bf16 mask (one pass) -------
__global__ __launch_bounds__(256) void occ_norm_kernel(
    const float* __restrict__ volf, const float* __restrict__ cnt,
    __hip_bfloat16* __restrict__ decn, __hip_bfloat16* __restrict__ msk)
{
    size_t i = (size_t)blockIdx.x * 256 + threadIdx.x;   // < NB*PL
    float cn = cnt[i];
    float inv = 1.0f / fmaxf(cn, 1.0f);
    const float4* vp = (const float4*)(volf + i * 16);
    float4 f0 = vp[0], f1 = vp[1], f2 = vp[2], f3 = vp[3];
    short8 o0, o1;
    o0[0] = (short)f2bf(f0.x * inv); o0[1] = (short)f2bf(f0.y * inv);
    o0[2] = (short)f2bf(f0.z * inv); o0[3] = (short)f2bf(f0.w * inv);
    o0[4] = (short)f2bf(f1.x * inv); o0[5] = (short)f2bf(f1.y * inv);
    o0[6] = (short)f2bf(f1.z * inv); o0[7] = (short)f2bf(f1.w * inv);
    o1[0] = (short)f2bf(f2.x * inv); o1[1] = (short)f2bf(f2.y * inv);
    o1[2] = (short)f2bf(f2.z * inv); o1[3] = (short)f2bf(f2.w * inv);
    o1[4] = (short)f2bf(f3.x * inv); o1[5] = (short)f2bf(f3.y * inv);
    o1[6] = (short)f2bf(f3.z * inv); o1[7] = (short)f2bf(f3.w * inv);
    short8* dp = (short8*)(decn + i * 16);
    dp[0] = o0; dp[1] = o1;
    msk[i] = __float2bfloat16(cn > 0.f ? 1.f : 0.f);
}

// ---------------- conv3d 3x3x3 via MFMA; MASK adds the 17th (mask) channel -------
template <bool MASK>
__global__ __launch_bounds__(256) void occ_conv_kernel(
    const __hip_bfloat16* __restrict__ in, const __hip_bfloat16* __restrict__ msk,
    const __hip_bfloat16* __restrict__ wBa, const __hip_bfloat16* __restrict__ wBm,
    const float* __restrict__ bias, __hip_bfloat16* __restrict__ out,
    float* __restrict__ stats)
{
    // XCD-chunked swizzle (20000 % 8 == 0 -> bijective)
    int bid = blockIdx.x;
    int blk = (bid & 7) * ((NB * GX * 50) / 8) + (bid >> 3);
    int b = blk / (GX * 50);
    int rem = blk % (GX * 50);
    int x = rem / 50;
    int y = (rem % 50) * 4 + (threadIdx.x >> 6);
    int lane = threadIdx.x & 63;
    int z = lane & 15, kg = lane >> 4;
    bool halfsel = (kg >> 1) != 0;
    int ci0 = (kg & 1) << 3;

    float bo = bias[lane & 15];
    floatx4 acc = {bo, bo, bo, bo};

    size_t cbase[3][3];
    bool   cval[3][3];
    #pragma unroll
    for (int kd = 0; kd < 3; ++kd)
        #pragma unroll
        for (int kh = 0; kh < 3; ++kh) {
            int cx = x + kd - 1, cy = y + kh - 1;
            bool v = ((unsigned)cx < (unsigned)GX) && ((unsigned)cy < (unsigned)GY);
            int cxc = min(GX - 1, max(0, cx)), cyc = min(GY - 1, max(0, cy));
            cbase[kd][kh] = (size_t)b * PL + ((size_t)cxc * GY + cyc) * 16;
            cval[kd][kh] = v;
        }
    int zoff[3];
    bool vz[3];
    zoff[0] = max(0, z - 1); zoff[1] = z; zoff[2] = min(15, z + 1);
    vz[0] = (z > 0); vz[1] = true; vz[2] = (z < 15);

    const short8* wp = (const short8*)wBa;

    #pragma unroll
    for (int t2 = 0; t2 < 14; ++t2) {
        const int ta = 2 * t2;
        const int tb = (2 * t2 + 1 > 26) ? 26 : 2 * t2 + 1;
        const int kda = ta / 9, kha = (ta / 3) % 3, kwa = ta % 3;
        const int kdb = tb / 9, khb = (tb / 3) % 3, kwb = tb % 3;
        size_t ia = cbase[kda][kha] + (size_t)zoff[kwa];
        size_t ib = cbase[kdb][khb] + (size_t)zoff[kwb];
        bool va = cval[kda][kha] && vz[kwa];
        bool vb = cval[kdb][khb] && vz[kwb];
        size_t idx = halfsel ? ib : ia;
        bool v = halfsel ? vb : va;
        short8 a = *(const short8*)(in + idx * 16 + ci0);
        if (!v) a = zero8();
        short8 bf = wp[t2 * 64 + lane];
        acc = __builtin_amdgcn_mfma_f32_16x16x32_bf16(a, bf, acc, 0, 0, 0);
    }

    if constexpr (MASK) {
        short8 am;
        #pragma unroll
        for (int e = 0; e < 8; ++e) {
            int tap = kg * 8 + e;
            int kd = tap / 9;
            int rm = tap - kd * 9;
            int kh = rm / 3;
            int kw = rm - kh * 3;
            int cx = x + kd - 1, cy = y + kh - 1, zr = z + kw - 1;
            bool v = (tap < 27) && ((unsigned)cx < (unsigned)GX) &&
                     ((unsigned)cy < (unsigned)GY) && ((unsigned)zr < 16u);
            int cxc = min(GX - 1, max(0, cx)), cyc = min(GY - 1, max(0, cy));
            int zrc = min(15, max(0, zr));
            size_t idx = (size_t)b * PL + ((size_t)cxc * GY + cyc) * 16 + zrc;
            unsigned short mv = v ? *(const unsigned short*)(msk + idx) : (unsigned short)0;
            am[e] = (short)mv;
        }
        short8 bm = ((const short8*)wBm)[lane];
        acc = __builtin_amdgcn_mfma_f32_16x16x32_bf16(am, bm, acc, 0, 0, 0);
    }

    // store D: row z = kg*4+r, col o = lane&15 ; layout [b][sp][16] bf16
    int o = lane & 15;
    size_t ocol = (size_t)b * PL + ((size_t)x * GY + y) * 16;
    #pragma unroll
    for (int r = 0; r < 4; ++r)
        out[(ocol + kg * 4 + r) * 16 + o] = __float2bfloat16(acc[r]);

    // fused BN stats
    float s  = acc[0] + acc[1] + acc[2] + acc[3];
    float sq = acc[0]*acc[0] + acc[1]*acc[1] + acc[2]*acc[2] + acc[3]*acc[3];
    s  += __shfl_xor(s, 16);  s  += __shfl_xor(s, 32);
    sq += __shfl_xor(sq, 16); sq += __shfl_xor(sq, 32);
    __shared__ float sred[4][32];
    int wv = threadIdx.x >> 6;
    if (lane < 16) { sred[wv][lane] = s; sred[wv][16 + lane] = sq; }
    __syncthreads();
    int t = threadIdx.x;
    if (t < 32) {
        float v2 = sred[0][t] + sred[1][t] + sred[2][t] + sred[3][t];
        atomicAdd(&stats[(size_t)(blockIdx.x & 63) * 32 + t], v2);
    }
}

// ---------------- BN finalize ----------------
__global__ void occ_bnfin_kernel(const float* __restrict__ stats, const float* __restrict__ g,
                                 const float* __restrict__ bb, float* __restrict__ bn)
{
    int c = threadIdx.x;
    if (c >= 16) return;
    float s = 0.f, sq = 0.f;
    for (int k = 0; k < 64; ++k) { s += stats[k * 32 + c]; sq += stats[k * 32 + 16 + c]; }
    const float N = (float)(NB * PL);
    float mean = s / N;
    float var = sq / N - mean * mean;
    float scale = g[c] * rsqrtf(var + EPSF);
    bn[c] = scale;
    bn[16 + c] = bb[c] - mean * scale;
}

// ---------------- BN affine + GELU, in-place bf16 channels-last ----------------
__global__ __launch_bounds__(256) void occ_bnact_kernel(__hip_bfloat16* __restrict__ buf,
                                                        const float* __restrict__ bn)
{
    __shared__ float sc[16], sh[16];
    int t = threadIdx.x;
    if (t < 16) sc[t] = bn[t];
    else if (t < 32) sh[t - 16] = bn[t];
    __syncthreads();
    size_t i = (size_t)blockIdx.x * 256 + t;
    short8* p = (short8*)(buf + i * 16);
    short8 v0 = p[0], v1 = p[1];
    #pragma unroll
    for (int e = 0; e < 8; ++e) {
        float a0 = gelu_exact(fmaf(bf2f(v0[e]), sc[e],     sh[e]));
        float a1 = gelu_exact(fmaf(bf2f(v1[e]), sc[8 + e], sh[8 + e]));
        v0[e] = (short)f2bf(a0);
        v1[e] = (short)f2bf(a1);
    }
    p[0] = v0; p[1] = v1;
}

// ---------------- conv3 1x1x1 (16 -> 20) with fused bn2+GELU ----------------
__global__ __launch_bounds__(256) void occ_conv3_kernel(const __hip_bfloat16* __restrict__ act,
                                                        const float* __restrict__ bn,
                                                        const float* __restrict__ w3,
                                                        const float* __restrict__ b3,
                                                        float* __restrict__ out)
{
    __shared__ float w[NCLS * 16];
    __shared__ float bb[NCLS];
    __shared__ float sc[16], sh[16];
    int t = threadIdx.x;
    for (int i = t; i < NCLS * 16; i += 256) w[i] = w3[i];
    if (t < NCLS) bb[t] = b3[t];
    if (t >= 32 && t < 48) sc[t - 32] = bn[t - 32];
    if (t >= 48 && t < 64) sh[t - 48] = bn[t - 32];
    __syncthreads();
    size_t i = (size_t)blockIdx.x * 256 + t;      // < NB*PL
    size_t b = i / PL, sp = i % PL;
    const short8* p = (const short8*)(act + i * 16);
    short8 v0 = p[0], v1 = p[1];
    float vi[16];
    #pragma unroll
    for (int e = 0; e < 8; ++e) {
        vi[e]     = gelu_exact(fmaf(bf2f(v0[e]), sc[e],     sh[e]));
        vi[8 + e] = gelu_exact(fmaf(bf2f(v1[e]), sc[8 + e], sh[8 + e]));
    }
    float* op = out + b * NCLS * PL + sp;
    #pragma unroll
    for (int cls = 0; cls < NCLS; ++cls) {
        float a = bb[cls];
        #pragma unroll
        for (int ci = 0; ci < 16; ++ci) a = fmaf(vi[ci], w[cls * 16 + ci], a);
        op[(size_t)cls * PL] = a;
    }
}

// ---------------- launch ----------------
extern "C" void kernel_launch(void* const* d_in, const int* in_sizes, int n_in,
                              void* d_out, int out_size, void* d_ws, size_t ws_size,
                              hipStream_t stream)
{
    const float* tokens = (const float*)d_in[0];
    const float* depth  = (const float*)d_in[1];
    const float* intr   = (const float*)d_in[2];
    const float* c2w    = (const float*)d_in[3];
    const float* l2w    = (const float*)d_in[4];
    const float* ln_g   = (const float*)d_in[5];
    const float* ln_b   = (const float*)d_in[6];
    const float* w1     = (const float*)d_in[7];
    const float* b1     = (const float*)d_in[8];
    const float* w2     = (const float*)d_in[9];
    const float* b2     = (const float*)d_in[10];
    const float* cv1w   = (const float*)d_in[11];
    const float* cv1b   = (const float*)d_in[12];
    const float* bn1g   = (const float*)d_in[13];
    const float* bn1b   = (const float*)d_in[14];
    const float* cv2w   = (const float*)d_in[15];
    const float* cv2b   = (const float*)d_in[16];
    const float* bn2g   = (const float*)d_in[17];
    const float* bn2b   = (const float*)d_in[18];
    const float* cv3w   = (const float*)d_in[19];
    const float* cv3b   = (const float*)d_in[20];

    if (ws_size < WS_FLOATS * sizeof(float)) return;

    float* ws   = (float*)d_ws;
    float* volf = ws + OFF_VOL;
    float* cntp = ws + OFF_CNT;
    float* st1  = ws + OFF_ST1;
    float* st2  = ws + OFF_ST2;
    float* mats = ws + OFF_MATS;
    float* w1T  = ws + OFF_W1T;
    __hip_bfloat16* wB1a = (__hip_bfloat16*)(ws + OFF_WB1A);
    __hip_bfloat16* wB1m = (__hip_bfloat16*)(ws + OFF_WB1M);
    __hip_bfloat16* wB2  = (__hip_bfloat16*)(ws + OFF_WB2);
    float* bnp1 = ws + OFF_BN1;
    float* bnp2 = ws + OFF_BN2;

    // staging in d_out (all regions dead before conv3's full overwrite):
    __hip_bfloat16* ob      = (__hip_bfloat16*)d_out;
    __hip_bfloat16* decn    = ob + DO_DECN;
    __hip_bfloat16* mskp    = ob + DO_MSK;
    __hip_bfloat16* staged2 = ob + DO_ST2;
    // conv2 output aliases volf region (volf dead after norm pass)
    __hip_bfloat16* staged3 = (__hip_bfloat16*)(ws + OFF_VOL);
    float* outp = (float*)d_out;

    hipMemsetAsync(ws, 0, ZERO_F * sizeof(float), stream);

    occ_prep_kernel<<<1, 256, 0, stream>>>(intr, c2w, l2w, w1, cv1w, cv2w,
                                           mats, w1T, wB1a, wB1m, wB2);

    occ_token_kernel<<<NB * NCAM * NP, 256, 0, stream>>>(
        tokens, depth, ln_g, ln_b, w1T, b1, w2, b2, mats, volf, cntp);

    occ_norm_kernel<<<5000, 256, 0, stream>>>(volf, cntp, decn, mskp);

    const int CGRID = NB * GX * (GY / 4);   // 20000
    occ_conv_kernel<true><<<CGRID, 256, 0, stream>>>(decn, mskp, wB1a, wB1m, cv1b, staged2, st1);
    occ_bnfin_kernel<<<1, 16, 0, stream>>>(st1, bn1g, bn1b, bnp1);
    occ_bnact_kernel<<<5000, 256, 0, stream>>>(staged2, bnp1);

    occ_conv_kernel<false><<<CGRID, 256, 0, stream>>>(staged2, nullptr, wB2, nullptr, cv2b, staged3, st2);
    occ_bnfin_kernel<<<1, 16, 0, stream>>>(st2, bn2g, bn2b, bnp2);

    occ_conv3_kernel<<<5000, 256, 0, stream>>>(staged3, bnp2, cv3w, cv3b, outp);
}

// Round 4
// 256.080 us; speedup vs baseline: 9.4997x; 1.2234x over previous
//
#include <hip/hip_runtime.h>
#include <hip/hip_bf16.h>
#include <math.h>

// ---------------- problem constants ----------------
#define PATCH 14
#define HID   16
#define NCLS  20
#define GX    200
#define GY    200
#define GZ    16
#define NB    2
#define NCAM  6
#define PH    37
#define PW    37
#define NP    (PH*PW)
#define TD    768
#define IMH   518
#define IMW   518
#define PL    ((size_t)GX*GY*GZ)   // 640000 voxels per batch
#define EPSF  1e-5f

// padded conv layout: [b][px 0..201][py 0..201][pz 0..17] rows of 16 ch
#define PX 202
#define PY 202
#define PZ 18
#define PROWS_TOT (NB*PX*PY*PZ)    // 1,468,944 rows

// ---------------- workspace layout (float units) ----------------
#define OFF_VOL   ((size_t)0)            // volf [b][sp][16] fp32 (later reused as staged3 bf16)
#define OFF_CNT   ((size_t)20480000)
#define OFF_ST1   ((size_t)21760000)
#define OFF_ST2   ((size_t)21762048)
#define ZERO_F    ((size_t)21764096)     // zeroed every call up to here
#define OFF_MATS  ((size_t)21764096)     // 144
#define OFF_W1T   ((size_t)21764240)     // 12,288
#define OFF_WB1A  ((size_t)21776528)     // 14*64*8 bf16 = 3,584 f
#define OFF_WB1M  ((size_t)21780112)     // 64*8 bf16 = 256 f
#define OFF_WB2   ((size_t)21780368)     // 3,584 f
#define OFF_BN1   ((size_t)21783952)     // 32
#define OFF_BN2   ((size_t)21783984)     // 32
#define WS_FLOATS ((size_t)21784016)

// ---------------- d_out staging (bf16 units; dead before conv3 writes) ----------
#define DO_DECN ((size_t)0)                       // padded dec_in, 23,503,104
#define DO_MSK  ((size_t)23503104)                // padded mask rows, 1,468,944
#define DO_ST2  ((size_t)24972048)                // padded conv1 out, 23,503,104
                                                  // end 48,475,152 <= 51,200,000

typedef __attribute__((ext_vector_type(8))) short short8;
typedef __attribute__((ext_vector_type(4))) float floatx4;

__device__ __forceinline__ float gelu_exact(float x) {
    return 0.5f * x * (1.0f + erff(x * 0.70710678118654752f));
}
__device__ __forceinline__ unsigned short f2bf(float f) {
    __hip_bfloat16 h = __float2bfloat16(f);
    return __builtin_bit_cast(unsigned short, h);
}
__device__ __forceinline__ float bf2f(short u) {
    unsigned int b = ((unsigned int)(unsigned short)u) << 16;
    return __builtin_bit_cast(float, b);
}
__device__ __forceinline__ short8 zero8() {
    short8 z = {0,0,0,0,0,0,0,0};
    return z;
}

// ---------------- 3x3 / 4x4 inverse in double ----------------
__device__ void inv3d(const double* m, double* o) {
    double a=m[0],b=m[1],c=m[2],d=m[3],e=m[4],f=m[5],g=m[6],h=m[7],i=m[8];
    double A=e*i-f*h, B=-(d*i-f*g), C=d*h-e*g;
    double det=a*A+b*B+c*C, id=1.0/det;
    o[0]=A*id;            o[1]=-(b*i-c*h)*id;   o[2]=(b*f-c*e)*id;
    o[3]=B*id;            o[4]=(a*i-c*g)*id;    o[5]=-(a*f-c*d)*id;
    o[6]=C*id;            o[7]=-(a*h-b*g)*id;   o[8]=(a*e-b*d)*id;
}

__device__ void inv4d(const double* m, double* o) {
    double i0  =  m[5]*m[10]*m[15]-m[5]*m[11]*m[14]-m[9]*m[6]*m[15]+m[9]*m[7]*m[14]+m[13]*m[6]*m[11]-m[13]*m[7]*m[10];
    double i4  = -m[4]*m[10]*m[15]+m[4]*m[11]*m[14]+m[8]*m[6]*m[15]-m[8]*m[7]*m[14]-m[12]*m[6]*m[11]+m[12]*m[7]*m[10];
    double i8  =  m[4]*m[9]*m[15]-m[4]*m[11]*m[13]-m[8]*m[5]*m[15]+m[8]*m[7]*m[13]+m[12]*m[5]*m[11]-m[12]*m[7]*m[9];
    double i12 = -m[4]*m[9]*m[14]+m[4]*m[10]*m[13]+m[8]*m[5]*m[14]-m[8]*m[6]*m[13]-m[12]*m[5]*m[10]+m[12]*m[6]*m[9];
    double i1  = -m[1]*m[10]*m[15]+m[1]*m[11]*m[14]+m[9]*m[2]*m[15]-m[9]*m[3]*m[14]-m[13]*m[2]*m[11]+m[13]*m[3]*m[10];
    double i5  =  m[0]*m[10]*m[15]-m[0]*m[11]*m[14]-m[8]*m[2]*m[15]+m[8]*m[3]*m[14]+m[12]*m[2]*m[11]-m[12]*m[3]*m[10];
    double i9  = -m[0]*m[9]*m[15]+m[0]*m[11]*m[13]+m[8]*m[1]*m[15]-m[8]*m[3]*m[13]-m[12]*m[1]*m[11]+m[12]*m[3]*m[9];
    double i13 =  m[0]*m[9]*m[14]-m[0]*m[10]*m[13]-m[8]*m[1]*m[14]+m[8]*m[2]*m[13]+m[12]*m[1]*m[10]-m[12]*m[2]*m[9];
    double i2  =  m[1]*m[6]*m[15]-m[1]*m[7]*m[14]-m[5]*m[2]*m[15]+m[5]*m[3]*m[14]+m[13]*m[2]*m[7]-m[13]*m[3]*m[6];
    double i6  = -m[0]*m[6]*m[15]+m[0]*m[7]*m[14]+m[4]*m[2]*m[15]-m[4]*m[3]*m[14]-m[12]*m[2]*m[7]+m[12]*m[3]*m[6];
    double i10 =  m[0]*m[5]*m[15]-m[0]*m[7]*m[13]-m[4]*m[1]*m[15]+m[4]*m[3]*m[13]+m[12]*m[1]*m[7]-m[12]*m[3]*m[5];
    double i14 = -m[0]*m[5]*m[14]+m[0]*m[6]*m[13]+m[4]*m[1]*m[14]-m[4]*m[2]*m[13]-m[12]*m[1]*m[6]+m[12]*m[2]*m[5];
    double i3  = -m[1]*m[6]*m[11]+m[1]*m[7]*m[10]+m[5]*m[2]*m[11]-m[5]*m[3]*m[10]-m[9]*m[2]*m[7]+m[9]*m[3]*m[6];
    double i7  =  m[0]*m[6]*m[11]-m[0]*m[7]*m[10]-m[4]*m[2]*m[11]+m[4]*m[3]*m[10]+m[8]*m[2]*m[7]-m[8]*m[3]*m[6];
    double i11 = -m[0]*m[5]*m[11]+m[0]*m[7]*m[9]+m[4]*m[1]*m[11]-m[4]*m[3]*m[9]-m[8]*m[1]*m[7]+m[8]*m[3]*m[5];
    double i15 =  m[0]*m[5]*m[10]-m[0]*m[6]*m[9]-m[4]*m[1]*m[10]+m[4]*m[2]*m[9]+m[8]*m[1]*m[6]-m[8]*m[2]*m[5];
    double det = m[0]*i0+m[1]*i4+m[2]*i8+m[3]*i12;
    double id = 1.0/det;
    o[0]=i0*id; o[1]=i1*id; o[2]=i2*id; o[3]=i3*id;
    o[4]=i4*id; o[5]=i5*id; o[6]=i6*id; o[7]=i7*id;
    o[8]=i8*id; o[9]=i9*id; o[10]=i10*id; o[11]=i11*id;
    o[12]=i12*id; o[13]=i13*id; o[14]=i14*id; o[15]=i15*id;
}

// ---------------- precompute ----------------
__global__ void occ_prep_kernel(const float* __restrict__ intr, const float* __restrict__ c2w,
                                const float* __restrict__ l2w, const float* __restrict__ w1,
                                const float* __restrict__ cw1, const float* __restrict__ cw2,
                                float* __restrict__ mats, float* __restrict__ w1T,
                                __hip_bfloat16* __restrict__ wB1a, __hip_bfloat16* __restrict__ wB1m,
                                __hip_bfloat16* __restrict__ wB2)
{
    int t = threadIdx.x;
    if (t < NB * NCAM) {
        int b = t / NCAM;
        double K[9], Ki[9], L[16], Li[16], C[16], M[16], A[9];
        #pragma unroll
        for (int i = 0; i < 9; ++i) K[i] = (double)intr[t * 9 + i];
        inv3d(K, Ki);
        #pragma unroll
        for (int i = 0; i < 16; ++i) L[i] = (double)l2w[b * 16 + i];
        inv4d(L, Li);
        #pragma unroll
        for (int i = 0; i < 16; ++i) C[i] = (double)c2w[t * 16 + i];
        #pragma unroll
        for (int r = 0; r < 4; ++r)
            #pragma unroll
            for (int c = 0; c < 4; ++c) {
                double s = 0.0;
                #pragma unroll
                for (int k = 0; k < 4; ++k) s += Li[r * 4 + k] * C[k * 4 + c];
                M[r * 4 + c] = s;
            }
        #pragma unroll
        for (int r = 0; r < 3; ++r)
            #pragma unroll
            for (int c = 0; c < 3; ++c) {
                double s = 0.0;
                #pragma unroll
                for (int k = 0; k < 3; ++k) s += M[r * 4 + k] * Ki[k * 3 + c];
                A[r * 3 + c] = s;
            }
        #pragma unroll
        for (int i = 0; i < 9; ++i) mats[t * 12 + i] = (float)A[i];
        mats[t * 12 + 9]  = (float)M[3];
        mats[t * 12 + 10] = (float)M[7];
        mats[t * 12 + 11] = (float)M[11];
    }
    // w1 (768,16) -> w1T (16,768)
    for (int i = t; i < TD * HID; i += 256) {
        int d = i >> 4, j = i & 15;
        w1T[j * TD + d] = w1[i];
    }
    // conv1 main (16 vol channels): wB1a[t2][lane][8]; K packs 2 taps x 16 ch
    for (int i = t; i < 14 * 64 * 8; i += 256) {
        int t2 = i >> 9; int r = i & 511; int ln = r >> 3; int e = r & 7;
        int kg = ln >> 4;
        int tt = 2 * t2 + (kg >> 1);
        int ci = ((kg & 1) << 3) + e;
        int o = ln & 15;
        float val = (tt < 27) ? cw1[(o * 17 + ci) * 27 + tt] : 0.f;
        wB1a[i] = __float2bfloat16(val);
    }
    // conv1 mask channel (ci=16): wB1m[lane][8]; K slot = tap index
    for (int i = t; i < 64 * 8; i += 256) {
        int ln = i >> 3; int e = i & 7;
        int k = ((ln >> 4) << 3) + e;
        int o = ln & 15;
        float val = (k < 27) ? cw1[(o * 17 + 16) * 27 + k] : 0.f;
        wB1m[i] = __float2bfloat16(val);
    }
    // conv2: wB2[t2][lane][8]
    for (int i = t; i < 14 * 64 * 8; i += 256) {
        int t2 = i >> 9; int r = i & 511; int ln = r >> 3; int e = r & 7;
        int kg = ln >> 4;
        int tt = 2 * t2 + (kg >> 1);
        int ci = ((kg & 1) << 3) + e;
        int o = ln & 15;
        float val = (tt < 27) ? cw2[(o * 16 + ci) * 27 + tt] : 0.f;
        wB2[i] = __float2bfloat16(val);
    }
}

// ---------------- token: depth pool + LN + MLP + geometry + scatter ----------------
__global__ __launch_bounds__(256) void occ_token_kernel(
    const float* __restrict__ tokens, const float* __restrict__ depth,
    const float* __restrict__ ln_g, const float* __restrict__ ln_b,
    const float* __restrict__ w1T, const float* __restrict__ b1,
    const float* __restrict__ w2, const float* __restrict__ b2,
    const float* __restrict__ mats, float* __restrict__ vol, float* __restrict__ cnt)
{
    int blk = blockIdx.x;
    int p = blk % NP;
    int bc = blk / NP;
    int b = bc / NCAM;
    int gy = p / PW, gx = p % PW;
    int t = threadIdx.x;

    __shared__ float red[256];
    __shared__ float red2[256];
    __shared__ float xn[TD];
    __shared__ float h1[HID];
    __shared__ float s_dm;

    float dv = 0.f;
    if (t < PATCH * PATCH) {
        int py = t / PATCH, px = t % PATCH;
        int row = gy * PATCH + py, col = gx * PATCH + px;
        dv = depth[((size_t)bc * IMH + row) * IMW + col];
    }
    red[t] = dv;
    __syncthreads();
    #pragma unroll
    for (int off = 128; off > 0; off >>= 1) {
        if (t < off) red[t] += red[t + off];
        __syncthreads();
    }
    if (t == 0) s_dm = red[0] * (1.0f / 196.0f);

    const float* tok = tokens + ((size_t)bc * NP + p) * TD;
    float x0 = tok[t], x1 = tok[t + 256], x2 = tok[t + 512];
    red[t]  = x0 + x1 + x2;
    red2[t] = x0 * x0 + x1 * x1 + x2 * x2;
    __syncthreads();
    #pragma unroll
    for (int off = 128; off > 0; off >>= 1) {
        if (t < off) { red[t] += red[t + off]; red2[t] += red2[t + off]; }
        __syncthreads();
    }
    float mu  = red[0] * (1.0f / (float)TD);
    float var = red2[0] * (1.0f / (float)TD) - mu * mu;
    float rs  = rsqrtf(var + EPSF);
    xn[t]       = (x0 - mu) * rs * ln_g[t]       + ln_b[t];
    xn[t + 256] = (x1 - mu) * rs * ln_g[t + 256] + ln_b[t + 256];
    xn[t + 512] = (x2 - mu) * rs * ln_g[t + 512] + ln_b[t + 512];
    __syncthreads();

    int j = t >> 4, sl = t & 15;
    float acc = 0.f;
    #pragma unroll
    for (int i = 0; i < TD / 16; ++i) {
        int d = sl + (i << 4);
        acc = fmaf(xn[d], w1T[j * TD + d], acc);
    }
    acc += __shfl_down(acc, 8, 16);
    acc += __shfl_down(acc, 4, 16);
    acc += __shfl_down(acc, 2, 16);
    acc += __shfl_down(acc, 1, 16);
    if (sl == 0) h1[j] = gelu_exact(acc + b1[j]);
    __syncthreads();

    if (t < HID) {
        const float* M = mats + bc * 12;
        float dmr = s_dm;
        float dm = fmaxf(dmr, 0.f);
        float u = (gx + 0.5f) * (float)PATCH;
        float v = (gy + 0.5f) * (float)PATCH;
        float lx = (M[0] * u + M[1] * v + M[2]) * dm + M[9];
        float ly = (M[3] * u + M[4] * v + M[5]) * dm + M[10];
        float lz = (M[6] * u + M[7] * v + M[8]) * dm + M[11];
        int cx = (int)floorf((lx + 40.0f) / 0.4f);
        int cy = (int)floorf((ly + 40.0f) / 0.4f);
        int cz = (int)floorf((lz + 1.0f) / 0.4f);
        bool valid = (dmr > 0.001f) &&
                     (unsigned)cx < (unsigned)GX &&
                     (unsigned)cy < (unsigned)GY &&
                     (unsigned)cz < (unsigned)GZ;
        float h2 = b2[t];
        #pragma unroll
        for (int jj = 0; jj < HID; ++jj) h2 = fmaf(h1[jj], w2[jj * HID + t], h2);
        if (valid) {
            size_t sp = ((size_t)cx * GY + cy) * GZ + cz;
            atomicAdd(&vol[((size_t)b * PL + sp) * 16 + t], h2);
            if (t == 0) atomicAdd(&cnt[(size_t)b * PL + sp], 1.0f);
        }
    }
}

// ------- norm+halo: vol/cnt -> padded bf16 dec_in + mask; zero all halos -------
__global__ __launch_bounds__(256) void occ_norm_kernel(
    const float* __restrict__ volf, const float* __restrict__ cnt,
    __hip_bfloat16* __restrict__ decn, __hip_bfloat16* __restrict__ msk,
    __hip_bfloat16* __restrict__ st2)
{
    size_t i = (size_t)blockIdx.x * 256 + threadIdx.x;   // padded row index
    if (i >= (size_t)PROWS_TOT) return;
    int pz = (int)(i % PZ);
    size_t t1 = i / PZ;
    int py = (int)(t1 % PY);
    size_t t2 = t1 / PY;
    int px = (int)(t2 % PX);
    int b  = (int)(t2 / PX);
    bool interior = (px >= 1) && (px <= GX) && (py >= 1) && (py <= GY) &&
                    (pz >= 1) && (pz <= GZ);
    short8* dp = (short8*)(decn + i * 16);
    if (interior) {
        size_t vi = (size_t)b * PL + (((size_t)(px - 1) * GY + (py - 1)) * GZ + (pz - 1));
        float cn = cnt[vi];
        float inv = 1.0f / fmaxf(cn, 1.0f);
        const float4* vp = (const float4*)(volf + vi * 16);
        float4 f0 = vp[0], f1 = vp[1], f2 = vp[2], f3 = vp[3];
        short8 o0, o1;
        o0[0] = (short)f2bf(f0.x * inv); o0[1] = (short)f2bf(f0.y * inv);
        o0[2] = (short)f2bf(f0.z * inv); o0[3] = (short)f2bf(f0.w * inv);
        o0[4] = (short)f2bf(f1.x * inv); o0[5] = (short)f2bf(f1.y * inv);
        o0[6] = (short)f2bf(f1.z * inv); o0[7] = (short)f2bf(f1.w * inv);
        o1[0] = (short)f2bf(f2.x * inv); o1[1] = (short)f2bf(f2.y * inv);
        o1[2] = (short)f2bf(f2.z * inv); o1[3] = (short)f2bf(f2.w * inv);
        o1[4] = (short)f2bf(f3.x * inv); o1[5] = (short)f2bf(f3.y * inv);
        o1[6] = (short)f2bf(f3.z * inv); o1[7] = (short)f2bf(f3.w * inv);
        dp[0] = o0; dp[1] = o1;
        msk[i] = __float2bfloat16(cn > 0.f ? 1.f : 0.f);
    } else {
        dp[0] = zero8(); dp[1] = zero8();
        msk[i] = __float2bfloat16(0.f);
        short8* sp2 = (short8*)(st2 + i * 16);
        sp2[0] = zero8(); sp2[1] = zero8();
    }
}

// ------- conv3d 3x3x3 via MFMA on padded layout; 4 output columns per wave -------
template <bool MASK, bool OUTPAD>
__global__ __launch_bounds__(256, 2) void occ_conv_kernel(
    const __hip_bfloat16* __restrict__ in, const __hip_bfloat16* __restrict__ msk,
    const __hip_bfloat16* __restrict__ wBa, const __hip_bfloat16* __restrict__ wBm,
    const float* __restrict__ bias, __hip_bfloat16* __restrict__ out,
    float* __restrict__ stats)
{
    // 5000 blocks = NB * (GX/2) * (GY/8); XCD-chunked swizzle (5000 = 8*625)
    int bid = blockIdx.x;
    int blk = (bid & 7) * 625 + (bid >> 3);
    int b   = blk / 2500;
    int rem = blk % 2500;
    int x0  = (rem / 25) * 2;
    int y0  = (rem % 25) * 8;
    int tid = threadIdx.x;
    int w = tid >> 6, lane = tid & 63;
    int wx = x0 + (w >> 1);
    int wy = y0 + (w & 1) * 4;
    int z = lane & 15, kg = lane >> 4;
    int ci0 = (kg & 1) << 3;
    bool halfsel = kg >= 2;

    __shared__ unsigned short smsk[4 * 10 * 18];
    if constexpr (MASK) {
        for (int ii = tid; ii < 720; ii += 256) {
            int dx = ii / 180; int r = ii % 180; int dy = r / 18; int dz = r % 18;
            smsk[ii] = *(const unsigned short*)(msk +
                (size_t)(((b * PX + x0 + dx) * PY) + (y0 + dy)) * PZ + dz);
        }
        __syncthreads();
    }

    // preload weight fragments (loop-invariant)
    const short8* wp = (const short8*)wBa;
    short8 wreg[14];
    #pragma unroll
    for (int t2 = 0; t2 < 14; ++t2) wreg[t2] = wp[t2 * 64 + lane];

    float bo = bias[lane & 15];
    floatx4 acc[4];
    #pragma unroll
    for (int j = 0; j < 4; ++j) { acc[j][0]=bo; acc[j][1]=bo; acc[j][2]=bo; acc[j][3]=bo; }

    // column bases (32-bit row indices into padded layout)
    int cb[3][3];
    #pragma unroll
    for (int kd = 0; kd < 3; ++kd)
        #pragma unroll
        for (int kh = 0; kh < 3; ++kh)
            cb[kd][kh] = (((b * PX + wx + kd) * PY) + (wy + kh)) * PZ;

    #pragma unroll
    for (int t2 = 0; t2 < 14; ++t2) {
        const int ta = 2 * t2;
        const int tb = (2 * t2 + 1 > 26) ? 26 : 2 * t2 + 1;
        const int kda = ta / 9, kha = (ta / 3) % 3, kwa = ta % 3;
        const int kdb = tb / 9, khb = (tb / 3) % 3, kwb = tb % 3;
        int offA = cb[kda][kha] + z + kwa;
        int offB = cb[kdb][khb] + z + kwb;
        int off = halfsel ? offB : offA;
        #pragma unroll
        for (int j = 0; j < 4; ++j) {
            short8 a = *(const short8*)(in + (size_t)(off + j * PZ) * 16 + ci0);
            acc[j] = __builtin_amdgcn_mfma_f32_16x16x32_bf16(a, wreg[t2], acc[j], 0, 0, 0);
        }
    }

    if constexpr (MASK) {
        int dxl = wx - x0;          // 0 or 1
        int dyl = wy - y0;          // 0 or 4
        int base8[8];
        #pragma unroll
        for (int e = 0; e < 8; ++e) {
            int tap = kg * 8 + e;
            int kd = tap / 9;
            int rm = tap - kd * 9;
            int kh = rm / 3;
            int kw = rm - kh * 3;
            int idx = (dxl + kd) * 180 + (dyl + kh) * 18 + z + kw;
            base8[e] = (tap < 27) ? idx : 0;    // weight is 0 for tap>=27
        }
        short8 wm = ((const short8*)wBm)[lane];
        #pragma unroll
        for (int j = 0; j < 4; ++j) {
            short8 am;
            #pragma unroll
            for (int e = 0; e < 8; ++e) am[e] = (short)smsk[base8[e] + j * 18];
            acc[j] = __builtin_amdgcn_mfma_f32_16x16x32_bf16(am, wm, acc[j], 0, 0, 0);
        }
    }

    // store; D: row z' = kg*4+r, col o = lane&15
    int o = lane & 15;
    #pragma unroll
    for (int j = 0; j < 4; ++j) {
        size_t rowbase;
        if constexpr (OUTPAD)
            rowbase = (size_t)(((b * PX + wx + 1) * PY) + (wy + j + 1)) * PZ + 1;
        else
            rowbase = (size_t)b * PL + ((size_t)wx * GY + (wy + j)) * GZ;
        #pragma unroll
        for (int r = 0; r < 4; ++r)
            out[(rowbase + kg * 4 + r) * 16 + o] = __float2bfloat16(acc[j][r]);
    }

    // fused BN stats (per-channel sum / sumsq)
    float s = 0.f, sq = 0.f;
    #pragma unroll
    for (int j = 0; j < 4; ++j)
        #pragma unroll
        for (int r = 0; r < 4; ++r) { float v = acc[j][r]; s += v; sq += v * v; }
    s  += __shfl_xor(s, 16);  s  += __shfl_xor(s, 32);
    sq += __shfl_xor(sq, 16); sq += __shfl_xor(sq, 32);
    __shared__ float sred[4][32];
    if (lane < 16) { sred[w][lane] = s; sred[w][16 + lane] = sq; }
    __syncthreads();
    if (tid < 32) {
        float v2 = sred[0][tid] + sred[1][tid] + sred[2][tid] + sred[3][tid];
        atomicAdd(&stats[(size_t)(blockIdx.x & 63) * 32 + tid], v2);
    }
}

// ---------------- BN finalize ----------------
__global__ void occ_bnfin_kernel(const float* __restrict__ stats, const float* __restrict__ g,
                                 const float* __restrict__ bb, float* __restrict__ bn)
{
    int c = threadIdx.x;
    if (c >= 16) return;
    float s = 0.f, sq = 0.f;
    for (int k = 0; k < 64; ++k) { s += stats[k * 32 + c]; sq += stats[k * 32 + 16 + c]; }
    const float N = (float)(NB * PL);
    float mean = s / N;
    float var = sq / N - mean * mean;
    float scale = g[c] * rsqrtf(var + EPSF);
    bn[c] = scale;
    bn[16 + c] = bb[c] - mean * scale;
}

// ------- BN affine + GELU in-place on padded buffer, interior rows only -------
__global__ __launch_bounds__(256) void occ_bnact_kernel(__hip_bfloat16* __restrict__ buf,
                                                        const float* __restrict__ bn)
{
    __shared__ float sc[16], sh[16];
    int t = threadIdx.x;
    if (t < 16) sc[t] = bn[t];
    else if (t < 32) sh[t - 16] = bn[t];
    __syncthreads();
    size_t i = (size_t)blockIdx.x * 256 + t;      // interior voxel index < NB*PL
    int b = (int)(i / PL);
    size_t sp = i % PL;
    int x = (int)(sp / (GY * GZ));
    int r2 = (int)(sp % (GY * GZ));
    int y = r2 / GZ, z = r2 & 15;
    size_t pidx = (size_t)(((b * PX + x + 1) * PY) + (y + 1)) * PZ + (z + 1);
    short8* p = (short8*)(buf + pidx * 16);
    short8 v0 = p[0], v1 = p[1];
    #pragma unroll
    for (int e = 0; e < 8; ++e) {
        float a0 = gelu_exact(fmaf(bf2f(v0[e]), sc[e],     sh[e]));
        float a1 = gelu_exact(fmaf(bf2f(v1[e]), sc[8 + e], sh[8 + e]));
        v0[e] = (short)f2bf(a0);
        v1[e] = (short)f2bf(a1);
    }
    p[0] = v0; p[1] = v1;
}

// ---------------- conv3 1x1x1 (16 -> 20) with fused bn2+GELU ----------------
__global__ __launch_bounds__(256) void occ_conv3_kernel(const __hip_bfloat16* __restrict__ act,
                                                        const float* __restrict__ bn,
                                                        const float* __restrict__ w3,
                                                        const float* __restrict__ b3,
                                                        float* __restrict__ out)
{
    __shared__ float w[NCLS * 16];
    __shared__ float bb[NCLS];
    __shared__ float sc[16], sh[16];
    int t = threadIdx.x;
    for (int i = t; i < NCLS * 16; i += 256) w[i] = w3[i];
    if (t < NCLS) bb[t] = b3[t];
    if (t >= 32 && t < 48) sc[t - 32] = bn[t - 32];
    if (t >= 48 && t < 64) sh[t - 48] = bn[t - 32];
    __syncthreads();
    size_t i = (size_t)blockIdx.x * 256 + t;      // < NB*PL
    size_t b = i / PL, sp = i % PL;
    const short8* p = (const short8*)(act + i * 16);
    short8 v0 = p[0], v1 = p[1];
    float vi[16];
    #pragma unroll
    for (int e = 0; e < 8; ++e) {
        vi[e]     = gelu_exact(fmaf(bf2f(v0[e]), sc[e],     sh[e]));
        vi[8 + e] = gelu_exact(fmaf(bf2f(v1[e]), sc[8 + e], sh[8 + e]));
    }
    float* op = out + b * NCLS * PL + sp;
    #pragma unroll
    for (int cls = 0; cls < NCLS; ++cls) {
        float a = bb[cls];
        #pragma unroll
        for (int ci = 0; ci < 16; ++ci) a = fmaf(vi[ci], w[cls * 16 + ci], a);
        op[(size_t)cls * PL] = a;
    }
}

// ---------------- launch ----------------
extern "C" void kernel_launch(void* const* d_in, const int* in_sizes, int n_in,
                              void* d_out, int out_size, void* d_ws, size_t ws_size,
                              hipStream_t stream)
{
    const float* tokens = (const float*)d_in[0];
    const float* depth  = (const float*)d_in[1];
    const float* intr   = (const float*)d_in[2];
    const float* c2w    = (const float*)d_in[3];
    const float* l2w    = (const float*)d_in[4];
    const float* ln_g   = (const float*)d_in[5];
    const float* ln_b   = (const float*)d_in[6];
    const float* w1     = (const float*)d_in[7];
    const float* b1     = (const float*)d_in[8];
    const float* w2     = (const float*)d_in[9];
    const float* b2     = (const float*)d_in[10];
    const float* cv1w   = (const float*)d_in[11];
    const float* cv1b   = (const float*)d_in[12];
    const float* bn1g   = (const float*)d_in[13];
    const float* bn1b   = (const float*)d_in[14];
    const float* cv2w   = (const float*)d_in[15];
    const float* cv2b   = (const float*)d_in[16];
    const float* bn2g   = (const float*)d_in[17];
    const float* bn2b   = (const float*)d_in[18];
    const float* cv3w   = (const float*)d_in[19];
    const float* cv3b   = (const float*)d_in[20];

    if (ws_size < WS_FLOATS * sizeof(float)) return;

    float* ws   = (float*)d_ws;
    float* volf = ws + OFF_VOL;
    float* cntp = ws + OFF_CNT;
    float* st1  = ws + OFF_ST1;
    float* st2s = ws + OFF_ST2;
    float* mats = ws + OFF_MATS;
    float* w1T  = ws + OFF_W1T;
    __hip_bfloat16* wB1a = (__hip_bfloat16*)(ws + OFF_WB1A);
    __hip_bfloat16* wB1m = (__hip_bfloat16*)(ws + OFF_WB1M);
    __hip_bfloat16* wB2  = (__hip_bfloat16*)(ws + OFF_WB2);
    float* bnp1 = ws + OFF_BN1;
    float* bnp2 = ws + OFF_BN2;

    __hip_bfloat16* ob      = (__hip_bfloat16*)d_out;
    __hip_bfloat16* decn    = ob + DO_DECN;     // padded
    __hip_bfloat16* mskp    = ob + DO_MSK;      // padded
    __hip_bfloat16* staged2 = ob + DO_ST2;      // padded conv1 out
    __hip_bfloat16* staged3 = (__hip_bfloat16*)(ws + OFF_VOL);  // unpadded conv2 out
    float* outp = (float*)d_out;

    hipMemsetAsync(ws, 0, ZERO_F * sizeof(float), stream);

    occ_prep_kernel<<<1, 256, 0, stream>>>(intr, c2w, l2w, w1, cv1w, cv2w,
                                           mats, w1T, wB1a, wB1m, wB2);

    occ_token_kernel<<<NB * NCAM * NP, 256, 0, stream>>>(
        tokens, depth, ln_g, ln_b, w1T, b1, w2, b2, mats, volf, cntp);

    occ_norm_kernel<<<(PROWS_TOT + 255) / 256, 256, 0, stream>>>(volf, cntp, decn, mskp, staged2);

    const int CGRID = NB * (GX / 2) * (GY / 8);   // 5000
    occ_conv_kernel<true, true><<<CGRID, 256, 0, stream>>>(decn, mskp, wB1a, wB1m, cv1b, staged2, st1);
    occ_bnfin_kernel<<<1, 16, 0, stream>>>(st1, bn1g, bn1b, bnp1);
    occ_bnact_kernel<<<5000, 256, 0, stream>>>(staged2, bnp1);

    occ_conv_kernel<false, false><<<CGRID, 256, 0, stream>>>(staged2, nullptr, wB2, nullptr, cv2b, staged3, st2s);
    occ_bnfin_kernel<<<1, 16, 0, stream>>>(st2s, bn2g, bn2b, bnp2);

    occ_conv3_kernel<<<5000, 256, 0, stream>>>(staged3, bnp2, cv3w, cv3b, outp);
}

// Round 5
// 229.982 us; speedup vs baseline: 10.5776x; 1.1135x over previous
//
#include <hip/hip_runtime.h>
#include <hip/hip_bf16.h>
#include <math.h>

// ---------------- problem constants ----------------
#define PATCH 14
#define HID   16
#define NCLS  20
#define GX    200
#define GY    200
#define GZ    16
#define NB    2
#define NCAM  6
#define PH    37
#define PW    37
#define NP    (PH*PW)
#define TD    768
#define IMH   518
#define IMW   518
#define PL    ((size_t)GX*GY*GZ)   // 640000 voxels per batch
#define EPSF  1e-5f

// padded conv layout: [b][px 0..201][py 0..201][pz 0..17] rows of 16 ch
#define PX 202
#define PY 202
#define PZ 18
#define PROWS_TOT (NB*PX*PY*PZ)    // 1,468,944 rows

// ---------------- workspace layout (float units) ----------------
#define OFF_VOL   ((size_t)0)            // volf [b][sp][16] fp32 (later reused as staged3 bf16)
#define OFF_CNT   ((size_t)20480000)
#define OFF_ST1   ((size_t)21760000)
#define OFF_ST2   ((size_t)21762048)
#define ZERO_F    ((size_t)21764096)     // zeroed every call up to here
#define OFF_MATS  ((size_t)21764096)     // 144
#define OFF_W1L   ((size_t)21764240)     // 12,288 bf16 = 6,144 f
#define OFF_WB1A  ((size_t)21776528)     // 14*64*8 bf16 = 3,584 f
#define OFF_WB1M  ((size_t)21780112)     // 64*8 bf16 = 256 f
#define OFF_WB2   ((size_t)21780368)     // 3,584 f
#define OFF_BN1   ((size_t)21783952)     // 32
#define OFF_BN2   ((size_t)21783984)     // 32
#define WS_FLOATS ((size_t)21784016)

// ---------------- d_out staging (bf16 units; dead before conv3 writes) ----------
#define DO_DECN ((size_t)0)                       // padded dec_in, 23,503,104
#define DO_MSK  ((size_t)23503104)                // padded mask rows, 1,468,944
#define DO_ST2  ((size_t)24972048)                // padded conv1 out, 23,503,104
                                                  // end 48,475,152 <= 51,200,000

typedef __attribute__((ext_vector_type(8))) short short8;
typedef __attribute__((ext_vector_type(4))) float floatx4;

__device__ __forceinline__ float gelu_exact(float x) {
    return 0.5f * x * (1.0f + erff(x * 0.70710678118654752f));
}
__device__ __forceinline__ unsigned short f2bf(float f) {
    __hip_bfloat16 h = __float2bfloat16(f);
    return __builtin_bit_cast(unsigned short, h);
}
__device__ __forceinline__ float bf2f(short u) {
    unsigned int b = ((unsigned int)(unsigned short)u) << 16;
    return __builtin_bit_cast(float, b);
}
__device__ __forceinline__ short8 zero8() {
    short8 z = {0,0,0,0,0,0,0,0};
    return z;
}

// ---------------- 3x3 / 4x4 inverse in double ----------------
__device__ void inv3d(const double* m, double* o) {
    double a=m[0],b=m[1],c=m[2],d=m[3],e=m[4],f=m[5],g=m[6],h=m[7],i=m[8];
    double A=e*i-f*h, B=-(d*i-f*g), C=d*h-e*g;
    double det=a*A+b*B+c*C, id=1.0/det;
    o[0]=A*id;            o[1]=-(b*i-c*h)*id;   o[2]=(b*f-c*e)*id;
    o[3]=B*id;            o[4]=(a*i-c*g)*id;    o[5]=-(a*f-c*d)*id;
    o[6]=C*id;            o[7]=-(a*h-b*g)*id;   o[8]=(a*e-b*d)*id;
}

__device__ void inv4d(const double* m, double* o) {
    double i0  =  m[5]*m[10]*m[15]-m[5]*m[11]*m[14]-m[9]*m[6]*m[15]+m[9]*m[7]*m[14]+m[13]*m[6]*m[11]-m[13]*m[7]*m[10];
    double i4  = -m[4]*m[10]*m[15]+m[4]*m[11]*m[14]+m[8]*m[6]*m[15]-m[8]*m[7]*m[14]-m[12]*m[6]*m[11]+m[12]*m[7]*m[10];
    double i8  =  m[4]*m[9]*m[15]-m[4]*m[11]*m[13]-m[8]*m[5]*m[15]+m[8]*m[7]*m[13]+m[12]*m[5]*m[11]-m[12]*m[7]*m[9];
    double i12 = -m[4]*m[9]*m[14]+m[4]*m[10]*m[13]+m[8]*m[5]*m[14]-m[8]*m[6]*m[13]-m[12]*m[5]*m[10]+m[12]*m[6]*m[9];
    double i1  = -m[1]*m[10]*m[15]+m[1]*m[11]*m[14]+m[9]*m[2]*m[15]-m[9]*m[3]*m[14]-m[13]*m[2]*m[11]+m[13]*m[3]*m[10];
    double i5  =  m[0]*m[10]*m[15]-m[0]*m[11]*m[14]-m[8]*m[2]*m[15]+m[8]*m[3]*m[14]+m[12]*m[2]*m[11]-m[12]*m[3]*m[10];
    double i9  = -m[0]*m[9]*m[15]+m[0]*m[11]*m[13]+m[8]*m[1]*m[15]-m[8]*m[3]*m[13]-m[12]*m[1]*m[11]+m[12]*m[3]*m[9];
    double i13 =  m[0]*m[9]*m[14]-m[0]*m[10]*m[13]-m[8]*m[1]*m[14]+m[8]*m[2]*m[13]+m[12]*m[1]*m[10]-m[12]*m[2]*m[9];
    double i2  =  m[1]*m[6]*m[15]-m[1]*m[7]*m[14]-m[5]*m[2]*m[15]+m[5]*m[3]*m[14]+m[13]*m[2]*m[7]-m[13]*m[3]*m[6];
    double i6  = -m[0]*m[6]*m[15]+m[0]*m[7]*m[14]+m[4]*m[2]*m[15]-m[4]*m[3]*m[14]-m[12]*m[2]*m[7]+m[12]*m[3]*m[6];
    double i10 =  m[0]*m[5]*m[15]-m[0]*m[7]*m[13]-m[4]*m[1]*m[15]+m[4]*m[3]*m[13]+m[12]*m[1]*m[7]-m[12]*m[3]*m[5];
    double i14 = -m[0]*m[5]*m[14]+m[0]*m[6]*m[13]+m[4]*m[1]*m[14]-m[4]*m[2]*m[13]-m[12]*m[1]*m[6]+m[12]*m[2]*m[5];
    double i3  = -m[1]*m[6]*m[11]+m[1]*m[7]*m[10]+m[5]*m[2]*m[11]-m[5]*m[3]*m[10]-m[9]*m[2]*m[7]+m[9]*m[3]*m[6];
    double i7  =  m[0]*m[6]*m[11]-m[0]*m[7]*m[10]-m[4]*m[2]*m[11]+m[4]*m[3]*m[10]+m[8]*m[2]*m[7]-m[8]*m[3]*m[6];
    double i11 = -m[0]*m[5]*m[11]+m[0]*m[7]*m[9]+m[4]*m[1]*m[11]-m[4]*m[3]*m[9]-m[8]*m[1]*m[7]+m[8]*m[3]*m[5];
    double i15 =  m[0]*m[5]*m[10]-m[0]*m[6]*m[9]-m[4]*m[1]*m[10]+m[4]*m[2]*m[9]+m[8]*m[1]*m[6]-m[8]*m[2]*m[5];
    double det = m[0]*i0+m[1]*i4+m[2]*i8+m[3]*i12;
    double id = 1.0/det;
    o[0]=i0*id; o[1]=i1*id; o[2]=i2*id; o[3]=i3*id;
    o[4]=i4*id; o[5]=i5*id; o[6]=i6*id; o[7]=i7*id;
    o[8]=i8*id; o[9]=i9*id; o[10]=i10*id; o[11]=i11*id;
    o[12]=i12*id; o[13]=i13*id; o[14]=i14*id; o[15]=i15*id;
}

// ---------------- precompute ----------------
__global__ void occ_prep_kernel(const float* __restrict__ intr, const float* __restrict__ c2w,
                                const float* __restrict__ l2w, const float* __restrict__ w1,
                                const float* __restrict__ cw1, const float* __restrict__ cw2,
                                float* __restrict__ mats, __hip_bfloat16* __restrict__ w1L,
                                __hip_bfloat16* __restrict__ wB1a, __hip_bfloat16* __restrict__ wB1m,
                                __hip_bfloat16* __restrict__ wB2)
{
    int t = threadIdx.x;
    if (t < NB * NCAM) {
        int b = t / NCAM;
        double K[9], Ki[9], L[16], Li[16], C[16], M[16], A[9];
        #pragma unroll
        for (int i = 0; i < 9; ++i) K[i] = (double)intr[t * 9 + i];
        inv3d(K, Ki);
        #pragma unroll
        for (int i = 0; i < 16; ++i) L[i] = (double)l2w[b * 16 + i];
        inv4d(L, Li);
        #pragma unroll
        for (int i = 0; i < 16; ++i) C[i] = (double)c2w[t * 16 + i];
        #pragma unroll
        for (int r = 0; r < 4; ++r)
            #pragma unroll
            for (int c = 0; c < 4; ++c) {
                double s = 0.0;
                #pragma unroll
                for (int k = 0; k < 4; ++k) s += Li[r * 4 + k] * C[k * 4 + c];
                M[r * 4 + c] = s;
            }
        #pragma unroll
        for (int r = 0; r < 3; ++r)
            #pragma unroll
            for (int c = 0; c < 3; ++c) {
                double s = 0.0;
                #pragma unroll
                for (int k = 0; k < 3; ++k) s += M[r * 4 + k] * Ki[k * 3 + c];
                A[r * 3 + c] = s;
            }
        #pragma unroll
        for (int i = 0; i < 9; ++i) mats[t * 12 + i] = (float)A[i];
        mats[t * 12 + 9]  = (float)M[3];
        mats[t * 12 + 10] = (float)M[7];
        mats[t * 12 + 11] = (float)M[11];
    }
    // w1 (768,16) -> lane-major bf16: w1L[l*192 + r*16 + j] = w1[(12l+r)*16 + j]
    for (int i = t; i < TD * HID; i += 256) {
        int l = i / 192, rr = i % 192;
        int r = rr >> 4, j = rr & 15;
        w1L[i] = __float2bfloat16(w1[(12 * l + r) * 16 + j]);
    }
    // conv1 main (16 vol channels): wB1a[t2][lane][8]; K packs 2 taps x 16 ch
    for (int i = t; i < 14 * 64 * 8; i += 256) {
        int t2 = i >> 9; int r = i & 511; int ln = r >> 3; int e = r & 7;
        int kg = ln >> 4;
        int tt = 2 * t2 + (kg >> 1);
        int ci = ((kg & 1) << 3) + e;
        int o = ln & 15;
        float val = (tt < 27) ? cw1[(o * 17 + ci) * 27 + tt] : 0.f;
        wB1a[i] = __float2bfloat16(val);
    }
    // conv1 mask channel (ci=16): wB1m[lane][8]; K slot = tap index
    for (int i = t; i < 64 * 8; i += 256) {
        int ln = i >> 3; int e = i & 7;
        int k = ((ln >> 4) << 3) + e;
        int o = ln & 15;
        float val = (k < 27) ? cw1[(o * 17 + 16) * 27 + k] : 0.f;
        wB1m[i] = __float2bfloat16(val);
    }
    // conv2: wB2[t2][lane][8]
    for (int i = t; i < 14 * 64 * 8; i += 256) {
        int t2 = i >> 9; int r = i & 511; int ln = r >> 3; int e = r & 7;
        int kg = ln >> 4;
        int tt = 2 * t2 + (kg >> 1);
        int ci = ((kg & 1) << 3) + e;
        int o = ln & 15;
        float val = (tt < 27) ? cw2[(o * 16 + ci) * 27 + tt] : 0.f;
        wB2[i] = __float2bfloat16(val);
    }
}

// ---------------- token: one WAVE per token, zero barriers ----------------
__global__ __launch_bounds__(256) void occ_token_kernel(
    const float* __restrict__ tokens, const float* __restrict__ depth,
    const float* __restrict__ ln_g, const float* __restrict__ ln_b,
    const __hip_bfloat16* __restrict__ w1L, const float* __restrict__ b1,
    const float* __restrict__ w2, const float* __restrict__ b2,
    const float* __restrict__ mats, float* __restrict__ vol, float* __restrict__ cnt)
{
    int tid = threadIdx.x;
    int l = tid & 63;
    int g = blockIdx.x * 4 + (tid >> 6);        // token id, exactly 16428 total
    int bc = g / NP;
    int p  = g - bc * NP;
    int b  = bc / NCAM;
    int gy = p / PW, gx = p - gy * PW;

    // --- depth patch partial (196 px, 3/lane + tail on lanes 0-3) ---
    float dsum = 0.f;
    const float* dbase = depth + (size_t)bc * (IMH * IMW);
    int rbase = gy * PATCH, cbase = gx * PATCH;
    #pragma unroll
    for (int i = 0; i < 3; ++i) {
        int idx = l + 64 * i;
        int py = idx / 14;
        int px = idx - py * 14;
        dsum += dbase[(size_t)(rbase + py) * IMW + (cbase + px)];
    }
    if (l < 4)
        dsum += dbase[(size_t)(rbase + 13) * IMW + (cbase + 10 + l)];

    // --- token slice: 12 contiguous floats per lane ---
    const float* tok = tokens + (size_t)g * TD + l * 12;
    float x[12];
    *(float4*)(x + 0) = *(const float4*)(tok + 0);
    *(float4*)(x + 4) = *(const float4*)(tok + 4);
    *(float4*)(x + 8) = *(const float4*)(tok + 8);
    float s = 0.f, sq = 0.f;
    #pragma unroll
    for (int r = 0; r < 12; ++r) { s += x[r]; sq += x[r] * x[r]; }

    // --- joint wave reduce (s, sq, dsum) ---
    #pragma unroll
    for (int m = 1; m <= 32; m <<= 1) {
        s    += __shfl_xor(s, m);
        sq   += __shfl_xor(sq, m);
        dsum += __shfl_xor(dsum, m);
    }
    float mu  = s * (1.0f / (float)TD);
    float var = sq * (1.0f / (float)TD) - mu * mu;
    float rs  = rsqrtf(var + EPSF);
    float dmr = dsum * (1.0f / 196.0f);

    // --- LN affine on lane's 12 elems ---
    float gg[12], bb[12];
    *(float4*)(gg + 0) = *(const float4*)(ln_g + l * 12 + 0);
    *(float4*)(gg + 4) = *(const float4*)(ln_g + l * 12 + 4);
    *(float4*)(gg + 8) = *(const float4*)(ln_g + l * 12 + 8);
    *(float4*)(bb + 0) = *(const float4*)(ln_b + l * 12 + 0);
    *(float4*)(bb + 4) = *(const float4*)(ln_b + l * 12 + 4);
    *(float4*)(bb + 8) = *(const float4*)(ln_b + l * 12 + 8);
    #pragma unroll
    for (int r = 0; r < 12; ++r) x[r] = (x[r] - mu) * rs * gg[r] + bb[r];

    // --- partials vs lane-major bf16 w1 (L1-resident 24.6 KB) ---
    float part[16];
    #pragma unroll
    for (int j = 0; j < 16; ++j) part[j] = 0.f;
    const short8* wrow = (const short8*)(w1L + l * 192);
    #pragma unroll
    for (int r = 0; r < 12; ++r) {
        short8 wa = wrow[2 * r], wb = wrow[2 * r + 1];
        float xv = x[r];
        #pragma unroll
        for (int e = 0; e < 8; ++e) {
            part[e]     = fmaf(xv, bf2f(wa[e]), part[e]);
            part[8 + e] = fmaf(xv, bf2f(wb[e]), part[8 + e]);
        }
    }

    // --- vector-halving butterfly: lane ends with h_raw[j = l&15] ---
    float c8[8];
    {
        int bit = l & 1;
        #pragma unroll
        for (int i = 0; i < 8; ++i) {
            float a = part[2 * i], bz = part[2 * i + 1];
            float send = bit ? a : bz;
            float recv = __shfl_xor(send, 1);
            c8[i] = (bit ? bz : a) + recv;
        }
    }
    float c4[4];
    {
        int bit = (l >> 1) & 1;
        #pragma unroll
        for (int i = 0; i < 4; ++i) {
            float a = c8[2 * i], bz = c8[2 * i + 1];
            float send = bit ? a : bz;
            float recv = __shfl_xor(send, 2);
            c4[i] = (bit ? bz : a) + recv;
        }
    }
    float c2v[2];
    {
        int bit = (l >> 2) & 1;
        #pragma unroll
        for (int i = 0; i < 2; ++i) {
            float a = c4[2 * i], bz = c4[2 * i + 1];
            float send = bit ? a : bz;
            float recv = __shfl_xor(send, 4);
            c2v[i] = (bit ? bz : a) + recv;
        }
    }
    float h;
    {
        int bit = (l >> 3) & 1;
        float a = c2v[0], bz = c2v[1];
        float send = bit ? a : bz;
        float recv = __shfl_xor(send, 8);
        h = (bit ? bz : a) + recv;
    }
    h += __shfl_xor(h, 16);
    h += __shfl_xor(h, 32);

    // --- h1 = gelu(h + b1[j]) ; h2 via group xor-reduce ---
    int j = l & 15;
    int g4 = l >> 4;
    float h1 = gelu_exact(h + b1[j]);
    float4 w2v = *(const float4*)(w2 + j * 16 + g4 * 4);
    float p0 = h1 * w2v.x, p1 = h1 * w2v.y, p2 = h1 * w2v.z, p3 = h1 * w2v.w;
    #pragma unroll
    for (int m = 1; m <= 8; m <<= 1) {
        p0 += __shfl_xor(p0, m);
        p1 += __shfl_xor(p1, m);
        p2 += __shfl_xor(p2, m);
        p3 += __shfl_xor(p3, m);
    }
    float4 b2v = *(const float4*)(b2 + g4 * 4);
    float h2_0 = p0 + b2v.x, h2_1 = p1 + b2v.y, h2_2 = p2 + b2v.z, h2_3 = p3 + b2v.w;

    // --- geometry + scatter ---
    const float* M = mats + bc * 12;
    float dm = fmaxf(dmr, 0.f);
    float u = (gx + 0.5f) * (float)PATCH;
    float v = (gy + 0.5f) * (float)PATCH;
    float lx = (M[0] * u + M[1] * v + M[2]) * dm + M[9];
    float ly = (M[3] * u + M[4] * v + M[5]) * dm + M[10];
    float lz = (M[6] * u + M[7] * v + M[8]) * dm + M[11];
    int cx = (int)floorf((lx + 40.0f) / 0.4f);
    int cy = (int)floorf((ly + 40.0f) / 0.4f);
    int cz = (int)floorf((lz + 1.0f) / 0.4f);
    bool valid = (dmr > 0.001f) &&
                 (unsigned)cx < (unsigned)GX &&
                 (unsigned)cy < (unsigned)GY &&
                 (unsigned)cz < (unsigned)GZ;
    if (valid) {
        size_t sp = ((size_t)cx * GY + cy) * GZ + cz;
        float* base = vol + ((size_t)b * PL + sp) * 16 + g4 * 4;
        int rm = l & 15;
        if      (rm == 0) atomicAdd(base + 0, h2_0);
        else if (rm == 1) atomicAdd(base + 1, h2_1);
        else if (rm == 2) atomicAdd(base + 2, h2_2);
        else if (rm == 3) atomicAdd(base + 3, h2_3);
        if (l == 0) atomicAdd(cnt + (size_t)b * PL + sp, 1.0f);
    }
}

// ------- norm+halo: vol/cnt -> padded bf16 dec_in + mask; zero all halos -------
__global__ __launch_bounds__(256) void occ_norm_kernel(
    const float* __restrict__ volf, const float* __restrict__ cnt,
    __hip_bfloat16* __restrict__ decn, __hip_bfloat16* __restrict__ msk,
    __hip_bfloat16* __restrict__ st2)
{
    size_t i = (size_t)blockIdx.x * 256 + threadIdx.x;   // padded row index
    if (i >= (size_t)PROWS_TOT) return;
    int pz = (int)(i % PZ);
    size_t t1 = i / PZ;
    int py = (int)(t1 % PY);
    size_t t2 = t1 / PY;
    int px = (int)(t2 % PX);
    int b  = (int)(t2 / PX);
    bool interior = (px >= 1) && (px <= GX) && (py >= 1) && (py <= GY) &&
                    (pz >= 1) && (pz <= GZ);
    short8* dp = (short8*)(decn + i * 16);
    if (interior) {
        size_t vi = (size_t)b * PL + (((size_t)(px - 1) * GY + (py - 1)) * GZ + (pz - 1));
        float cn = cnt[vi];
        float inv = 1.0f / fmaxf(cn, 1.0f);
        const float4* vp = (const float4*)(volf + vi * 16);
        float4 f0 = vp[0], f1 = vp[1], f2 = vp[2], f3 = vp[3];
        short8 o0, o1;
        o0[0] = (short)f2bf(f0.x * inv); o0[1] = (short)f2bf(f0.y * inv);
        o0[2] = (short)f2bf(f0.z * inv); o0[3] = (short)f2bf(f0.w * inv);
        o0[4] = (short)f2bf(f1.x * inv); o0[5] = (short)f2bf(f1.y * inv);
        o0[6] = (short)f2bf(f1.z * inv); o0[7] = (short)f2bf(f1.w * inv);
        o1[0] = (short)f2bf(f2.x * inv); o1[1] = (short)f2bf(f2.y * inv);
        o1[2] = (short)f2bf(f2.z * inv); o1[3] = (short)f2bf(f2.w * inv);
        o1[4] = (short)f2bf(f3.x * inv); o1[5] = (short)f2bf(f3.y * inv);
        o1[6] = (short)f2bf(f3.z * inv); o1[7] = (short)f2bf(f3.w * inv);
        dp[0] = o0; dp[1] = o1;
        msk[i] = __float2bfloat16(cn > 0.f ? 1.f : 0.f);
    } else {
        dp[0] = zero8(); dp[1] = zero8();
        msk[i] = __float2bfloat16(0.f);
        short8* sp2 = (short8*)(st2 + i * 16);
        sp2[0] = zero8(); sp2[1] = zero8();
    }
}

// ------- conv3d 3x3x3 via MFMA, LDS-staged input tile -------
template <bool MASK, bool OUTPAD>
__global__ __launch_bounds__(256, 4) void occ_conv_kernel(
    const __hip_bfloat16* __restrict__ in, const __hip_bfloat16* __restrict__ msk,
    const __hip_bfloat16* __restrict__ wBa, const __hip_bfloat16* __restrict__ wBm,
    const float* __restrict__ bias, __hip_bfloat16* __restrict__ out,
    float* __restrict__ stats)
{
    // 5000 blocks = NB * (GX/2) * (GY/8); XCD-chunked swizzle (5000 = 8*625)
    int bid = blockIdx.x;
    int blk = (bid & 7) * 625 + (bid >> 3);
    int b   = blk / 2500;
    int rem = blk % 2500;
    int x0  = (rem / 25) * 2;
    int y0  = (rem % 25) * 8;
    int tid = threadIdx.x;

    __shared__ __hip_bfloat16 sA[720 * 16];     // 4x10x18 rows of 16ch = 23,040 B
    __shared__ unsigned short sM[720];
    __shared__ float sred[4][32];

    // cooperative stage: rows (dx, dy*18+dz) contiguous per x-slab
    {
        const short8* gin = (const short8*)in;
        short8* sa8 = (short8*)sA;
        for (int ii = tid; ii < 720; ii += 256) {
            int dx = ii / 180;
            int r2 = ii - dx * 180;
            size_t grow = ((size_t)((b * PX + x0 + dx) * PY + y0) * PZ) + r2;
            sa8[ii * 2]     = gin[grow * 2];
            sa8[ii * 2 + 1] = gin[grow * 2 + 1];
            if constexpr (MASK)
                sM[ii] = *(const unsigned short*)(msk + grow);
        }
    }
    __syncthreads();

    int w = tid >> 6, lane = tid & 63;
    int dxw = w >> 1;               // 0/1 : wave's x within tile
    int wyl = (w & 1) * 4;          // 0/4 : wave's y-base within tile
    int z = lane & 15, kg = lane >> 4;
    int ci0 = (kg & 1) << 3;
    bool halfsel = kg >= 2;

    // preload weight fragments (loop-invariant)
    const short8* wp = (const short8*)wBa;
    short8 wreg[14];
    #pragma unroll
    for (int t2 = 0; t2 < 14; ++t2) wreg[t2] = wp[t2 * 64 + lane];

    float bo = bias[lane & 15];
    floatx4 acc[4];
    #pragma unroll
    for (int j = 0; j < 4; ++j) { acc[j][0]=bo; acc[j][1]=bo; acc[j][2]=bo; acc[j][3]=bo; }

    #pragma unroll
    for (int t2 = 0; t2 < 14; ++t2) {
        const int ta = 2 * t2;
        const int tb = (2 * t2 + 1 > 26) ? 26 : 2 * t2 + 1;
        const int kda = ta / 9, kha = (ta / 3) % 3, kwa = ta % 3;
        const int kdb = tb / 9, khb = (tb / 3) % 3, kwb = tb % 3;
        int rowA = (dxw + kda) * 180 + (wyl + kha) * 18 + (z + kwa);
        int rowB = (dxw + kdb) * 180 + (wyl + khb) * 18 + (z + kwb);
        int row = halfsel ? rowB : rowA;
        const __hip_bfloat16* ap = sA + row * 16 + ci0;
        #pragma unroll
        for (int j = 0; j < 4; ++j) {
            short8 a = *(const short8*)(ap + j * (18 * 16));   // +576B per y-col
            acc[j] = __builtin_amdgcn_mfma_f32_16x16x32_bf16(a, wreg[t2], acc[j], 0, 0, 0);
        }
    }

    if constexpr (MASK) {
        int base8[8];
        #pragma unroll
        for (int e = 0; e < 8; ++e) {
            int tap = kg * 8 + e;
            int kd = tap / 9;
            int rm = tap - kd * 9;
            int kh = rm / 3;
            int kw = rm - kh * 3;
            int idx = (dxw + kd) * 180 + (wyl + kh) * 18 + z + kw;
            base8[e] = (tap < 27) ? idx : 0;    // weight is 0 for tap>=27
        }
        short8 wm = ((const short8*)wBm)[lane];
        #pragma unroll
        for (int j = 0; j < 4; ++j) {
            short8 am;
            #pragma unroll
            for (int e = 0; e < 8; ++e) am[e] = (short)sM[base8[e] + j * 18];
            acc[j] = __builtin_amdgcn_mfma_f32_16x16x32_bf16(am, wm, acc[j], 0, 0, 0);
        }
    }

    // store; D: row z' = kg*4+r, col o = lane&15
    int o = lane & 15;
    int wx = x0 + dxw;
    int wy = y0 + wyl;
    #pragma unroll
    for (int j = 0; j < 4; ++j) {
        size_t rowbase;
        if constexpr (OUTPAD)
            rowbase = (size_t)(((b * PX + wx + 1) * PY) + (wy + j + 1)) * PZ + 1;
        else
            rowbase = (size_t)b * PL + ((size_t)wx * GY + (wy + j)) * GZ;
        #pragma unroll
        for (int r = 0; r < 4; ++r)
            out[(rowbase + kg * 4 + r) * 16 + o] = __float2bfloat16(acc[j][r]);
    }

    // fused BN stats (per-channel sum / sumsq)
    float s = 0.f, sq = 0.f;
    #pragma unroll
    for (int j = 0; j < 4; ++j)
        #pragma unroll
        for (int r = 0; r < 4; ++r) { float v = acc[j][r]; s += v; sq += v * v; }
    s  += __shfl_xor(s, 16);  s  += __shfl_xor(s, 32);
    sq += __shfl_xor(sq, 16); sq += __shfl_xor(sq, 32);
    if (lane < 16) { sred[w][lane] = s; sred[w][16 + lane] = sq; }
    __syncthreads();
    if (tid < 32) {
        float v2 = sred[0][tid] + sred[1][tid] + sred[2][tid] + sred[3][tid];
        atomicAdd(&stats[(size_t)(blockIdx.x & 63) * 32 + tid], v2);
    }
}

// ---------------- BN finalize ----------------
__global__ void occ_bnfin_kernel(const float* __restrict__ stats, const float* __restrict__ g,
                                 const float* __restrict__ bb, float* __restrict__ bn)
{
    int c = threadIdx.x;
    if (c >= 16) return;
    float s = 0.f, sq = 0.f;
    for (int k = 0; k < 64; ++k) { s += stats[k * 32 + c]; sq += stats[k * 32 + 16 + c]; }
    const float N = (float)(NB * PL);
    float mean = s / N;
    float var = sq / N - mean * mean;
    float scale = g[c] * rsqrtf(var + EPSF);
    bn[c] = scale;
    bn[16 + c] = bb[c] - mean * scale;
}

// ------- BN affine + GELU in-place on padded buffer, interior rows only -------
__global__ __launch_bounds__(256) void occ_bnact_kernel(__hip_bfloat16* __restrict__ buf,
                                                        const float* __restrict__ bn)
{
    __shared__ float sc[16], sh[16];
    int t = threadIdx.x;
    if (t < 16) sc[t] = bn[t];
    else if (t < 32) sh[t - 16] = bn[t];
    __syncthreads();
    size_t i = (size_t)blockIdx.x * 256 + t;      // interior voxel index < NB*PL
    int b = (int)(i / PL);
    size_t sp = i % PL;
    int x = (int)(sp / (GY * GZ));
    int r2 = (int)(sp % (GY * GZ));
    int y = r2 / GZ, z = r2 & 15;
    size_t pidx = (size_t)(((b * PX + x + 1) * PY) + (y + 1)) * PZ + (z + 1);
    short8* p = (short8*)(buf + pidx * 16);
    short8 v0 = p[0], v1 = p[1];
    #pragma unroll
    for (int e = 0; e < 8; ++e) {
        float a0 = gelu_exact(fmaf(bf2f(v0[e]), sc[e],     sh[e]));
        float a1 = gelu_exact(fmaf(bf2f(v1[e]), sc[8 + e], sh[8 + e]));
        v0[e] = (short)f2bf(a0);
        v1[e] = (short)f2bf(a1);
    }
    p[0] = v0; p[1] = v1;
}

// ---------------- conv3 1x1x1 (16 -> 20) with fused bn2+GELU ----------------
__global__ __launch_bounds__(256) void occ_conv3_kernel(const __hip_bfloat16* __restrict__ act,
                                                        const float* __restrict__ bn,
                                                        const float* __restrict__ w3,
                                                        const float* __restrict__ b3,
                                                        float* __restrict__ out)
{
    __shared__ float w[NCLS * 16];
    __shared__ float bb[NCLS];
    __shared__ float sc[16], sh[16];
    int t = threadIdx.x;
    for (int i = t; i < NCLS * 16; i += 256) w[i] = w3[i];
    if (t < NCLS) bb[t] = b3[t];
    if (t >= 32 && t < 48) sc[t - 32] = bn[t - 32];
    if (t >= 48 && t < 64) sh[t - 48] = bn[t - 32];
    __syncthreads();
    size_t i = (size_t)blockIdx.x * 256 + t;      // < NB*PL
    size_t b = i / PL, sp = i % PL;
    const short8* p = (const short8*)(act + i * 16);
    short8 v0 = p[0], v1 = p[1];
    float vi[16];
    #pragma unroll
    for (int e = 0; e < 8; ++e) {
        vi[e]     = gelu_exact(fmaf(bf2f(v0[e]), sc[e],     sh[e]));
        vi[8 + e] = gelu_exact(fmaf(bf2f(v1[e]), sc[8 + e], sh[8 + e]));
    }
    float* op = out + b * NCLS * PL + sp;
    #pragma unroll
    for (int cls = 0; cls < NCLS; ++cls) {
        float a = bb[cls];
        #pragma unroll
        for (int ci = 0; ci < 16; ++ci) a = fmaf(vi[ci], w[cls * 16 + ci], a);
        op[(size_t)cls * PL] = a;
    }
}

// ---------------- launch ----------------
extern "C" void kernel_launch(void* const* d_in, const int* in_sizes, int n_in,
                              void* d_out, int out_size, void* d_ws, size_t ws_size,
                              hipStream_t stream)
{
    const float* tokens = (const float*)d_in[0];
    const float* depth  = (const float*)d_in[1];
    const float* intr   = (const float*)d_in[2];
    const float* c2w    = (const float*)d_in[3];
    const float* l2w    = (const float*)d_in[4];
    const float* ln_g   = (const float*)d_in[5];
    const float* ln_b   = (const float*)d_in[6];
    const float* w1     = (const float*)d_in[7];
    const float* b1     = (const float*)d_in[8];
    const float* w2     = (const float*)d_in[9];
    const float* b2     = (const float*)d_in[10];
    const float* cv1w   = (const float*)d_in[11];
    const float* cv1b   = (const float*)d_in[12];
    const float* bn1g   = (const float*)d_in[13];
    const float* bn1b   = (const float*)d_in[14];
    const float* cv2w   = (const float*)d_in[15];
    const float* cv2b   = (const float*)d_in[16];
    const float* bn2g   = (const float*)d_in[17];
    const float* bn2b   = (const float*)d_in[18];
    const float* cv3w   = (const float*)d_in[19];
    const float* cv3b   = (const float*)d_in[20];

    if (ws_size < WS_FLOATS * sizeof(float)) return;

    float* ws   = (float*)d_ws;
    float* volf = ws + OFF_VOL;
    float* cntp = ws + OFF_CNT;
    float* st1  = ws + OFF_ST1;
    float* st2s = ws + OFF_ST2;
    float* mats = ws + OFF_MATS;
    __hip_bfloat16* w1L  = (__hip_bfloat16*)(ws + OFF_W1L);
    __hip_bfloat16* wB1a = (__hip_bfloat16*)(ws + OFF_WB1A);
    __hip_bfloat16* wB1m = (__hip_bfloat16*)(ws + OFF_WB1M);
    __hip_bfloat16* wB2  = (__hip_bfloat16*)(ws + OFF_WB2);
    float* bnp1 = ws + OFF_BN1;
    float* bnp2 = ws + OFF_BN2;

    __hip_bfloat16* ob      = (__hip_bfloat16*)d_out;
    __hip_bfloat16* decn    = ob + DO_DECN;     // padded
    __hip_bfloat16* mskp    = ob + DO_MSK;      // padded
    __hip_bfloat16* staged2 = ob + DO_ST2;      // padded conv1 out
    __hip_bfloat16* staged3 = (__hip_bfloat16*)(ws + OFF_VOL);  // unpadded conv2 out
    float* outp = (float*)d_out;

    hipMemsetAsync(ws, 0, ZERO_F * sizeof(float), stream);

    occ_prep_kernel<<<1, 256, 0, stream>>>(intr, c2w, l2w, w1, cv1w, cv2w,
                                           mats, w1L, wB1a, wB1m, wB2);

    occ_token_kernel<<<NB * NCAM * NP / 4, 256, 0, stream>>>(
        tokens, depth, ln_g, ln_b, w1L, b1, w2, b2, mats, volf, cntp);

    occ_norm_kernel<<<(PROWS_TOT + 255) / 256, 256, 0, stream>>>(volf, cntp, decn, mskp, staged2);

    const int CGRID = NB * (GX / 2) * (GY / 8);   // 5000
    occ_conv_kernel<true, true><<<CGRID, 256, 0, stream>>>(decn, mskp, wB1a, wB1m, cv1b, staged2, st1);
    occ_bnfin_kernel<<<1, 16, 0, stream>>>(st1, bn1g, bn1b, bnp1);
    occ_bnact_kernel<<<5000, 256, 0, stream>>>(staged2, bnp1);

    occ_conv_kernel<false, false><<<CGRID, 256, 0, stream>>>(staged2, nullptr, wB2, nullptr, cv2b, staged3, st2s);
    occ_bnfin_kernel<<<1, 16, 0, stream>>>(st2s, bn2g, bn2b, bnp2);

    occ_conv3_kernel<<<5000, 256, 0, stream>>>(staged3, bnp2, cv3w, cv3b, outp);
}

// Round 6
// 213.538 us; speedup vs baseline: 11.3922x; 1.0770x over previous
//
#include <hip/hip_runtime.h>
#include <hip/hip_bf16.h>
#include <math.h>

// ---------------- problem constants ----------------
#define PATCH 14
#define HID   16
#define NCLS  20
#define GX    200
#define GY    200
#define GZ    16
#define NB    2
#define NCAM  6
#define PH    37
#define PW    37
#define NP    (PH*PW)
#define NT    (NB*NCAM*NP)         // 16428 tokens
#define TD    768
#define IMH   518
#define IMW   518
#define PL    ((size_t)GX*GY*GZ)   // 640000 voxels per batch
#define EPSF  1e-5f

// padded conv layout: [b][px 0..201][py 0..201][pz 0..17] rows of 16 ch
#define PX 202
#define PY 202
#define PZ 18
#define PROWS_TOT (NB*PX*PY*PZ)    // 1,468,944 rows

// ---------------- workspace layout (float units) ----------------
#define OFF_VOL   ((size_t)0)            // volf [b][sp][16] fp32 (later reused as staged3 bf16)
#define OFF_CNT   ((size_t)20480000)
#define OFF_ST1   ((size_t)21760000)
#define OFF_ST2   ((size_t)21762048)
#define ZERO_F    ((size_t)21764096)     // zeroed every call up to here
#define OFF_MATS  ((size_t)21764096)     // 144
#define OFF_WGM   ((size_t)21764240)     // 24*64*8 bf16 = 6,144 f
#define OFF_WA2   ((size_t)21770384)     // 64*8 bf16 = 256 f
#define OFF_C12   ((size_t)21770640)     // 32
#define OFF_WB1A  ((size_t)21770672)     // 3,584
#define OFF_WB1M  ((size_t)21774256)     // 256
#define OFF_WB2   ((size_t)21774512)     // 3,584
#define OFF_BN1   ((size_t)21778096)     // 32
#define OFF_BN2   ((size_t)21778128)     // 32
#define WS_FLOATS ((size_t)21778160)

// ---------------- d_out staging (bf16 units; dead before conv3 writes) ----------
#define DO_DECN ((size_t)0)                       // padded dec_in, 23,503,104
#define DO_MSK  ((size_t)23503104)                // padded mask rows, 1,468,944
#define DO_ST2  ((size_t)24972048)                // padded conv1 out, 23,503,104
#define DO_DM   ((size_t)48600000)                // dmean fp32[NT] = 32,856 bf16
                                                  // end 48,632,856 <= 51,200,000

typedef __attribute__((ext_vector_type(8))) short short8;
typedef __attribute__((ext_vector_type(4))) float floatx4;

__device__ __forceinline__ float gelu_exact(float x) {
    return 0.5f * x * (1.0f + erff(x * 0.70710678118654752f));
}
__device__ __forceinline__ unsigned short f2bf(float f) {
    __hip_bfloat16 h = __float2bfloat16(f);
    return __builtin_bit_cast(unsigned short, h);
}
__device__ __forceinline__ float bf2f(short u) {
    unsigned int b = ((unsigned int)(unsigned short)u) << 16;
    return __builtin_bit_cast(float, b);
}
__device__ __forceinline__ short8 zero8() {
    short8 z = {0,0,0,0,0,0,0,0};
    return z;
}

// ---------------- 3x3 / 4x4 inverse in double ----------------
__device__ void inv3d(const double* m, double* o) {
    double a=m[0],b=m[1],c=m[2],d=m[3],e=m[4],f=m[5],g=m[6],h=m[7],i=m[8];
    double A=e*i-f*h, B=-(d*i-f*g), C=d*h-e*g;
    double det=a*A+b*B+c*C, id=1.0/det;
    o[0]=A*id;            o[1]=-(b*i-c*h)*id;   o[2]=(b*f-c*e)*id;
    o[3]=B*id;            o[4]=(a*i-c*g)*id;    o[5]=-(a*f-c*d)*id;
    o[6]=C*id;            o[7]=-(a*h-b*g)*id;   o[8]=(a*e-b*d)*id;
}

__device__ void inv4d(const double* m, double* o) {
    double i0  =  m[5]*m[10]*m[15]-m[5]*m[11]*m[14]-m[9]*m[6]*m[15]+m[9]*m[7]*m[14]+m[13]*m[6]*m[11]-m[13]*m[7]*m[10];
    double i4  = -m[4]*m[10]*m[15]+m[4]*m[11]*m[14]+m[8]*m[6]*m[15]-m[8]*m[7]*m[14]-m[12]*m[6]*m[11]+m[12]*m[7]*m[10];
    double i8  =  m[4]*m[9]*m[15]-m[4]*m[11]*m[13]-m[8]*m[5]*m[15]+m[8]*m[7]*m[13]+m[12]*m[5]*m[11]-m[12]*m[7]*m[9];
    double i12 = -m[4]*m[9]*m[14]+m[4]*m[10]*m[13]+m[8]*m[5]*m[14]-m[8]*m[6]*m[13]-m[12]*m[5]*m[10]+m[12]*m[6]*m[9];
    double i1  = -m[1]*m[10]*m[15]+m[1]*m[11]*m[14]+m[9]*m[2]*m[15]-m[9]*m[3]*m[14]-m[13]*m[2]*m[11]+m[13]*m[3]*m[10];
    double i5  =  m[0]*m[10]*m[15]-m[0]*m[11]*m[14]-m[8]*m[2]*m[15]+m[8]*m[3]*m[14]+m[12]*m[2]*m[11]-m[12]*m[3]*m[10];
    double i9  = -m[0]*m[9]*m[15]+m[0]*m[11]*m[13]+m[8]*m[1]*m[15]-m[8]*m[3]*m[13]-m[12]*m[1]*m[11]+m[12]*m[3]*m[9];
    double i13 =  m[0]*m[9]*m[14]-m[0]*m[10]*m[13]-m[8]*m[1]*m[14]+m[8]*m[2]*m[13]+m[12]*m[1]*m[10]-m[12]*m[2]*m[9];
    double i2  =  m[1]*m[6]*m[15]-m[1]*m[7]*m[14]-m[5]*m[2]*m[15]+m[5]*m[3]*m[14]+m[13]*m[2]*m[7]-m[13]*m[3]*m[6];
    double i6  = -m[0]*m[6]*m[15]+m[0]*m[7]*m[14]+m[4]*m[2]*m[15]-m[4]*m[3]*m[14]-m[12]*m[2]*m[7]+m[12]*m[3]*m[6];
    double i10 =  m[0]*m[5]*m[15]-m[0]*m[7]*m[13]-m[4]*m[1]*m[15]+m[4]*m[3]*m[13]+m[12]*m[1]*m[7]-m[12]*m[3]*m[5];
    double i14 = -m[0]*m[5]*m[14]+m[0]*m[6]*m[13]+m[4]*m[1]*m[14]-m[4]*m[2]*m[13]-m[12]*m[1]*m[6]+m[12]*m[2]*m[5];
    double i3  = -m[1]*m[6]*m[11]+m[1]*m[7]*m[10]+m[5]*m[2]*m[11]-m[5]*m[3]*m[10]-m[9]*m[2]*m[7]+m[9]*m[3]*m[6];
    double i7  =  m[0]*m[6]*m[11]-m[0]*m[7]*m[10]-m[4]*m[2]*m[11]+m[4]*m[3]*m[10]+m[8]*m[2]*m[7]-m[8]*m[3]*m[6];
    double i11 = -m[0]*m[5]*m[11]+m[0]*m[7]*m[9]+m[4]*m[1]*m[11]-m[4]*m[3]*m[9]-m[8]*m[1]*m[7]+m[8]*m[3]*m[5];
    double i15 =  m[0]*m[5]*m[10]-m[0]*m[6]*m[9]-m[4]*m[1]*m[10]+m[4]*m[2]*m[9]+m[8]*m[1]*m[6]-m[8]*m[2]*m[5];
    double det = m[0]*i0+m[1]*i4+m[2]*i8+m[3]*i12;
    double id = 1.0/det;
    o[0]=i0*id; o[1]=i1*id; o[2]=i2*id; o[3]=i3*id;
    o[4]=i4*id; o[5]=i5*id; o[6]=i6*id; o[7]=i7*id;
    o[8]=i8*id; o[9]=i9*id; o[10]=i10*id; o[11]=i11*id;
    o[12]=i12*id; o[13]=i13*id; o[14]=i14*id; o[15]=i15*id;
}

// ---------------- precompute ----------------
__global__ void occ_prep_kernel(const float* __restrict__ intr, const float* __restrict__ c2w,
                                const float* __restrict__ l2w, const float* __restrict__ w1,
                                const float* __restrict__ ln_g, const float* __restrict__ ln_b,
                                const float* __restrict__ b1, const float* __restrict__ w2,
                                const float* __restrict__ cw1, const float* __restrict__ cw2,
                                float* __restrict__ mats, __hip_bfloat16* __restrict__ wGm,
                                __hip_bfloat16* __restrict__ wA2, float* __restrict__ c12,
                                __hip_bfloat16* __restrict__ wB1a, __hip_bfloat16* __restrict__ wB1m,
                                __hip_bfloat16* __restrict__ wB2)
{
    int t = threadIdx.x;
    if (t < NB * NCAM) {
        int b = t / NCAM;
        double K[9], Ki[9], L[16], Li[16], C[16], M[16], A[9];
        #pragma unroll
        for (int i = 0; i < 9; ++i) K[i] = (double)intr[t * 9 + i];
        inv3d(K, Ki);
        #pragma unroll
        for (int i = 0; i < 16; ++i) L[i] = (double)l2w[b * 16 + i];
        inv4d(L, Li);
        #pragma unroll
        for (int i = 0; i < 16; ++i) C[i] = (double)c2w[t * 16 + i];
        #pragma unroll
        for (int r = 0; r < 4; ++r)
            #pragma unroll
            for (int c = 0; c < 4; ++c) {
                double s = 0.0;
                #pragma unroll
                for (int k = 0; k < 4; ++k) s += Li[r * 4 + k] * C[k * 4 + c];
                M[r * 4 + c] = s;
            }
        #pragma unroll
        for (int r = 0; r < 3; ++r)
            #pragma unroll
            for (int c = 0; c < 3; ++c) {
                double s = 0.0;
                #pragma unroll
                for (int k = 0; k < 3; ++k) s += M[r * 4 + k] * Ki[k * 3 + c];
                A[r * 3 + c] = s;
            }
        #pragma unroll
        for (int i = 0; i < 9; ++i) mats[t * 12 + i] = (float)A[i];
        mats[t * 12 + 9]  = (float)M[3];
        mats[t * 12 + 10] = (float)M[7];
        mats[t * 12 + 11] = (float)M[11];
    }
    // token GEMM1 B-fragments: wGm[step][lane][8], k = d = step*32 + 8*kg + e, col j = lane&15
    for (int i = t; i < 24 * 64 * 8; i += 256) {
        int st = i >> 9; int ln = (i >> 3) & 63; int e = i & 7;
        int kg = ln >> 4, j = ln & 15;
        int d = st * 32 + kg * 8 + e;
        wGm[i] = __float2bfloat16(ln_g[d] * w1[d * 16 + j]);
    }
    // token GEMM2 A-fragment: w2^T, m = ch = lane&15, k = hid = 8*kg+e (valid k<16)
    for (int i = t; i < 64 * 8; i += 256) {
        int ln = i >> 3; int e = i & 7;
        int kg = ln >> 4, ch = ln & 15;
        int k = kg * 8 + e;
        wA2[i] = __float2bfloat16((k < 16) ? w2[k * 16 + ch] : 0.f);
    }
    // c1_j = sum_d round_bf16(g_d*w1_dj) ; c2'_j = sum_d b_d*w1_dj + b1_j
    if (t < 16) {
        float c1 = 0.f, c2p = 0.f;
        for (int d = 0; d < TD; ++d) {
            c1  += bf2f((short)f2bf(ln_g[d] * w1[d * 16 + t]));
            c2p += ln_b[d] * w1[d * 16 + t];
        }
        c12[t] = c1;
        c12[16 + t] = c2p + b1[t];
    }
    // conv1 main (16 vol channels): wB1a[t2][lane][8]; K packs 2 taps x 16 ch
    for (int i = t; i < 14 * 64 * 8; i += 256) {
        int t2 = i >> 9; int r = i & 511; int ln = r >> 3; int e = r & 7;
        int kg = ln >> 4;
        int tt = 2 * t2 + (kg >> 1);
        int ci = ((kg & 1) << 3) + e;
        int o = ln & 15;
        float val = (tt < 27) ? cw1[(o * 17 + ci) * 27 + tt] : 0.f;
        wB1a[i] = __float2bfloat16(val);
    }
    // conv1 mask channel (ci=16): wB1m[lane][8]; K slot = tap index
    for (int i = t; i < 64 * 8; i += 256) {
        int ln = i >> 3; int e = i & 7;
        int k = ((ln >> 4) << 3) + e;
        int o = ln & 15;
        float val = (k < 27) ? cw1[(o * 17 + 16) * 27 + k] : 0.f;
        wB1m[i] = __float2bfloat16(val);
    }
    // conv2: wB2[t2][lane][8]
    for (int i = t; i < 14 * 64 * 8; i += 256) {
        int t2 = i >> 9; int r = i & 511; int ln = r >> 3; int e = r & 7;
        int kg = ln >> 4;
        int tt = 2 * t2 + (kg >> 1);
        int ci = ((kg & 1) << 3) + e;
        int o = ln & 15;
        float val = (tt < 27) ? cw2[(o * 16 + ci) * 27 + tt] : 0.f;
        wB2[i] = __float2bfloat16(val);
    }
}

// ---------------- depth patch means: one wave per token ----------------
__global__ __launch_bounds__(256) void occ_depth_kernel(const float* __restrict__ depth,
                                                        float* __restrict__ dmean)
{
    int tid = threadIdx.x;
    int l = tid & 63;
    int g = blockIdx.x * 4 + (tid >> 6);     // 4107 blocks * 4 = 16428 exactly
    int bc = g / NP;
    int p  = g - bc * NP;
    int gy = p / PW, gx = p - gy * PW;
    const float* dbase = depth + (size_t)bc * (IMH * IMW);
    int rbase = gy * PATCH, cb = gx * PATCH;
    float dsum = 0.f;
    #pragma unroll
    for (int i = 0; i < 3; ++i) {
        int idx = l + 64 * i;
        int py = idx / 14;
        int px = idx - py * 14;
        dsum += dbase[(size_t)(rbase + py) * IMW + (cb + px)];
    }
    if (l < 4)
        dsum += dbase[(size_t)(rbase + 13) * IMW + (cb + 10 + l)];
    #pragma unroll
    for (int m = 1; m <= 32; m <<= 1) dsum += __shfl_xor(dsum, m);
    if (l == 0) dmean[g] = dsum * (1.0f / 196.0f);
}

// ------- token GEMM: LN folded into epilogue; 16 tokens per wave; MFMA -------
__global__ __launch_bounds__(256) void occ_tokgemm_kernel(
    const float* __restrict__ tokens, const float* __restrict__ dmean,
    const __hip_bfloat16* __restrict__ wGm, const __hip_bfloat16* __restrict__ wA2,
    const float* __restrict__ c12, const float* __restrict__ b2,
    const float* __restrict__ mats, float* __restrict__ vol, float* __restrict__ cnt)
{
    int tid = threadIdx.x;
    int w = tid >> 6, lane = tid & 63;
    int tile = (blockIdx.x * 4 + w) * 16;
    int j16 = lane & 15, kg = lane >> 4;

    __shared__ __hip_bfloat16 sH[4][16][16];

    int tka  = tile + j16;
    int tkac = min(tka, NT - 1);

    const float* tokp = tokens + (size_t)tkac * TD + (kg << 3);
    const short8* wg8 = (const short8*)wGm;

    floatx4 acc = {0.f, 0.f, 0.f, 0.f};
    float s = 0.f, sq = 0.f;
    #pragma unroll
    for (int st = 0; st < 24; ++st) {
        float4 xa = *(const float4*)(tokp + st * 32);
        float4 xb = *(const float4*)(tokp + st * 32 + 4);
        s += xa.x + xa.y + xa.z + xa.w + xb.x + xb.y + xb.z + xb.w;
        sq = fmaf(xa.x, xa.x, sq); sq = fmaf(xa.y, xa.y, sq);
        sq = fmaf(xa.z, xa.z, sq); sq = fmaf(xa.w, xa.w, sq);
        sq = fmaf(xb.x, xb.x, sq); sq = fmaf(xb.y, xb.y, sq);
        sq = fmaf(xb.z, xb.z, sq); sq = fmaf(xb.w, xb.w, sq);
        short8 a;
        a[0] = (short)f2bf(xa.x); a[1] = (short)f2bf(xa.y);
        a[2] = (short)f2bf(xa.z); a[3] = (short)f2bf(xa.w);
        a[4] = (short)f2bf(xb.x); a[5] = (short)f2bf(xb.y);
        a[6] = (short)f2bf(xb.z); a[7] = (short)f2bf(xb.w);
        acc = __builtin_amdgcn_mfma_f32_16x16x32_bf16(a, wg8[st * 64 + lane], acc, 0, 0, 0);
    }
    // stats for token j16 (dims split across kg groups)
    s  += __shfl_xor(s, 16);  s  += __shfl_xor(s, 32);
    sq += __shfl_xor(sq, 16); sq += __shfl_xor(sq, 32);
    float mu = s * (1.0f / (float)TD);
    float rs = rsqrtf(sq * (1.0f / (float)TD) - mu * mu + EPSF);

    // epilogue: h_j = rs*(acc - mu*c1_j) + c2'_j ; gelu ; stash h1 in LDS
    float c1  = c12[j16];
    float c2p = c12[16 + j16];
    #pragma unroll
    for (int r = 0; r < 4; ++r) {
        int srcl = kg * 4 + r;                 // row token within the 16-group
        float mur = __shfl(mu, srcl, 16);
        float rsr = __shfl(rs, srcl, 16);
        float h = rsr * (acc[r] - mur * c1) + c2p;
        sH[w][srcl][j16] = __float2bfloat16(gelu_exact(h));
    }
    __syncthreads();

    // GEMM2: D2[ch][token] = w2^T @ h1^T + b2
    short8 hb = zero8();
    if (kg < 2) hb = *(const short8*)&sH[w][j16][kg * 8];
    floatx4 acc2;
    acc2[0] = b2[kg * 4 + 0]; acc2[1] = b2[kg * 4 + 1];
    acc2[2] = b2[kg * 4 + 2]; acc2[3] = b2[kg * 4 + 3];
    short8 a2 = ((const short8*)wA2)[lane];
    acc2 = __builtin_amdgcn_mfma_f32_16x16x32_bf16(a2, hb, acc2, 0, 0, 0);

    // geometry + scatter: lane owns token tile+j16, channels kg*4 .. kg*4+3
    float dmr = dmean[tkac];
    int bc = tkac / NP;
    int p  = tkac - bc * NP;
    int b  = bc / NCAM;
    int gy = p / PW, gx = p - gy * PW;
    const float* M = mats + bc * 12;
    float dm = fmaxf(dmr, 0.f);
    float u = (gx + 0.5f) * (float)PATCH;
    float v = (gy + 0.5f) * (float)PATCH;
    float lx = (M[0] * u + M[1] * v + M[2]) * dm + M[9];
    float ly = (M[3] * u + M[4] * v + M[5]) * dm + M[10];
    float lz = (M[6] * u + M[7] * v + M[8]) * dm + M[11];
    int cx = (int)floorf((lx + 40.0f) / 0.4f);
    int cy = (int)floorf((ly + 40.0f) / 0.4f);
    int cz = (int)floorf((lz + 1.0f) / 0.4f);
    bool valid = (tka < NT) && (dmr > 0.001f) &&
                 (unsigned)cx < (unsigned)GX &&
                 (unsigned)cy < (unsigned)GY &&
                 (unsigned)cz < (unsigned)GZ;
    if (valid) {
        size_t sp = ((size_t)cx * GY + cy) * GZ + cz;
        float* base = vol + ((size_t)b * PL + sp) * 16 + kg * 4;
        atomicAdd(base + 0, acc2[0]);
        atomicAdd(base + 1, acc2[1]);
        atomicAdd(base + 2, acc2[2]);
        atomicAdd(base + 3, acc2[3]);
        if (kg == 0) atomicAdd(cnt + (size_t)b * PL + sp, 1.0f);
    }
}

// ------- norm+halo: vol/cnt -> padded bf16 dec_in + mask; zero all halos -------
__global__ __launch_bounds__(256) void occ_norm_kernel(
    const float* __restrict__ volf, const float* __restrict__ cnt,
    __hip_bfloat16* __restrict__ decn, __hip_bfloat16* __restrict__ msk,
    __hip_bfloat16* __restrict__ st2)
{
    size_t i = (size_t)blockIdx.x * 256 + threadIdx.x;   // padded row index
    if (i >= (size_t)PROWS_TOT) return;
    int pz = (int)(i % PZ);
    size_t t1 = i / PZ;
    int py = (int)(t1 % PY);
    size_t t2 = t1 / PY;
    int px = (int)(t2 % PX);
    int b  = (int)(t2 / PX);
    bool interior = (px >= 1) && (px <= GX) && (py >= 1) && (py <= GY) &&
                    (pz >= 1) && (pz <= GZ);
    short8* dp = (short8*)(decn + i * 16);
    if (interior) {
        size_t vi = (size_t)b * PL + (((size_t)(px - 1) * GY + (py - 1)) * GZ + (pz - 1));
        float cn = cnt[vi];
        float inv = 1.0f / fmaxf(cn, 1.0f);
        const float4* vp = (const float4*)(volf + vi * 16);
        float4 f0 = vp[0], f1 = vp[1], f2 = vp[2], f3 = vp[3];
        short8 o0, o1;
        o0[0] = (short)f2bf(f0.x * inv); o0[1] = (short)f2bf(f0.y * inv);
        o0[2] = (short)f2bf(f0.z * inv); o0[3] = (short)f2bf(f0.w * inv);
        o0[4] = (short)f2bf(f1.x * inv); o0[5] = (short)f2bf(f1.y * inv);
        o0[6] = (short)f2bf(f1.z * inv); o0[7] = (short)f2bf(f1.w * inv);
        o1[0] = (short)f2bf(f2.x * inv); o1[1] = (short)f2bf(f2.y * inv);
        o1[2] = (short)f2bf(f2.z * inv); o1[3] = (short)f2bf(f2.w * inv);
        o1[4] = (short)f2bf(f3.x * inv); o1[5] = (short)f2bf(f3.y * inv);
        o1[6] = (short)f2bf(f3.z * inv); o1[7] = (short)f2bf(f3.w * inv);
        dp[0] = o0; dp[1] = o1;
        msk[i] = __float2bfloat16(cn > 0.f ? 1.f : 0.f);
    } else {
        dp[0] = zero8(); dp[1] = zero8();
        msk[i] = __float2bfloat16(0.f);
        short8* sp2 = (short8*)(st2 + i * 16);
        sp2[0] = zero8(); sp2[1] = zero8();
    }
}

// ------- conv3d 3x3x3 via MFMA, LDS-staged input tile -------
template <bool MASK, bool OUTPAD>
__global__ __launch_bounds__(256, 4) void occ_conv_kernel(
    const __hip_bfloat16* __restrict__ in, const __hip_bfloat16* __restrict__ msk,
    const __hip_bfloat16* __restrict__ wBa, const __hip_bfloat16* __restrict__ wBm,
    const float* __restrict__ bias, __hip_bfloat16* __restrict__ out,
    float* __restrict__ stats)
{
    // 5000 blocks = NB * (GX/2) * (GY/8); XCD-chunked swizzle (5000 = 8*625)
    int bid = blockIdx.x;
    int blk = (bid & 7) * 625 + (bid >> 3);
    int b   = blk / 2500;
    int rem = blk % 2500;
    int x0  = (rem / 25) * 2;
    int y0  = (rem % 25) * 8;
    int tid = threadIdx.x;

    __shared__ __hip_bfloat16 sA[720 * 16];     // 4x10x18 rows of 16ch = 23,040 B
    __shared__ unsigned short sM[720];
    __shared__ float sred[4][32];

    // cooperative stage: rows (dx, dy*18+dz) contiguous per x-slab
    {
        const short8* gin = (const short8*)in;
        short8* sa8 = (short8*)sA;
        for (int ii = tid; ii < 720; ii += 256) {
            int dx = ii / 180;
            int r2 = ii - dx * 180;
            size_t grow = ((size_t)((b * PX + x0 + dx) * PY + y0) * PZ) + r2;
            sa8[ii * 2]     = gin[grow * 2];
            sa8[ii * 2 + 1] = gin[grow * 2 + 1];
            if constexpr (MASK)
                sM[ii] = *(const unsigned short*)(msk + grow);
        }
    }
    __syncthreads();

    int w = tid >> 6, lane = tid & 63;
    int dxw = w >> 1;               // 0/1 : wave's x within tile
    int wyl = (w & 1) * 4;          // 0/4 : wave's y-base within tile
    int z = lane & 15, kg = lane >> 4;
    int ci0 = (kg & 1) << 3;
    bool halfsel = kg >= 2;

    // preload weight fragments (loop-invariant)
    const short8* wp = (const short8*)wBa;
    short8 wreg[14];
    #pragma unroll
    for (int t2 = 0; t2 < 14; ++t2) wreg[t2] = wp[t2 * 64 + lane];

    float bo = bias[lane & 15];
    floatx4 acc[4];
    #pragma unroll
    for (int j = 0; j < 4; ++j) { acc[j][0]=bo; acc[j][1]=bo; acc[j][2]=bo; acc[j][3]=bo; }

    #pragma unroll
    for (int t2 = 0; t2 < 14; ++t2) {
        const int ta = 2 * t2;
        const int tb = (2 * t2 + 1 > 26) ? 26 : 2 * t2 + 1;
        const int kda = ta / 9, kha = (ta / 3) % 3, kwa = ta % 3;
        const int kdb = tb / 9, khb = (tb / 3) % 3, kwb = tb % 3;
        int rowA = (dxw + kda) * 180 + (wyl + kha) * 18 + (z + kwa);
        int rowB = (dxw + kdb) * 180 + (wyl + khb) * 18 + (z + kwb);
        int row = halfsel ? rowB : rowA;
        const __hip_bfloat16* ap = sA + row * 16 + ci0;
        #pragma unroll
        for (int j = 0; j < 4; ++j) {
            short8 a = *(const short8*)(ap + j * (18 * 16));   // +576B per y-col
            acc[j] = __builtin_amdgcn_mfma_f32_16x16x32_bf16(a, wreg[t2], acc[j], 0, 0, 0);
        }
    }

    if constexpr (MASK) {
        int base8[8];
        #pragma unroll
        for (int e = 0; e < 8; ++e) {
            int tap = kg * 8 + e;
            int kd = tap / 9;
            int rm = tap - kd * 9;
            int kh = rm / 3;
            int kw = rm - kh * 3;
            int idx = (dxw + kd) * 180 + (wyl + kh) * 18 + z + kw;
            base8[e] = (tap < 27) ? idx : 0;    // weight is 0 for tap>=27
        }
        short8 wm = ((const short8*)wBm)[lane];
        #pragma unroll
        for (int j = 0; j < 4; ++j) {
            short8 am;
            #pragma unroll
            for (int e = 0; e < 8; ++e) am[e] = (short)sM[base8[e] + j * 18];
            acc[j] = __builtin_amdgcn_mfma_f32_16x16x32_bf16(am, wm, acc[j], 0, 0, 0);
        }
    }

    // store; D: row z' = kg*4+r, col o = lane&15
    int o = lane & 15;
    int wx = x0 + dxw;
    int wy = y0 + wyl;
    #pragma unroll
    for (int j = 0; j < 4; ++j) {
        size_t rowbase;
        if constexpr (OUTPAD)
            rowbase = (size_t)(((b * PX + wx + 1) * PY) + (wy + j + 1)) * PZ + 1;
        else
            rowbase = (size_t)b * PL + ((size_t)wx * GY + (wy + j)) * GZ;
        #pragma unroll
        for (int r = 0; r < 4; ++r)
            out[(rowbase + kg * 4 + r) * 16 + o] = __float2bfloat16(acc[j][r]);
    }

    // fused BN stats (per-channel sum / sumsq)
    float s = 0.f, sq = 0.f;
    #pragma unroll
    for (int j = 0; j < 4; ++j)
        #pragma unroll
        for (int r = 0; r < 4; ++r) { float v = acc[j][r]; s += v; sq += v * v; }
    s  += __shfl_xor(s, 16);  s  += __shfl_xor(s, 32);
    sq += __shfl_xor(sq, 16); sq += __shfl_xor(sq, 32);
    if (lane < 16) { sred[w][lane] = s; sred[w][16 + lane] = sq; }
    __syncthreads();
    if (tid < 32) {
        float v2 = sred[0][tid] + sred[1][tid] + sred[2][tid] + sred[3][tid];
        atomicAdd(&stats[(size_t)(blockIdx.x & 63) * 32 + tid], v2);
    }
}

// ---------------- BN finalize ----------------
__global__ void occ_bnfin_kernel(const float* __restrict__ stats, const float* __restrict__ g,
                                 const float* __restrict__ bb, float* __restrict__ bn)
{
    int c = threadIdx.x;
    if (c >= 16) return;
    float s = 0.f, sq = 0.f;
    for (int k = 0; k < 64; ++k) { s += stats[k * 32 + c]; sq += stats[k * 32 + 16 + c]; }
    const float N = (float)(NB * PL);
    float mean = s / N;
    float var = sq / N - mean * mean;
    float scale = g[c] * rsqrtf(var + EPSF);
    bn[c] = scale;
    bn[16 + c] = bb[c] - mean * scale;
}

// ------- BN affine + GELU in-place on padded buffer, interior rows only -------
__global__ __launch_bounds__(256) void occ_bnact_kernel(__hip_bfloat16* __restrict__ buf,
                                                        const float* __restrict__ bn)
{
    __shared__ float sc[16], sh[16];
    int t = threadIdx.x;
    if (t < 16) sc[t] = bn[t];
    else if (t < 32) sh[t - 16] = bn[t];
    __syncthreads();
    size_t i = (size_t)blockIdx.x * 256 + t;      // interior voxel index < NB*PL
    int b = (int)(i / PL);
    size_t sp = i % PL;
    int x = (int)(sp / (GY * GZ));
    int r2 = (int)(sp % (GY * GZ));
    int y = r2 / GZ, z = r2 & 15;
    size_t pidx = (size_t)(((b * PX + x + 1) * PY) + (y + 1)) * PZ + (z + 1);
    short8* p = (short8*)(buf + pidx * 16);
    short8 v0 = p[0], v1 = p[1];
    #pragma unroll
    for (int e = 0; e < 8; ++e) {
        float a0 = gelu_exact(fmaf(bf2f(v0[e]), sc[e],     sh[e]));
        float a1 = gelu_exact(fmaf(bf2f(v1[e]), sc[8 + e], sh[8 + e]));
        v0[e] = (short)f2bf(a0);
        v1[e] = (short)f2bf(a1);
    }
    p[0] = v0; p[1] = v1;
}

// ---------------- conv3 1x1x1 (16 -> 20) with fused bn2+GELU ----------------
__global__ __launch_bounds__(256) void occ_conv3_kernel(const __hip_bfloat16* __restrict__ act,
                                                        const float* __restrict__ bn,
                                                        const float* __restrict__ w3,
                                                        const float* __restrict__ b3,
                                                        float* __restrict__ out)
{
    __shared__ float w[NCLS * 16];
    __shared__ float bb[NCLS];
    __shared__ float sc[16], sh[16];
    int t = threadIdx.x;
    for (int i = t; i < NCLS * 16; i += 256) w[i] = w3[i];
    if (t < NCLS) bb[t] = b3[t];
    if (t >= 32 && t < 48) sc[t - 32] = bn[t - 32];
    if (t >= 48 && t < 64) sh[t - 48] = bn[t - 32];
    __syncthreads();
    size_t i = (size_t)blockIdx.x * 256 + t;      // < NB*PL
    size_t b = i / PL, sp = i % PL;
    const short8* p = (const short8*)(act + i * 16);
    short8 v0 = p[0], v1 = p[1];
    float vi[16];
    #pragma unroll
    for (int e = 0; e < 8; ++e) {
        vi[e]     = gelu_exact(fmaf(bf2f(v0[e]), sc[e],     sh[e]));
        vi[8 + e] = gelu_exact(fmaf(bf2f(v1[e]), sc[8 + e], sh[8 + e]));
    }
    float* op = out + b * NCLS * PL + sp;
    #pragma unroll
    for (int cls = 0; cls < NCLS; ++cls) {
        float a = bb[cls];
        #pragma unroll
        for (int ci = 0; ci < 16; ++ci) a = fmaf(vi[ci], w[cls * 16 + ci], a);
        op[(size_t)cls * PL] = a;
    }
}

// ---------------- launch ----------------
extern "C" void kernel_launch(void* const* d_in, const int* in_sizes, int n_in,
                              void* d_out, int out_size, void* d_ws, size_t ws_size,
                              hipStream_t stream)
{
    const float* tokens = (const float*)d_in[0];
    const float* depth  = (const float*)d_in[1];
    const float* intr   = (const float*)d_in[2];
    const float* c2w    = (const float*)d_in[3];
    const float* l2w    = (const float*)d_in[4];
    const float* ln_g   = (const float*)d_in[5];
    const float* ln_b   = (const float*)d_in[6];
    const float* w1     = (const float*)d_in[7];
    const float* b1     = (const float*)d_in[8];
    const float* w2     = (const float*)d_in[9];
    const float* b2     = (const float*)d_in[10];
    const float* cv1w   = (const float*)d_in[11];
    const float* cv1b   = (const float*)d_in[12];
    const float* bn1g   = (const float*)d_in[13];
    const float* bn1b   = (const float*)d_in[14];
    const float* cv2w   = (const float*)d_in[15];
    const float* cv2b   = (const float*)d_in[16];
    const float* bn2g   = (const float*)d_in[17];
    const float* bn2b   = (const float*)d_in[18];
    const float* cv3w   = (const float*)d_in[19];
    const float* cv3b   = (const float*)d_in[20];

    if (ws_size < WS_FLOATS * sizeof(float)) return;

    float* ws   = (float*)d_ws;
    float* volf = ws + OFF_VOL;
    float* cntp = ws + OFF_CNT;
    float* st1  = ws + OFF_ST1;
    float* st2s = ws + OFF_ST2;
    float* mats = ws + OFF_MATS;
    __hip_bfloat16* wGm  = (__hip_bfloat16*)(ws + OFF_WGM);
    __hip_bfloat16* wA2  = (__hip_bfloat16*)(ws + OFF_WA2);
    float* c12  = ws + OFF_C12;
    __hip_bfloat16* wB1a = (__hip_bfloat16*)(ws + OFF_WB1A);
    __hip_bfloat16* wB1m = (__hip_bfloat16*)(ws + OFF_WB1M);
    __hip_bfloat16* wB2  = (__hip_bfloat16*)(ws + OFF_WB2);
    float* bnp1 = ws + OFF_BN1;
    float* bnp2 = ws + OFF_BN2;

    __hip_bfloat16* ob      = (__hip_bfloat16*)d_out;
    __hip_bfloat16* decn    = ob + DO_DECN;     // padded
    __hip_bfloat16* mskp    = ob + DO_MSK;      // padded
    __hip_bfloat16* staged2 = ob + DO_ST2;      // padded conv1 out
    float* dmean            = (float*)(ob + DO_DM);
    __hip_bfloat16* staged3 = (__hip_bfloat16*)(ws + OFF_VOL);  // unpadded conv2 out
    float* outp = (float*)d_out;

    hipMemsetAsync(ws, 0, ZERO_F * sizeof(float), stream);

    occ_prep_kernel<<<1, 256, 0, stream>>>(intr, c2w, l2w, w1, ln_g, ln_b, b1, w2,
                                           cv1w, cv2w, mats, wGm, wA2, c12,
                                           wB1a, wB1m, wB2);

    occ_depth_kernel<<<NT / 4, 256, 0, stream>>>(depth, dmean);

    const int TGBLK = (NT / 16 + 4) / 4;   // 257 blocks (4 waves x 16 tokens each)
    occ_tokgemm_kernel<<<TGBLK, 256, 0, stream>>>(
        tokens, dmean, wGm, wA2, c12, b2, mats, volf, cntp);

    occ_norm_kernel<<<(PROWS_TOT + 255) / 256, 256, 0, stream>>>(volf, cntp, decn, mskp, staged2);

    const int CGRID = NB * (GX / 2) * (GY / 8);   // 5000
    occ_conv_kernel<true, true><<<CGRID, 256, 0, stream>>>(decn, mskp, wB1a, wB1m, cv1b, staged2, st1);
    occ_bnfin_kernel<<<1, 16, 0, stream>>>(st1, bn1g, bn1b, bnp1);
    occ_bnact_kernel<<<5000, 256, 0, stream>>>(staged2, bnp1);

    occ_conv_kernel<false, false><<<CGRID, 256, 0, stream>>>(staged2, nullptr, wB2, nullptr, cv2b, staged3, st2s);
    occ_bnfin_kernel<<<1, 16, 0, stream>>>(st2s, bn2g, bn2b, bnp2);

    occ_conv3_kernel<<<5000, 256, 0, stream>>>(staged3, bnp2, cv3w, cv3b, outp);
}

// Round 7
// 190.693 us; speedup vs baseline: 12.7570x; 1.1198x over previous
//
#include <hip/hip_runtime.h>
#include <hip/hip_bf16.h>
#include <math.h>

// ---------------- problem constants ----------------
#define PATCH 14
#define HID   16
#define NCLS  20
#define GX    200
#define GY    200
#define GZ    16
#define NB    2
#define NCAM  6
#define PH    37
#define PW    37
#define NP    (PH*PW)
#define NT    (NB*NCAM*NP)         // 16428 tokens
#define TD    768
#define IMH   518
#define IMW   518
#define PL    ((size_t)GX*GY*GZ)   // 640000 voxels per batch
#define EPSF  1e-5f

// padded conv layout: [b][px 0..201][py 0..201][pz 0..17] rows of 16 ch
#define PX 202
#define PY 202
#define PZ 18
#define PROWS_TOT (NB*PX*PY*PZ)    // 1,468,944 rows

// ---------------- workspace layout (float units) ----------------
#define OFF_VOL   ((size_t)0)            // volf [b][sp][16] fp32 (aliased as staged3 bf16)
#define OFF_CNT   ((size_t)20480000)
#define OFF_ST1   ((size_t)21760000)
#define OFF_ST2   ((size_t)21762048)
#define ZERO_F    ((size_t)21764096)     // memset covers OFF_CNT..ZERO_F only
#define OFF_MATS  ((size_t)21764096)     // 144
#define OFF_WGM   ((size_t)21764240)     // 24*64*8 bf16 = 6,144 f
#define OFF_WA2   ((size_t)21770384)     // 64*8 bf16 = 256 f
#define OFF_C12   ((size_t)21770640)     // 32
#define OFF_WB1A  ((size_t)21770672)     // 3,584
#define OFF_WB1M  ((size_t)21774256)     // 256
#define OFF_WB2   ((size_t)21774512)     // 3,584
#define OFF_BN1   ((size_t)21778096)     // 32
#define OFF_BN2   ((size_t)21778128)     // 32
#define WS_FLOATS ((size_t)21778160)

// ---------------- d_out staging (bf16 units; dead before conv3 writes) ----------
#define DO_DECN ((size_t)0)                       // padded dec_in, 23,503,104
#define DO_MSK  ((size_t)23503104)                // padded mask rows, 1,468,944
#define DO_ST2  ((size_t)24972048)                // padded conv1 out, 23,503,104
#define DO_DM   ((size_t)48600000)                // dmean fp32[NT] = 32,856 bf16
                                                  // end 48,632,856 <= 51,200,000

typedef __attribute__((ext_vector_type(8))) short short8;
typedef __attribute__((ext_vector_type(4))) float floatx4;

__device__ __forceinline__ float gelu_exact(float x) {
    return 0.5f * x * (1.0f + erff(x * 0.70710678118654752f));
}
__device__ __forceinline__ unsigned short f2bf(float f) {
    __hip_bfloat16 h = __float2bfloat16(f);
    return __builtin_bit_cast(unsigned short, h);
}
__device__ __forceinline__ float bf2f(short u) {
    unsigned int b = ((unsigned int)(unsigned short)u) << 16;
    return __builtin_bit_cast(float, b);
}
__device__ __forceinline__ short8 zero8() {
    short8 z = {0,0,0,0,0,0,0,0};
    return z;
}

// shared geometry: token -> voxel (must match EXACTLY between zero-pass and tokgemm)
__device__ __forceinline__ bool tok_voxel(int tk, float dmr, const float* __restrict__ mats,
                                          int& b, size_t& sp)
{
    int bc = tk / NP;
    int p  = tk - bc * NP;
    b = bc / NCAM;
    int gy = p / PW, gx = p - gy * PW;
    const float* M = mats + bc * 12;
    float dm = fmaxf(dmr, 0.f);
    float u = (gx + 0.5f) * (float)PATCH;
    float v = (gy + 0.5f) * (float)PATCH;
    float lx = (M[0] * u + M[1] * v + M[2]) * dm + M[9];
    float ly = (M[3] * u + M[4] * v + M[5]) * dm + M[10];
    float lz = (M[6] * u + M[7] * v + M[8]) * dm + M[11];
    int cx = (int)floorf((lx + 40.0f) / 0.4f);
    int cy = (int)floorf((ly + 40.0f) / 0.4f);
    int cz = (int)floorf((lz + 1.0f) / 0.4f);
    bool valid = (dmr > 0.001f) &&
                 (unsigned)cx < (unsigned)GX &&
                 (unsigned)cy < (unsigned)GY &&
                 (unsigned)cz < (unsigned)GZ;
    sp = ((size_t)cx * GY + cy) * GZ + cz;
    return valid;
}

// ---------------- 3x3 / 4x4 inverse in double ----------------
__device__ void inv3d(const double* m, double* o) {
    double a=m[0],b=m[1],c=m[2],d=m[3],e=m[4],f=m[5],g=m[6],h=m[7],i=m[8];
    double A=e*i-f*h, B=-(d*i-f*g), C=d*h-e*g;
    double det=a*A+b*B+c*C, id=1.0/det;
    o[0]=A*id;            o[1]=-(b*i-c*h)*id;   o[2]=(b*f-c*e)*id;
    o[3]=B*id;            o[4]=(a*i-c*g)*id;    o[5]=-(a*f-c*d)*id;
    o[6]=C*id;            o[7]=-(a*h-b*g)*id;   o[8]=(a*e-b*d)*id;
}

__device__ void inv4d(const double* m, double* o) {
    double i0  =  m[5]*m[10]*m[15]-m[5]*m[11]*m[14]-m[9]*m[6]*m[15]+m[9]*m[7]*m[14]+m[13]*m[6]*m[11]-m[13]*m[7]*m[10];
    double i4  = -m[4]*m[10]*m[15]+m[4]*m[11]*m[14]+m[8]*m[6]*m[15]-m[8]*m[7]*m[14]-m[12]*m[6]*m[11]+m[12]*m[7]*m[10];
    double i8  =  m[4]*m[9]*m[15]-m[4]*m[11]*m[13]-m[8]*m[5]*m[15]+m[8]*m[7]*m[13]+m[12]*m[5]*m[11]-m[12]*m[7]*m[9];
    double i12 = -m[4]*m[9]*m[14]+m[4]*m[10]*m[13]+m[8]*m[5]*m[14]-m[8]*m[6]*m[13]-m[12]*m[5]*m[10]+m[12]*m[6]*m[9];
    double i1  = -m[1]*m[10]*m[15]+m[1]*m[11]*m[14]+m[9]*m[2]*m[15]-m[9]*m[3]*m[14]-m[13]*m[2]*m[11]+m[13]*m[3]*m[10];
    double i5  =  m[0]*m[10]*m[15]-m[0]*m[11]*m[14]-m[8]*m[2]*m[15]+m[8]*m[3]*m[14]+m[12]*m[2]*m[11]-m[12]*m[3]*m[10];
    double i9  = -m[0]*m[9]*m[15]+m[0]*m[11]*m[13]+m[8]*m[1]*m[15]-m[8]*m[3]*m[13]-m[12]*m[1]*m[11]+m[12]*m[3]*m[9];
    double i13 =  m[0]*m[9]*m[14]-m[0]*m[10]*m[13]-m[8]*m[1]*m[14]+m[8]*m[2]*m[13]+m[12]*m[1]*m[10]-m[12]*m[2]*m[9];
    double i2  =  m[1]*m[6]*m[15]-m[1]*m[7]*m[14]-m[5]*m[2]*m[15]+m[5]*m[3]*m[14]+m[13]*m[2]*m[7]-m[13]*m[3]*m[6];
    double i6  = -m[0]*m[6]*m[15]+m[0]*m[7]*m[14]+m[4]*m[2]*m[15]-m[4]*m[3]*m[14]-m[12]*m[2]*m[7]+m[12]*m[3]*m[6];
    double i10 =  m[0]*m[5]*m[15]-m[0]*m[7]*m[13]-m[4]*m[1]*m[15]+m[4]*m[3]*m[13]+m[12]*m[1]*m[7]-m[12]*m[3]*m[5];
    double i14 = -m[0]*m[5]*m[14]+m[0]*m[6]*m[13]+m[4]*m[1]*m[14]-m[4]*m[2]*m[13]-m[12]*m[1]*m[6]+m[12]*m[2]*m[5];
    double i3  = -m[1]*m[6]*m[11]+m[1]*m[7]*m[10]+m[5]*m[2]*m[11]-m[5]*m[3]*m[10]-m[9]*m[2]*m[7]+m[9]*m[3]*m[6];
    double i7  =  m[0]*m[6]*m[11]-m[0]*m[7]*m[10]-m[4]*m[2]*m[11]+m[4]*m[3]*m[10]+m[8]*m[2]*m[7]-m[8]*m[3]*m[6];
    double i11 = -m[0]*m[5]*m[11]+m[0]*m[7]*m[9]+m[4]*m[1]*m[11]-m[4]*m[3]*m[9]-m[8]*m[1]*m[7]+m[8]*m[3]*m[5];
    double i15 =  m[0]*m[5]*m[10]-m[0]*m[6]*m[9]-m[4]*m[1]*m[10]+m[4]*m[2]*m[9]+m[8]*m[1]*m[6]-m[8]*m[2]*m[5];
    double det = m[0]*i0+m[1]*i4+m[2]*i8+m[3]*i12;
    double id = 1.0/det;
    o[0]=i0*id; o[1]=i1*id; o[2]=i2*id; o[3]=i3*id;
    o[4]=i4*id; o[5]=i5*id; o[6]=i6*id; o[7]=i7*id;
    o[8]=i8*id; o[9]=i9*id; o[10]=i10*id; o[11]=i11*id;
    o[12]=i12*id; o[13]=i13*id; o[14]=i14*id; o[15]=i15*id;
}

// ---------------- precompute ----------------
__global__ void occ_prep_kernel(const float* __restrict__ intr, const float* __restrict__ c2w,
                                const float* __restrict__ l2w, const float* __restrict__ w1,
                                const float* __restrict__ ln_g, const float* __restrict__ ln_b,
                                const float* __restrict__ b1, const float* __restrict__ w2,
                                const float* __restrict__ cw1, const float* __restrict__ cw2,
                                float* __restrict__ mats, __hip_bfloat16* __restrict__ wGm,
                                __hip_bfloat16* __restrict__ wA2, float* __restrict__ c12,
                                __hip_bfloat16* __restrict__ wB1a, __hip_bfloat16* __restrict__ wB1m,
                                __hip_bfloat16* __restrict__ wB2)
{
    int t = threadIdx.x;
    if (t < NB * NCAM) {
        int b = t / NCAM;
        double K[9], Ki[9], L[16], Li[16], C[16], M[16], A[9];
        #pragma unroll
        for (int i = 0; i < 9; ++i) K[i] = (double)intr[t * 9 + i];
        inv3d(K, Ki);
        #pragma unroll
        for (int i = 0; i < 16; ++i) L[i] = (double)l2w[b * 16 + i];
        inv4d(L, Li);
        #pragma unroll
        for (int i = 0; i < 16; ++i) C[i] = (double)c2w[t * 16 + i];
        #pragma unroll
        for (int r = 0; r < 4; ++r)
            #pragma unroll
            for (int c = 0; c < 4; ++c) {
                double s = 0.0;
                #pragma unroll
                for (int k = 0; k < 4; ++k) s += Li[r * 4 + k] * C[k * 4 + c];
                M[r * 4 + c] = s;
            }
        #pragma unroll
        for (int r = 0; r < 3; ++r)
            #pragma unroll
            for (int c = 0; c < 3; ++c) {
                double s = 0.0;
                #pragma unroll
                for (int k = 0; k < 3; ++k) s += M[r * 4 + k] * Ki[k * 3 + c];
                A[r * 3 + c] = s;
            }
        #pragma unroll
        for (int i = 0; i < 9; ++i) mats[t * 12 + i] = (float)A[i];
        mats[t * 12 + 9]  = (float)M[3];
        mats[t * 12 + 10] = (float)M[7];
        mats[t * 12 + 11] = (float)M[11];
    }
    // token GEMM1 B-fragments: wGm[step][lane][8], k = d = step*32 + 8*kg + e, col j = lane&15
    for (int i = t; i < 24 * 64 * 8; i += 256) {
        int st = i >> 9; int ln = (i >> 3) & 63; int e = i & 7;
        int kg = ln >> 4, j = ln & 15;
        int d = st * 32 + kg * 8 + e;
        wGm[i] = __float2bfloat16(ln_g[d] * w1[d * 16 + j]);
    }
    // token GEMM2 A-fragment: w2^T, m = ch = lane&15, k = hid = 8*kg+e (valid k<16)
    for (int i = t; i < 64 * 8; i += 256) {
        int ln = i >> 3; int e = i & 7;
        int kg = ln >> 4, ch = ln & 15;
        int k = kg * 8 + e;
        wA2[i] = __float2bfloat16((k < 16) ? w2[k * 16 + ch] : 0.f);
    }
    // c1_j = sum_d round_bf16(g_d*w1_dj) ; c2'_j = sum_d b_d*w1_dj + b1_j
    if (t < 16) {
        float c1 = 0.f, c2p = 0.f;
        for (int d = 0; d < TD; ++d) {
            c1  += bf2f((short)f2bf(ln_g[d] * w1[d * 16 + t]));
            c2p += ln_b[d] * w1[d * 16 + t];
        }
        c12[t] = c1;
        c12[16 + t] = c2p + b1[t];
    }
    // conv1 main (16 vol channels): wB1a[t2][lane][8]; K packs 2 taps x 16 ch
    for (int i = t; i < 14 * 64 * 8; i += 256) {
        int t2 = i >> 9; int r = i & 511; int ln = r >> 3; int e = r & 7;
        int kg = ln >> 4;
        int tt = 2 * t2 + (kg >> 1);
        int ci = ((kg & 1) << 3) + e;
        int o = ln & 15;
        float val = (tt < 27) ? cw1[(o * 17 + ci) * 27 + tt] : 0.f;
        wB1a[i] = __float2bfloat16(val);
    }
    // conv1 mask channel (ci=16): wB1m[lane][8]; K slot = tap index
    for (int i = t; i < 64 * 8; i += 256) {
        int ln = i >> 3; int e = i & 7;
        int k = ((ln >> 4) << 3) + e;
        int o = ln & 15;
        float val = (k < 27) ? cw1[(o * 17 + 16) * 27 + k] : 0.f;
        wB1m[i] = __float2bfloat16(val);
    }
    // conv2: wB2[t2][lane][8]
    for (int i = t; i < 14 * 64 * 8; i += 256) {
        int t2 = i >> 9; int r = i & 511; int ln = r >> 3; int e = r & 7;
        int kg = ln >> 4;
        int tt = 2 * t2 + (kg >> 1);
        int ci = ((kg & 1) << 3) + e;
        int o = ln & 15;
        float val = (tt < 27) ? cw2[(o * 16 + ci) * 27 + tt] : 0.f;
        wB2[i] = __float2bfloat16(val);
    }
}

// ---------------- depth patch means: one wave per token ----------------
__global__ __launch_bounds__(256) void occ_depth_kernel(const float* __restrict__ depth,
                                                        float* __restrict__ dmean)
{
    int tid = threadIdx.x;
    int l = tid & 63;
    int g = blockIdx.x * 4 + (tid >> 6);     // 4107 blocks * 4 = 16428 exactly
    int bc = g / NP;
    int p  = g - bc * NP;
    int gy = p / PW, gx = p - gy * PW;
    const float* dbase = depth + (size_t)bc * (IMH * IMW);
    int rbase = gy * PATCH, cb = gx * PATCH;
    float dsum = 0.f;
    #pragma unroll
    for (int i = 0; i < 3; ++i) {
        int idx = l + 64 * i;
        int py = idx / 14;
        int px = idx - py * 14;
        dsum += dbase[(size_t)(rbase + py) * IMW + (cb + px)];
    }
    if (l < 4)
        dsum += dbase[(size_t)(rbase + 13) * IMW + (cb + 10 + l)];
    #pragma unroll
    for (int m = 1; m <= 32; m <<= 1) dsum += __shfl_xor(dsum, m);
    if (l == 0) dmean[g] = dsum * (1.0f / 196.0f);
}

// ------- scatter-zero: zero exactly the vol rows that will receive adds -------
__global__ __launch_bounds__(256) void occ_zerovol_kernel(
    const float* __restrict__ dmean, const float* __restrict__ mats,
    float* __restrict__ vol)
{
    int tk = blockIdx.x * 256 + threadIdx.x;
    if (tk >= NT) return;
    int b; size_t sp;
    if (tok_voxel(tk, dmean[tk], mats, b, sp)) {
        float4* p = (float4*)(vol + ((size_t)b * PL + sp) * 16);
        float4 z = {0.f, 0.f, 0.f, 0.f};
        p[0] = z; p[1] = z; p[2] = z; p[3] = z;
    }
}

// ------- token GEMM: LN folded into epilogue; 16 tokens per wave; MFMA -------
__global__ __launch_bounds__(256) void occ_tokgemm_kernel(
    const float* __restrict__ tokens, const float* __restrict__ dmean,
    const __hip_bfloat16* __restrict__ wGm, const __hip_bfloat16* __restrict__ wA2,
    const float* __restrict__ c12, const float* __restrict__ b2,
    const float* __restrict__ mats, float* __restrict__ vol, float* __restrict__ cnt)
{
    int tid = threadIdx.x;
    int w = tid >> 6, lane = tid & 63;
    int tile = (blockIdx.x * 4 + w) * 16;
    int j16 = lane & 15, kg = lane >> 4;

    __shared__ __hip_bfloat16 sH[4][16][16];

    int tka  = tile + j16;
    int tkac = min(tka, NT - 1);

    const float* tokp = tokens + (size_t)tkac * TD + (kg << 3);
    const short8* wg8 = (const short8*)wGm;

    floatx4 acc = {0.f, 0.f, 0.f, 0.f};
    float s = 0.f, sq = 0.f;
    #pragma unroll
    for (int st = 0; st < 24; ++st) {
        float4 xa = *(const float4*)(tokp + st * 32);
        float4 xb = *(const float4*)(tokp + st * 32 + 4);
        s += xa.x + xa.y + xa.z + xa.w + xb.x + xb.y + xb.z + xb.w;
        sq = fmaf(xa.x, xa.x, sq); sq = fmaf(xa.y, xa.y, sq);
        sq = fmaf(xa.z, xa.z, sq); sq = fmaf(xa.w, xa.w, sq);
        sq = fmaf(xb.x, xb.x, sq); sq = fmaf(xb.y, xb.y, sq);
        sq = fmaf(xb.z, xb.z, sq); sq = fmaf(xb.w, xb.w, sq);
        short8 a;
        a[0] = (short)f2bf(xa.x); a[1] = (short)f2bf(xa.y);
        a[2] = (short)f2bf(xa.z); a[3] = (short)f2bf(xa.w);
        a[4] = (short)f2bf(xb.x); a[5] = (short)f2bf(xb.y);
        a[6] = (short)f2bf(xb.z); a[7] = (short)f2bf(xb.w);
        acc = __builtin_amdgcn_mfma_f32_16x16x32_bf16(a, wg8[st * 64 + lane], acc, 0, 0, 0);
    }
    // stats for token j16 (dims split across kg groups)
    s  += __shfl_xor(s, 16);  s  += __shfl_xor(s, 32);
    sq += __shfl_xor(sq, 16); sq += __shfl_xor(sq, 32);
    float mu = s * (1.0f / (float)TD);
    float rs = rsqrtf(sq * (1.0f / (float)TD) - mu * mu + EPSF);

    // epilogue: h_j = rs*(acc - mu*c1_j) + c2'_j ; gelu ; stash h1 in LDS
    float c1  = c12[j16];
    float c2p = c12[16 + j16];
    #pragma unroll
    for (int r = 0; r < 4; ++r) {
        int srcl = kg * 4 + r;                 // row token within the 16-group
        float mur = __shfl(mu, srcl, 16);
        float rsr = __shfl(rs, srcl, 16);
        float h = rsr * (acc[r] - mur * c1) + c2p;
        sH[w][srcl][j16] = __float2bfloat16(gelu_exact(h));
    }
    __syncthreads();

    // GEMM2: D2[ch][token] = w2^T @ h1^T + b2
    short8 hb = zero8();
    if (kg < 2) hb = *(const short8*)&sH[w][j16][kg * 8];
    floatx4 acc2;
    acc2[0] = b2[kg * 4 + 0]; acc2[1] = b2[kg * 4 + 1];
    acc2[2] = b2[kg * 4 + 2]; acc2[3] = b2[kg * 4 + 3];
    short8 a2 = ((const short8*)wA2)[lane];
    acc2 = __builtin_amdgcn_mfma_f32_16x16x32_bf16(a2, hb, acc2, 0, 0, 0);

    // geometry + scatter: lane owns token tile+j16, channels kg*4 .. kg*4+3
    int b; size_t sp;
    bool valid = tok_voxel(tkac, dmean[tkac], mats, b, sp) && (tka < NT);
    if (valid) {
        float* base = vol + ((size_t)b * PL + sp) * 16 + kg * 4;
        atomicAdd(base + 0, acc2[0]);
        atomicAdd(base + 1, acc2[1]);
        atomicAdd(base + 2, acc2[2]);
        atomicAdd(base + 3, acc2[3]);
        if (kg == 0) atomicAdd(cnt + (size_t)b * PL + sp, 1.0f);
    }
}

// ------- norm+halo: vol/cnt -> padded bf16 dec_in + mask; zero halos;
//         cnt==0 fast path writes zeros WITHOUT reading vol -------
__global__ __launch_bounds__(256) void occ_norm_kernel(
    const float* __restrict__ volf, const float* __restrict__ cnt,
    __hip_bfloat16* __restrict__ decn, __hip_bfloat16* __restrict__ msk,
    __hip_bfloat16* __restrict__ st2)
{
    size_t i = (size_t)blockIdx.x * 256 + threadIdx.x;   // padded row index
    if (i >= (size_t)PROWS_TOT) return;
    int pz = (int)(i % PZ);
    size_t t1 = i / PZ;
    int py = (int)(t1 % PY);
    size_t t2 = t1 / PY;
    int px = (int)(t2 % PX);
    int b  = (int)(t2 / PX);
    bool interior = (px >= 1) && (px <= GX) && (py >= 1) && (py <= GY) &&
                    (pz >= 1) && (pz <= GZ);
    short8* dp = (short8*)(decn + i * 16);
    if (interior) {
        size_t vi = (size_t)b * PL + (((size_t)(px - 1) * GY + (py - 1)) * GZ + (pz - 1));
        float cn = cnt[vi];
        if (cn > 0.f) {
            float inv = 1.0f / cn;
            const float4* vp = (const float4*)(volf + vi * 16);
            float4 f0 = vp[0], f1 = vp[1], f2 = vp[2], f3 = vp[3];
            short8 o0, o1;
            o0[0] = (short)f2bf(f0.x * inv); o0[1] = (short)f2bf(f0.y * inv);
            o0[2] = (short)f2bf(f0.z * inv); o0[3] = (short)f2bf(f0.w * inv);
            o0[4] = (short)f2bf(f1.x * inv); o0[5] = (short)f2bf(f1.y * inv);
            o0[6] = (short)f2bf(f1.z * inv); o0[7] = (short)f2bf(f1.w * inv);
            o1[0] = (short)f2bf(f2.x * inv); o1[1] = (short)f2bf(f2.y * inv);
            o1[2] = (short)f2bf(f2.z * inv); o1[3] = (short)f2bf(f2.w * inv);
            o1[4] = (short)f2bf(f3.x * inv); o1[5] = (short)f2bf(f3.y * inv);
            o1[6] = (short)f2bf(f3.z * inv); o1[7] = (short)f2bf(f3.w * inv);
            dp[0] = o0; dp[1] = o1;
            msk[i] = __float2bfloat16(1.f);
        } else {
            // no scatter landed here -> true vol is exactly 0
            dp[0] = zero8(); dp[1] = zero8();
            msk[i] = __float2bfloat16(0.f);
        }
    } else {
        dp[0] = zero8(); dp[1] = zero8();
        msk[i] = __float2bfloat16(0.f);
        short8* sp2 = (short8*)(st2 + i * 16);
        sp2[0] = zero8(); sp2[1] = zero8();
    }
}

// ------- conv3d 3x3x3 via MFMA, LDS-staged 4x8 tile (4 waves x 8 y-cols) -------
template <bool MASK, bool OUTPAD>
__global__ __launch_bounds__(256, 4) void occ_conv_kernel(
    const __hip_bfloat16* __restrict__ in, const __hip_bfloat16* __restrict__ msk,
    const __hip_bfloat16* __restrict__ wBa, const __hip_bfloat16* __restrict__ wBm,
    const float* __restrict__ bias, __hip_bfloat16* __restrict__ out,
    float* __restrict__ stats)
{
    // 2500 blocks = NB * (GX/4) * (GY/8); bijective XCD swizzle (2500 = 4*313 + 4*312)
    int bid = blockIdx.x;
    int xcd = bid & 7, off = bid >> 3;
    int blk = (xcd < 4 ? xcd * 313 : 4 * 313 + (xcd - 4) * 312) + off;
    int b   = blk / 1250;
    int rem = blk % 1250;
    int x0  = (rem / 25) * 4;
    int y0  = (rem % 25) * 8;
    int tid = threadIdx.x;

    __shared__ __hip_bfloat16 sA[1080 * 16];    // 6x10x18 rows of 16ch = 34,560 B
    __shared__ unsigned short sM[1080];
    __shared__ float sred[4][32];

    // cooperative stage: rows (dx, dy*18+dz) contiguous per x-slab
    {
        const short8* gin = (const short8*)in;
        short8* sa8 = (short8*)sA;
        for (int ii = tid; ii < 1080; ii += 256) {
            int dx = ii / 180;
            int r2 = ii - dx * 180;
            size_t grow = ((size_t)((b * PX + x0 + dx) * PY + y0) * PZ) + r2;
            sa8[ii * 2]     = gin[grow * 2];
            sa8[ii * 2 + 1] = gin[grow * 2 + 1];
            if constexpr (MASK)
                sM[ii] = *(const unsigned short*)(msk + grow);
        }
    }
    __syncthreads();

    int w = tid >> 6, lane = tid & 63;
    int z = lane & 15, kg = lane >> 4;
    int ci0 = (kg & 1) << 3;
    bool halfsel = kg >= 2;

    // preload weight fragments (loop-invariant)
    const short8* wp = (const short8*)wBa;
    short8 wreg[14];
    #pragma unroll
    for (int t2 = 0; t2 < 14; ++t2) wreg[t2] = wp[t2 * 64 + lane];

    float bo = bias[lane & 15];
    floatx4 acc[8];
    #pragma unroll
    for (int j = 0; j < 8; ++j) { acc[j][0]=bo; acc[j][1]=bo; acc[j][2]=bo; acc[j][3]=bo; }

    #pragma unroll
    for (int t2 = 0; t2 < 14; ++t2) {
        const int ta = 2 * t2;
        const int tb = (2 * t2 + 1 > 26) ? 26 : 2 * t2 + 1;
        const int kda = ta / 9, kha = (ta / 3) % 3, kwa = ta % 3;
        const int kdb = tb / 9, khb = (tb / 3) % 3, kwb = tb % 3;
        int rowA = (w + kda) * 180 + kha * 18 + (z + kwa);
        int rowB = (w + kdb) * 180 + khb * 18 + (z + kwb);
        int row = halfsel ? rowB : rowA;
        const __hip_bfloat16* ap = sA + row * 16 + ci0;
        #pragma unroll
        for (int j = 0; j < 8; ++j) {
            short8 a = *(const short8*)(ap + j * (18 * 16));   // +576B per y-col
            acc[j] = __builtin_amdgcn_mfma_f32_16x16x32_bf16(a, wreg[t2], acc[j], 0, 0, 0);
        }
    }

    if constexpr (MASK) {
        int base8[8];
        #pragma unroll
        for (int e = 0; e < 8; ++e) {
            int tap = kg * 8 + e;
            int kd = tap / 9;
            int rm = tap - kd * 9;
            int kh = rm / 3;
            int kw = rm - kh * 3;
            int idx = (w + kd) * 180 + kh * 18 + z + kw;
            base8[e] = (tap < 27) ? idx : 0;    // weight is 0 for tap>=27
        }
        short8 wm = ((const short8*)wBm)[lane];
        #pragma unroll
        for (int j = 0; j < 8; ++j) {
            short8 am;
            #pragma unroll
            for (int e = 0; e < 8; ++e) am[e] = (short)sM[base8[e] + j * 18];
            acc[j] = __builtin_amdgcn_mfma_f32_16x16x32_bf16(am, wm, acc[j], 0, 0, 0);
        }
    }

    // store; D: row z' = kg*4+r, col o = lane&15
    int o = lane & 15;
    int wx = x0 + w;
    #pragma unroll
    for (int j = 0; j < 8; ++j) {
        int wy = y0 + j;
        size_t rowbase;
        if constexpr (OUTPAD)
            rowbase = (size_t)(((b * PX + wx + 1) * PY) + (wy + 1)) * PZ + 1;
        else
            rowbase = (size_t)b * PL + ((size_t)wx * GY + wy) * GZ;
        #pragma unroll
        for (int r = 0; r < 4; ++r)
            out[(rowbase + kg * 4 + r) * 16 + o] = __float2bfloat16(acc[j][r]);
    }

    // fused BN stats (per-channel sum / sumsq)
    float s = 0.f, sq = 0.f;
    #pragma unroll
    for (int j = 0; j < 8; ++j)
        #pragma unroll
        for (int r = 0; r < 4; ++r) { float v = acc[j][r]; s += v; sq += v * v; }
    s  += __shfl_xor(s, 16);  s  += __shfl_xor(s, 32);
    sq += __shfl_xor(sq, 16); sq += __shfl_xor(sq, 32);
    if (lane < 16) { sred[w][lane] = s; sred[w][16 + lane] = sq; }
    __syncthreads();
    if (tid < 32) {
        float v2 = sred[0][tid] + sred[1][tid] + sred[2][tid] + sred[3][tid];
        atomicAdd(&stats[(size_t)(blockIdx.x & 63) * 32 + tid], v2);
    }
}

// ---------------- BN finalize ----------------
__global__ void occ_bnfin_kernel(const float* __restrict__ stats, const float* __restrict__ g,
                                 const float* __restrict__ bb, float* __restrict__ bn)
{
    int c = threadIdx.x;
    if (c >= 16) return;
    float s = 0.f, sq = 0.f;
    for (int k = 0; k < 64; ++k) { s += stats[k * 32 + c]; sq += stats[k * 32 + 16 + c]; }
    const float N = (float)(NB * PL);
    float mean = s / N;
    float var = sq / N - mean * mean;
    float scale = g[c] * rsqrtf(var + EPSF);
    bn[c] = scale;
    bn[16 + c] = bb[c] - mean * scale;
}

// ------- BN affine + GELU in-place on padded buffer, interior rows only -------
__global__ __launch_bounds__(256) void occ_bnact_kernel(__hip_bfloat16* __restrict__ buf,
                                                        const float* __restrict__ bn)
{
    __shared__ float sc[16], sh[16];
    int t = threadIdx.x;
    if (t < 16) sc[t] = bn[t];
    else if (t < 32) sh[t - 16] = bn[t];
    __syncthreads();
    size_t i = (size_t)blockIdx.x * 256 + t;      // interior voxel index < NB*PL
    int b = (int)(i / PL);
    size_t sp = i % PL;
    int x = (int)(sp / (GY * GZ));
    int r2 = (int)(sp % (GY * GZ));
    int y = r2 / GZ, z = r2 & 15;
    size_t pidx = (size_t)(((b * PX + x + 1) * PY) + (y + 1)) * PZ + (z + 1);
    short8* p = (short8*)(buf + pidx * 16);
    short8 v0 = p[0], v1 = p[1];
    #pragma unroll
    for (int e = 0; e < 8; ++e) {
        float a0 = gelu_exact(fmaf(bf2f(v0[e]), sc[e],     sh[e]));
        float a1 = gelu_exact(fmaf(bf2f(v1[e]), sc[8 + e], sh[8 + e]));
        v0[e] = (short)f2bf(a0);
        v1[e] = (short)f2bf(a1);
    }
    p[0] = v0; p[1] = v1;
}

// ---------------- conv3 1x1x1 (16 -> 20) with fused bn2+GELU ----------------
__global__ __launch_bounds__(256) void occ_conv3_kernel(const __hip_bfloat16* __restrict__ act,
                                                        const float* __restrict__ bn,
                                                        const float* __restrict__ w3,
                                                        const float* __restrict__ b3,
                                                        float* __restrict__ out)
{
    __shared__ float w[NCLS * 16];
    __shared__ float bb[NCLS];
    __shared__ float sc[16], sh[16];
    int t = threadIdx.x;
    for (int i = t; i < NCLS * 16; i += 256) w[i] = w3[i];
    if (t < NCLS) bb[t] = b3[t];
    if (t >= 32 && t < 48) sc[t - 32] = bn[t - 32];
    if (t >= 48 && t < 64) sh[t - 48] = bn[t - 32];
    __syncthreads();
    size_t i = (size_t)blockIdx.x * 256 + t;      // < NB*PL
    size_t b = i / PL, sp = i % PL;
    const short8* p = (const short8*)(act + i * 16);
    short8 v0 = p[0], v1 = p[1];
    float vi[16];
    #pragma unroll
    for (int e = 0; e < 8; ++e) {
        vi[e]     = gelu_exact(fmaf(bf2f(v0[e]), sc[e],     sh[e]));
        vi[8 + e] = gelu_exact(fmaf(bf2f(v1[e]), sc[8 + e], sh[8 + e]));
    }
    float* op = out + b * NCLS * PL + sp;
    #pragma unroll
    for (int cls = 0; cls < NCLS; ++cls) {
        float a = bb[cls];
        #pragma unroll
        for (int ci = 0; ci < 16; ++ci) a = fmaf(vi[ci], w[cls * 16 + ci], a);
        op[(size_t)cls * PL] = a;
    }
}

// ---------------- launch ----------------
extern "C" void kernel_launch(void* const* d_in, const int* in_sizes, int n_in,
                              void* d_out, int out_size, void* d_ws, size_t ws_size,
                              hipStream_t stream)
{
    const float* tokens = (const float*)d_in[0];
    const float* depth  = (const float*)d_in[1];
    const float* intr   = (const float*)d_in[2];
    const float* c2w    = (const float*)d_in[3];
    const float* l2w    = (const float*)d_in[4];
    const float* ln_g   = (const float*)d_in[5];
    const float* ln_b   = (const float*)d_in[6];
    const float* w1     = (const float*)d_in[7];
    const float* b1     = (const float*)d_in[8];
    const float* w2     = (const float*)d_in[9];
    const float* b2     = (const float*)d_in[10];
    const float* cv1w   = (const float*)d_in[11];
    const float* cv1b   = (const float*)d_in[12];
    const float* bn1g   = (const float*)d_in[13];
    const float* bn1b   = (const float*)d_in[14];
    const float* cv2w   = (const float*)d_in[15];
    const float* cv2b   = (const float*)d_in[16];
    const float* bn2g   = (const float*)d_in[17];
    const float* bn2b   = (const float*)d_in[18];
    const float* cv3w   = (const float*)d_in[19];
    const float* cv3b   = (const float*)d_in[20];

    if (ws_size < WS_FLOATS * sizeof(float)) return;

    float* ws   = (float*)d_ws;
    float* volf = ws + OFF_VOL;
    float* cntp = ws + OFF_CNT;
    float* st1  = ws + OFF_ST1;
    float* st2s = ws + OFF_ST2;
    float* mats = ws + OFF_MATS;
    __hip_bfloat16* wGm  = (__hip_bfloat16*)(ws + OFF_WGM);
    __hip_bfloat16* wA2  = (__hip_bfloat16*)(ws + OFF_WA2);
    float* c12  = ws + OFF_C12;
    __hip_bfloat16* wB1a = (__hip_bfloat16*)(ws + OFF_WB1A);
    __hip_bfloat16* wB1m = (__hip_bfloat16*)(ws + OFF_WB1M);
    __hip_bfloat16* wB2  = (__hip_bfloat16*)(ws + OFF_WB2);
    float* bnp1 = ws + OFF_BN1;
    float* bnp2 = ws + OFF_BN2;

    __hip_bfloat16* ob      = (__hip_bfloat16*)d_out;
    __hip_bfloat16* decn    = ob + DO_DECN;     // padded
    __hip_bfloat16* mskp    = ob + DO_MSK;      // padded
    __hip_bfloat16* staged2 = ob + DO_ST2;      // padded conv1 out
    float* dmean            = (float*)(ob + DO_DM);
    __hip_bfloat16* staged3 = (__hip_bfloat16*)(ws + OFF_VOL);  // unpadded conv2 out
    float* outp = (float*)d_out;

    // zero only cnt + BN-stat accumulators (5.1 MB); vol rows are zeroed by
    // the scatter-zero pass (norm never reads vol where cnt==0)
    hipMemsetAsync(ws + OFF_CNT, 0, (ZERO_F - OFF_CNT) * sizeof(float), stream);

    occ_prep_kernel<<<1, 256, 0, stream>>>(intr, c2w, l2w, w1, ln_g, ln_b, b1, w2,
                                           cv1w, cv2w, mats, wGm, wA2, c12,
                                           wB1a, wB1m, wB2);

    occ_depth_kernel<<<NT / 4, 256, 0, stream>>>(depth, dmean);

    occ_zerovol_kernel<<<(NT + 255) / 256, 256, 0, stream>>>(dmean, mats, volf);

    const int TGBLK = (NT / 16 + 4) / 4;   // 257 blocks (4 waves x 16 tokens each)
    occ_tokgemm_kernel<<<TGBLK, 256, 0, stream>>>(
        tokens, dmean, wGm, wA2, c12, b2, mats, volf, cntp);

    occ_norm_kernel<<<(PROWS_TOT + 255) / 256, 256, 0, stream>>>(volf, cntp, decn, mskp, staged2);

    const int CGRID = NB * (GX / 4) * (GY / 8);   // 2500
    occ_conv_kernel<true, true><<<CGRID, 256, 0, stream>>>(decn, mskp, wB1a, wB1m, cv1b, staged2, st1);
    occ_bnfin_kernel<<<1, 16, 0, stream>>>(st1, bn1g, bn1b, bnp1);
    occ_bnact_kernel<<<5000, 256, 0, stream>>>(staged2, bnp1);

    occ_conv_kernel<false, false><<<CGRID, 256, 0, stream>>>(staged2, nullptr, wB2, nullptr, cv2b, staged3, st2s);
    occ_bnfin_kernel<<<1, 16, 0, stream>>>(st2s, bn2g, bn2b, bnp2);

    occ_conv3_kernel<<<5000, 256, 0, stream>>>(staged3, bnp2, cv3w, cv3b, outp);
}

// Round 8
// 154.648 us; speedup vs baseline: 15.7303x; 1.2331x over previous
//
#include <hip/hip_runtime.h>
#include <hip/hip_bf16.h>
#include <math.h>

// ---------------- problem constants ----------------
#define PATCH 14
#define HID   16
#define NCLS  20
#define GX    200
#define GY    200
#define GZ    16
#define NB    2
#define NCAM  6
#define PH    37
#define PW    37
#define NP    (PH*PW)
#define NT    (NB*NCAM*NP)         // 16428 tokens
#define TD    768
#define IMH   518
#define IMW   518
#define PL    ((size_t)GX*GY*GZ)   // 640000 voxels per batch
#define EPSF  1e-5f

// padded conv layout: [b][px 0..201][py 0..201][pz 0..17] rows of 16 ch
#define PX 202
#define PY 202
#define PZ 18

// ---------------- workspace layout (float units) ----------------
#define OFF_VOL   ((size_t)0)            // volf [b][sp][16] fp32 (aliased as staged3 bf16)
#define OFF_CNT   ((size_t)20480000)
#define OFF_ST1   ((size_t)21760000)
#define OFF_ST2   ((size_t)21762048)
#define ZERO_F    ((size_t)21764096)     // memset covers OFF_CNT..ZERO_F only
#define OFF_MATS  ((size_t)21764096)     // 144
#define OFF_WGM   ((size_t)21764240)     // 24*64*8 bf16 = 6,144 f
#define OFF_WA2   ((size_t)21770384)     // 64*8 bf16 = 256 f
#define OFF_C12   ((size_t)21770640)     // 32
#define OFF_WB1A  ((size_t)21770672)     // 3,584
#define OFF_WB1M  ((size_t)21774256)     // 256
#define OFF_WB2   ((size_t)21774512)     // 3,584
#define OFF_BN1   ((size_t)21778096)     // 32
#define OFF_BN2   ((size_t)21778128)     // 32
#define WS_FLOATS ((size_t)21778160)

// ---------------- d_out staging (bf16 units; dead before conv3 writes) ----------
#define DO_ST2  ((size_t)0)                       // padded conv1 out, 23,503,104
#define DO_DM   ((size_t)23503104)                // dmean fp32[NT] = 32,856 bf16
                                                  // end 23,535,960 <= 51,200,000

typedef __attribute__((ext_vector_type(8))) short short8;
typedef __attribute__((ext_vector_type(4))) float floatx4;

__device__ __forceinline__ float gelu_exact(float x) {
    return 0.5f * x * (1.0f + erff(x * 0.70710678118654752f));
}
__device__ __forceinline__ unsigned short f2bf(float f) {
    __hip_bfloat16 h = __float2bfloat16(f);
    return __builtin_bit_cast(unsigned short, h);
}
__device__ __forceinline__ float bf2f(short u) {
    unsigned int b = ((unsigned int)(unsigned short)u) << 16;
    return __builtin_bit_cast(float, b);
}
__device__ __forceinline__ short8 zero8() {
    short8 z = {0,0,0,0,0,0,0,0};
    return z;
}

// shared geometry: token -> voxel (must match EXACTLY between zero-pass and tokgemm)
__device__ __forceinline__ bool tok_voxel(int tk, float dmr, const float* __restrict__ mats,
                                          int& b, size_t& sp)
{
    int bc = tk / NP;
    int p  = tk - bc * NP;
    b = bc / NCAM;
    int gy = p / PW, gx = p - gy * PW;
    const float* M = mats + bc * 12;
    float dm = fmaxf(dmr, 0.f);
    float u = (gx + 0.5f) * (float)PATCH;
    float v = (gy + 0.5f) * (float)PATCH;
    float lx = (M[0] * u + M[1] * v + M[2]) * dm + M[9];
    float ly = (M[3] * u + M[4] * v + M[5]) * dm + M[10];
    float lz = (M[6] * u + M[7] * v + M[8]) * dm + M[11];
    int cx = (int)floorf((lx + 40.0f) / 0.4f);
    int cy = (int)floorf((ly + 40.0f) / 0.4f);
    int cz = (int)floorf((lz + 1.0f) / 0.4f);
    bool valid = (dmr > 0.001f) &&
                 (unsigned)cx < (unsigned)GX &&
                 (unsigned)cy < (unsigned)GY &&
                 (unsigned)cz < (unsigned)GZ;
    sp = ((size_t)cx * GY + cy) * GZ + cz;
    return valid;
}

// ---------------- 3x3 / 4x4 inverse in double ----------------
__device__ void inv3d(const double* m, double* o) {
    double a=m[0],b=m[1],c=m[2],d=m[3],e=m[4],f=m[5],g=m[6],h=m[7],i=m[8];
    double A=e*i-f*h, B=-(d*i-f*g), C=d*h-e*g;
    double det=a*A+b*B+c*C, id=1.0/det;
    o[0]=A*id;            o[1]=-(b*i-c*h)*id;   o[2]=(b*f-c*e)*id;
    o[3]=B*id;            o[4]=(a*i-c*g)*id;    o[5]=-(a*f-c*d)*id;
    o[6]=C*id;            o[7]=-(a*h-b*g)*id;   o[8]=(a*e-b*d)*id;
}

__device__ void inv4d(const double* m, double* o) {
    double i0  =  m[5]*m[10]*m[15]-m[5]*m[11]*m[14]-m[9]*m[6]*m[15]+m[9]*m[7]*m[14]+m[13]*m[6]*m[11]-m[13]*m[7]*m[10];
    double i4  = -m[4]*m[10]*m[15]+m[4]*m[11]*m[14]+m[8]*m[6]*m[15]-m[8]*m[7]*m[14]-m[12]*m[6]*m[11]+m[12]*m[7]*m[10];
    double i8  =  m[4]*m[9]*m[15]-m[4]*m[11]*m[13]-m[8]*m[5]*m[15]+m[8]*m[7]*m[13]+m[12]*m[5]*m[11]-m[12]*m[7]*m[9];
    double i12 = -m[4]*m[9]*m[14]+m[4]*m[10]*m[13]+m[8]*m[5]*m[14]-m[8]*m[6]*m[13]-m[12]*m[5]*m[10]+m[12]*m[6]*m[9];
    double i1  = -m[1]*m[10]*m[15]+m[1]*m[11]*m[14]+m[9]*m[2]*m[15]-m[9]*m[3]*m[14]-m[13]*m[2]*m[11]+m[13]*m[3]*m[10];
    double i5  =  m[0]*m[10]*m[15]-m[0]*m[11]*m[14]-m[8]*m[2]*m[15]+m[8]*m[3]*m[14]+m[12]*m[2]*m[11]-m[12]*m[3]*m[10];
    double i9  = -m[0]*m[9]*m[15]+m[0]*m[11]*m[13]+m[8]*m[1]*m[15]-m[8]*m[3]*m[13]-m[12]*m[1]*m[11]+m[12]*m[3]*m[9];
    double i13 =  m[0]*m[9]*m[14]-m[0]*m[10]*m[13]-m[8]*m[1]*m[14]+m[8]*m[2]*m[13]+m[12]*m[1]*m[10]-m[12]*m[2]*m[9];
    double i2  =  m[1]*m[6]*m[15]-m[1]*m[7]*m[14]-m[5]*m[2]*m[15]+m[5]*m[3]*m[14]+m[13]*m[2]*m[7]-m[13]*m[3]*m[6];
    double i6  = -m[0]*m[6]*m[15]+m[0]*m[7]*m[14]+m[4]*m[2]*m[15]-m[4]*m[3]*m[14]-m[12]*m[2]*m[7]+m[12]*m[3]*m[6];
    double i10 =  m[0]*m[5]*m[15]-m[0]*m[7]*m[13]-m[4]*m[1]*m[15]+m[4]*m[3]*m[13]+m[12]*m[1]*m[7]-m[12]*m[3]*m[5];
    double i14 = -m[0]*m[5]*m[14]+m[0]*m[6]*m[13]+m[4]*m[1]*m[14]-m[4]*m[2]*m[13]-m[12]*m[1]*m[6]+m[12]*m[2]*m[5];
    double i3  = -m[1]*m[6]*m[11]+m[1]*m[7]*m[10]+m[5]*m[2]*m[11]-m[5]*m[3]*m[10]-m[9]*m[2]*m[7]+m[9]*m[3]*m[6];
    double i7  =  m[0]*m[6]*m[11]-m[0]*m[7]*m[10]-m[4]*m[2]*m[11]+m[4]*m[3]*m[10]+m[8]*m[2]*m[7]-m[8]*m[3]*m[6];
    double i11 = -m[0]*m[5]*m[11]+m[0]*m[7]*m[9]+m[4]*m[1]*m[11]-m[4]*m[3]*m[9]-m[8]*m[1]*m[7]+m[8]*m[3]*m[5];
    double i15 =  m[0]*m[5]*m[10]-m[0]*m[6]*m[9]-m[4]*m[1]*m[10]+m[4]*m[2]*m[9]+m[8]*m[1]*m[6]-m[8]*m[2]*m[5];
    double det = m[0]*i0+m[1]*i4+m[2]*i8+m[3]*i12;
    double id = 1.0/det;
    o[0]=i0*id; o[1]=i1*id; o[2]=i2*id; o[3]=i3*id;
    o[4]=i4*id; o[5]=i5*id; o[6]=i6*id; o[7]=i7*id;
    o[8]=i8*id; o[9]=i9*id; o[10]=i10*id; o[11]=i11*id;
    o[12]=i12*id; o[13]=i13*id; o[14]=i14*id; o[15]=i15*id;
}

// ---------------- precompute (c12 parallelized across 256 threads) ----------------
__global__ void occ_prep_kernel(const float* __restrict__ intr, const float* __restrict__ c2w,
                                const float* __restrict__ l2w, const float* __restrict__ w1,
                                const float* __restrict__ ln_g, const float* __restrict__ ln_b,
                                const float* __restrict__ b1, const float* __restrict__ w2,
                                const float* __restrict__ cw1, const float* __restrict__ cw2,
                                float* __restrict__ mats, __hip_bfloat16* __restrict__ wGm,
                                __hip_bfloat16* __restrict__ wA2, float* __restrict__ c12,
                                __hip_bfloat16* __restrict__ wB1a, __hip_bfloat16* __restrict__ wB1m,
                                __hip_bfloat16* __restrict__ wB2)
{
    __shared__ float sc1[256], sc2[256];
    int t = threadIdx.x;

    // parallel c12 partials: thread (j = t&15, chunk = t>>4) covers 48 d's, coalesced
    {
        int j = t & 15, ck = t >> 4;
        float c1 = 0.f, c2p = 0.f;
        #pragma unroll 4
        for (int dd = 0; dd < TD / 16; ++dd) {
            int d = ck * (TD / 16) + dd;
            c1  += bf2f((short)f2bf(ln_g[d] * w1[d * 16 + j]));
            c2p += ln_b[d] * w1[d * 16 + j];
        }
        sc1[t] = c1; sc2[t] = c2p;
    }
    __syncthreads();
    if (t < 16) {
        float a1 = 0.f, a2 = 0.f;
        #pragma unroll
        for (int k = 0; k < 16; ++k) { a1 += sc1[k * 16 + t]; a2 += sc2[k * 16 + t]; }
        c12[t] = a1;
        c12[16 + t] = a2 + b1[t];
    }

    if (t < NB * NCAM) {
        int b = t / NCAM;
        double K[9], Ki[9], L[16], Li[16], C[16], M[16], A[9];
        #pragma unroll
        for (int i = 0; i < 9; ++i) K[i] = (double)intr[t * 9 + i];
        inv3d(K, Ki);
        #pragma unroll
        for (int i = 0; i < 16; ++i) L[i] = (double)l2w[b * 16 + i];
        inv4d(L, Li);
        #pragma unroll
        for (int i = 0; i < 16; ++i) C[i] = (double)c2w[t * 16 + i];
        #pragma unroll
        for (int r = 0; r < 4; ++r)
            #pragma unroll
            for (int c = 0; c < 4; ++c) {
                double s = 0.0;
                #pragma unroll
                for (int k = 0; k < 4; ++k) s += Li[r * 4 + k] * C[k * 4 + c];
                M[r * 4 + c] = s;
            }
        #pragma unroll
        for (int r = 0; r < 3; ++r)
            #pragma unroll
            for (int c = 0; c < 3; ++c) {
                double s = 0.0;
                #pragma unroll
                for (int k = 0; k < 3; ++k) s += M[r * 4 + k] * Ki[k * 3 + c];
                A[r * 3 + c] = s;
            }
        #pragma unroll
        for (int i = 0; i < 9; ++i) mats[t * 12 + i] = (float)A[i];
        mats[t * 12 + 9]  = (float)M[3];
        mats[t * 12 + 10] = (float)M[7];
        mats[t * 12 + 11] = (float)M[11];
    }
    // token GEMM1 B-fragments: wGm[step][lane][8], k = d = step*32 + 8*kg + e, col j = lane&15
    for (int i = t; i < 24 * 64 * 8; i += 256) {
        int st = i >> 9; int ln = (i >> 3) & 63; int e = i & 7;
        int kg = ln >> 4, j = ln & 15;
        int d = st * 32 + kg * 8 + e;
        wGm[i] = __float2bfloat16(ln_g[d] * w1[d * 16 + j]);
    }
    // token GEMM2 A-fragment: w2^T, m = ch = lane&15, k = hid = 8*kg+e (valid k<16)
    for (int i = t; i < 64 * 8; i += 256) {
        int ln = i >> 3; int e = i & 7;
        int kg = ln >> 4, ch = ln & 15;
        int k = kg * 8 + e;
        wA2[i] = __float2bfloat16((k < 16) ? w2[k * 16 + ch] : 0.f);
    }
    // conv1 main (16 vol channels): wB1a[t2][lane][8]; K packs 2 taps x 16 ch
    for (int i = t; i < 14 * 64 * 8; i += 256) {
        int t2 = i >> 9; int r = i & 511; int ln = r >> 3; int e = r & 7;
        int kg = ln >> 4;
        int tt = 2 * t2 + (kg >> 1);
        int ci = ((kg & 1) << 3) + e;
        int o = ln & 15;
        float val = (tt < 27) ? cw1[(o * 17 + ci) * 27 + tt] : 0.f;
        wB1a[i] = __float2bfloat16(val);
    }
    // conv1 mask channel (ci=16): wB1m[lane][8]; K slot = tap index
    for (int i = t; i < 64 * 8; i += 256) {
        int ln = i >> 3; int e = i & 7;
        int k = ((ln >> 4) << 3) + e;
        int o = ln & 15;
        float val = (k < 27) ? cw1[(o * 17 + 16) * 27 + k] : 0.f;
        wB1m[i] = __float2bfloat16(val);
    }
    // conv2: wB2[t2][lane][8]
    for (int i = t; i < 14 * 64 * 8; i += 256) {
        int t2 = i >> 9; int r = i & 511; int ln = r >> 3; int e = r & 7;
        int kg = ln >> 4;
        int tt = 2 * t2 + (kg >> 1);
        int ci = ((kg & 1) << 3) + e;
        int o = ln & 15;
        float val = (tt < 27) ? cw2[(o * 16 + ci) * 27 + tt] : 0.f;
        wB2[i] = __float2bfloat16(val);
    }
}

// ---------------- depth patch means: one wave per token ----------------
__global__ __launch_bounds__(256) void occ_depth_kernel(const float* __restrict__ depth,
                                                        float* __restrict__ dmean)
{
    int tid = threadIdx.x;
    int l = tid & 63;
    int g = blockIdx.x * 4 + (tid >> 6);     // 4107 blocks * 4 = 16428 exactly
    int bc = g / NP;
    int p  = g - bc * NP;
    int gy = p / PW, gx = p - gy * PW;
    const float* dbase = depth + (size_t)bc * (IMH * IMW);
    int rbase = gy * PATCH, cb = gx * PATCH;
    float dsum = 0.f;
    #pragma unroll
    for (int i = 0; i < 3; ++i) {
        int idx = l + 64 * i;
        int py = idx / 14;
        int px = idx - py * 14;
        dsum += dbase[(size_t)(rbase + py) * IMW + (cb + px)];
    }
    if (l < 4)
        dsum += dbase[(size_t)(rbase + 13) * IMW + (cb + 10 + l)];
    #pragma unroll
    for (int m = 1; m <= 32; m <<= 1) dsum += __shfl_xor(dsum, m);
    if (l == 0) dmean[g] = dsum * (1.0f / 196.0f);
}

// ------- scatter-zero: zero exactly the vol rows that will receive adds -------
__global__ __launch_bounds__(256) void occ_zerovol_kernel(
    const float* __restrict__ dmean, const float* __restrict__ mats,
    float* __restrict__ vol)
{
    int tk = blockIdx.x * 256 + threadIdx.x;
    if (tk >= NT) return;
    int b; size_t sp;
    if (tok_voxel(tk, dmean[tk], mats, b, sp)) {
        float4* p = (float4*)(vol + ((size_t)b * PL + sp) * 16);
        float4 z = {0.f, 0.f, 0.f, 0.f};
        p[0] = z; p[1] = z; p[2] = z; p[3] = z;
    }
}

// ------- token GEMM: LN folded into epilogue; 16 tokens per wave; MFMA -------
__global__ __launch_bounds__(256) void occ_tokgemm_kernel(
    const float* __restrict__ tokens, const float* __restrict__ dmean,
    const __hip_bfloat16* __restrict__ wGm, const __hip_bfloat16* __restrict__ wA2,
    const float* __restrict__ c12, const float* __restrict__ b2,
    const float* __restrict__ mats, float* __restrict__ vol, float* __restrict__ cnt)
{
    int tid = threadIdx.x;
    int w = tid >> 6, lane = tid & 63;
    int tile = (blockIdx.x * 4 + w) * 16;
    int j16 = lane & 15, kg = lane >> 4;

    __shared__ __hip_bfloat16 sH[4][16][16];

    int tka  = tile + j16;
    int tkac = min(tka, NT - 1);

    const float* tokp = tokens + (size_t)tkac * TD + (kg << 3);
    const short8* wg8 = (const short8*)wGm;

    floatx4 acc = {0.f, 0.f, 0.f, 0.f};
    float s = 0.f, sq = 0.f;
    #pragma unroll
    for (int st = 0; st < 24; ++st) {
        float4 xa = *(const float4*)(tokp + st * 32);
        float4 xb = *(const float4*)(tokp + st * 32 + 4);
        s += xa.x + xa.y + xa.z + xa.w + xb.x + xb.y + xb.z + xb.w;
        sq = fmaf(xa.x, xa.x, sq); sq = fmaf(xa.y, xa.y, sq);
        sq = fmaf(xa.z, xa.z, sq); sq = fmaf(xa.w, xa.w, sq);
        sq = fmaf(xb.x, xb.x, sq); sq = fmaf(xb.y, xb.y, sq);
        sq = fmaf(xb.z, xb.z, sq); sq = fmaf(xb.w, xb.w, sq);
        short8 a;
        a[0] = (short)f2bf(xa.x); a[1] = (short)f2bf(xa.y);
        a[2] = (short)f2bf(xa.z); a[3] = (short)f2bf(xa.w);
        a[4] = (short)f2bf(xb.x); a[5] = (short)f2bf(xb.y);
        a[6] = (short)f2bf(xb.z); a[7] = (short)f2bf(xb.w);
        acc = __builtin_amdgcn_mfma_f32_16x16x32_bf16(a, wg8[st * 64 + lane], acc, 0, 0, 0);
    }
    // stats for token j16 (dims split across kg groups)
    s  += __shfl_xor(s, 16);  s  += __shfl_xor(s, 32);
    sq += __shfl_xor(sq, 16); sq += __shfl_xor(sq, 32);
    float mu = s * (1.0f / (float)TD);
    float rs = rsqrtf(sq * (1.0f / (float)TD) - mu * mu + EPSF);

    // epilogue: h_j = rs*(acc - mu*c1_j) + c2'_j ; gelu ; stash h1 in LDS
    float c1  = c12[j16];
    float c2p = c12[16 + j16];
    #pragma unroll
    for (int r = 0; r < 4; ++r) {
        int srcl = kg * 4 + r;                 // row token within the 16-group
        float mur = __shfl(mu, srcl, 16);
        float rsr = __shfl(rs, srcl, 16);
        float h = rsr * (acc[r] - mur * c1) + c2p;
        sH[w][srcl][j16] = __float2bfloat16(gelu_exact(h));
    }
    __syncthreads();

    // GEMM2: D2[ch][token] = w2^T @ h1^T + b2
    short8 hb = zero8();
    if (kg < 2) hb = *(const short8*)&sH[w][j16][kg * 8];
    floatx4 acc2;
    acc2[0] = b2[kg * 4 + 0]; acc2[1] = b2[kg * 4 + 1];
    acc2[2] = b2[kg * 4 + 2]; acc2[3] = b2[kg * 4 + 3];
    short8 a2 = ((const short8*)wA2)[lane];
    acc2 = __builtin_amdgcn_mfma_f32_16x16x32_bf16(a2, hb, acc2, 0, 0, 0);

    // geometry + scatter: lane owns token tile+j16, channels kg*4 .. kg*4+3
    int b; size_t sp;
    bool valid = tok_voxel(tkac, dmean[tkac], mats, b, sp) && (tka < NT);
    if (valid) {
        float* base = vol + ((size_t)b * PL + sp) * 16 + kg * 4;
        atomicAdd(base + 0, acc2[0]);
        atomicAdd(base + 1, acc2[1]);
        atomicAdd(base + 2, acc2[2]);
        atomicAdd(base + 3, acc2[3]);
        if (kg == 0) atomicAdd(cnt + (size_t)b * PL + sp, 1.0f);
    }
}

// ------- conv3d 3x3x3 via MFMA, LDS-staged 4x8 tile -------
// MODE 0 (conv1): stage = normalize vol/cnt on the fly (+mask), OUTPAD store
// MODE 1 (conv2): stage = gelu(bn1(x)) on the fly with interior zero-pad, flat store
template <int MODE>
__global__ __launch_bounds__(256, 4) void occ_conv_kernel(
    const float* __restrict__ volf, const float* __restrict__ cnt,
    const __hip_bfloat16* __restrict__ inbf, const float* __restrict__ bnp,
    const __hip_bfloat16* __restrict__ wBa, const __hip_bfloat16* __restrict__ wBm,
    const float* __restrict__ bias, __hip_bfloat16* __restrict__ out,
    float* __restrict__ stats)
{
    // 2500 blocks = NB * (GX/4) * (GY/8); bijective XCD swizzle (2500 = 4*313 + 4*312)
    int bid = blockIdx.x;
    int xcd = bid & 7, off = bid >> 3;
    int blk = (xcd < 4 ? xcd * 313 : 4 * 313 + (xcd - 4) * 312) + off;
    int b   = blk / 1250;
    int rem = blk % 1250;
    int x0  = (rem / 25) * 4;
    int y0  = (rem % 25) * 8;
    int tid = threadIdx.x;

    __shared__ __hip_bfloat16 sA[1080 * 16];    // 6x10x18 rows of 16ch = 34,560 B
    __shared__ unsigned short sM[1080];
    __shared__ float sred[4][32];
    __shared__ float sbn[32];

    if constexpr (MODE == 1) {
        if (tid < 32) sbn[tid] = bnp[tid];
        __syncthreads();
    }

    // cooperative stage with fused normalize (MODE 0) or fused bn+gelu (MODE 1)
    {
        short8* sa8 = (short8*)sA;
        const short8* gin = (const short8*)inbf;
        for (int ii = tid; ii < 1080; ii += 256) {
            int dx = ii / 180;
            int r2 = ii - dx * 180;
            int dy = r2 / 18, dz = r2 - dy * 18;
            int px = x0 + dx, py = y0 + dy, pz = dz;
            bool interior = ((unsigned)(px - 1) < (unsigned)GX) &&
                            ((unsigned)(py - 1) < (unsigned)GY) &&
                            ((unsigned)(pz - 1) < (unsigned)GZ);
            short8 o0 = zero8(), o1 = zero8();
            if constexpr (MODE == 0) {
                unsigned short m = 0;
                if (interior) {
                    size_t vi = (size_t)b * PL +
                                (((size_t)(px - 1) * GY + (py - 1)) * GZ + (pz - 1));
                    float cn = cnt[vi];
                    if (cn > 0.f) {
                        float inv = 1.0f / cn;
                        const float4* vp = (const float4*)(volf + vi * 16);
                        float4 f0 = vp[0], f1 = vp[1], f2 = vp[2], f3 = vp[3];
                        o0[0] = (short)f2bf(f0.x * inv); o0[1] = (short)f2bf(f0.y * inv);
                        o0[2] = (short)f2bf(f0.z * inv); o0[3] = (short)f2bf(f0.w * inv);
                        o0[4] = (short)f2bf(f1.x * inv); o0[5] = (short)f2bf(f1.y * inv);
                        o0[6] = (short)f2bf(f1.z * inv); o0[7] = (short)f2bf(f1.w * inv);
                        o1[0] = (short)f2bf(f2.x * inv); o1[1] = (short)f2bf(f2.y * inv);
                        o1[2] = (short)f2bf(f2.z * inv); o1[3] = (short)f2bf(f2.w * inv);
                        o1[4] = (short)f2bf(f3.x * inv); o1[5] = (short)f2bf(f3.y * inv);
                        o1[6] = (short)f2bf(f3.z * inv); o1[7] = (short)f2bf(f3.w * inv);
                        m = f2bf(1.0f);
                    }
                }
                sM[ii] = m;
            } else {
                if (interior) {
                    size_t grow = ((size_t)((b * PX + px) * PY + py) * PZ) + pz;
                    short8 v0 = gin[grow * 2], v1 = gin[grow * 2 + 1];
                    #pragma unroll
                    for (int e = 0; e < 8; ++e) {
                        o0[e] = (short)f2bf(gelu_exact(fmaf(bf2f(v0[e]), sbn[e],     sbn[16 + e])));
                        o1[e] = (short)f2bf(gelu_exact(fmaf(bf2f(v1[e]), sbn[8 + e], sbn[24 + e])));
                    }
                }
            }
            sa8[ii * 2] = o0; sa8[ii * 2 + 1] = o1;
        }
    }
    __syncthreads();

    int w = tid >> 6, lane = tid & 63;
    int z = lane & 15, kg = lane >> 4;
    int ci0 = (kg & 1) << 3;
    bool halfsel = kg >= 2;

    // preload weight fragments (loop-invariant)
    const short8* wp = (const short8*)wBa;
    short8 wreg[14];
    #pragma unroll
    for (int t2 = 0; t2 < 14; ++t2) wreg[t2] = wp[t2 * 64 + lane];

    float bo = bias[lane & 15];
    floatx4 acc[8];
    #pragma unroll
    for (int j = 0; j < 8; ++j) { acc[j][0]=bo; acc[j][1]=bo; acc[j][2]=bo; acc[j][3]=bo; }

    #pragma unroll
    for (int t2 = 0; t2 < 14; ++t2) {
        const int ta = 2 * t2;
        const int tb = (2 * t2 + 1 > 26) ? 26 : 2 * t2 + 1;
        const int kda = ta / 9, kha = (ta / 3) % 3, kwa = ta % 3;
        const int kdb = tb / 9, khb = (tb / 3) % 3, kwb = tb % 3;
        int rowA = (w + kda) * 180 + kha * 18 + (z + kwa);
        int rowB = (w + kdb) * 180 + khb * 18 + (z + kwb);
        int row = halfsel ? rowB : rowA;
        const __hip_bfloat16* ap = sA + row * 16 + ci0;
        #pragma unroll
        for (int j = 0; j < 8; ++j) {
            short8 a = *(const short8*)(ap + j * (18 * 16));   // +576B per y-col
            acc[j] = __builtin_amdgcn_mfma_f32_16x16x32_bf16(a, wreg[t2], acc[j], 0, 0, 0);
        }
    }

    if constexpr (MODE == 0) {
        int base8[8];
        #pragma unroll
        for (int e = 0; e < 8; ++e) {
            int tap = kg * 8 + e;
            int kd = tap / 9;
            int rm = tap - kd * 9;
            int kh = rm / 3;
            int kw = rm - kh * 3;
            int idx = (w + kd) * 180 + kh * 18 + z + kw;
            base8[e] = (tap < 27) ? idx : 0;    // weight is 0 for tap>=27
        }
        short8 wm = ((const short8*)wBm)[lane];
        #pragma unroll
        for (int j = 0; j < 8; ++j) {
            short8 am;
            #pragma unroll
            for (int e = 0; e < 8; ++e) am[e] = (short)sM[base8[e] + j * 18];
            acc[j] = __builtin_amdgcn_mfma_f32_16x16x32_bf16(am, wm, acc[j], 0, 0, 0);
        }
    }

    // store; D: row z' = kg*4+r, col o = lane&15
    int o = lane & 15;
    int wx = x0 + w;
    #pragma unroll
    for (int j = 0; j < 8; ++j) {
        int wy = y0 + j;
        size_t rowbase;
        if constexpr (MODE == 0)
            rowbase = (size_t)(((b * PX + wx + 1) * PY) + (wy + 1)) * PZ + 1;
        else
            rowbase = (size_t)b * PL + ((size_t)wx * GY + wy) * GZ;
        #pragma unroll
        for (int r = 0; r < 4; ++r)
            out[(rowbase + kg * 4 + r) * 16 + o] = __float2bfloat16(acc[j][r]);
    }

    // fused BN stats (per-channel sum / sumsq)
    float s = 0.f, sq = 0.f;
    #pragma unroll
    for (int j = 0; j < 8; ++j)
        #pragma unroll
        for (int r = 0; r < 4; ++r) { float v = acc[j][r]; s += v; sq += v * v; }
    s  += __shfl_xor(s, 16);  s  += __shfl_xor(s, 32);
    sq += __shfl_xor(sq, 16); sq += __shfl_xor(sq, 32);
    if (lane < 16) { sred[w][lane] = s; sred[w][16 + lane] = sq; }
    __syncthreads();
    if (tid < 32) {
        float v2 = sred[0][tid] + sred[1][tid] + sred[2][tid] + sred[3][tid];
        atomicAdd(&stats[(size_t)(blockIdx.x & 63) * 32 + tid], v2);
    }
}

// ---------------- BN finalize ----------------
__global__ void occ_bnfin_kernel(const float* __restrict__ stats, const float* __restrict__ g,
                                 const float* __restrict__ bb, float* __restrict__ bn)
{
    int c = threadIdx.x;
    if (c >= 16) return;
    float s = 0.f, sq = 0.f;
    for (int k = 0; k < 64; ++k) { s += stats[k * 32 + c]; sq += stats[k * 32 + 16 + c]; }
    const float N = (float)(NB * PL);
    float mean = s / N;
    float var = sq / N - mean * mean;
    float scale = g[c] * rsqrtf(var + EPSF);
    bn[c] = scale;
    bn[16 + c] = bb[c] - mean * scale;
}

// ---------------- conv3 1x1x1 (16 -> 20) with fused bn2+GELU ----------------
__global__ __launch_bounds__(256) void occ_conv3_kernel(const __hip_bfloat16* __restrict__ act,
                                                        const float* __restrict__ bn,
                                                        const float* __restrict__ w3,
                                                        const float* __restrict__ b3,
                                                        float* __restrict__ out)
{
    __shared__ float w[NCLS * 16];
    __shared__ float bb[NCLS];
    __shared__ float sc[16], sh[16];
    int t = threadIdx.x;
    for (int i = t; i < NCLS * 16; i += 256) w[i] = w3[i];
    if (t < NCLS) bb[t] = b3[t];
    if (t >= 32 && t < 48) sc[t - 32] = bn[t - 32];
    if (t >= 48 && t < 64) sh[t - 48] = bn[t - 32];
    __syncthreads();
    size_t i = (size_t)blockIdx.x * 256 + t;      // < NB*PL
    size_t b = i / PL, sp = i % PL;
    const short8* p = (const short8*)(act + i * 16);
    short8 v0 = p[0], v1 = p[1];
    float vi[16];
    #pragma unroll
    for (int e = 0; e < 8; ++e) {
        vi[e]     = gelu_exact(fmaf(bf2f(v0[e]), sc[e],     sh[e]));
        vi[8 + e] = gelu_exact(fmaf(bf2f(v1[e]), sc[8 + e], sh[8 + e]));
    }
    float* op = out + b * NCLS * PL + sp;
    #pragma unroll
    for (int cls = 0; cls < NCLS; ++cls) {
        float a = bb[cls];
        #pragma unroll
        for (int ci = 0; ci < 16; ++ci) a = fmaf(vi[ci], w[cls * 16 + ci], a);
        op[(size_t)cls * PL] = a;
    }
}

// ---------------- launch ----------------
extern "C" void kernel_launch(void* const* d_in, const int* in_sizes, int n_in,
                              void* d_out, int out_size, void* d_ws, size_t ws_size,
                              hipStream_t stream)
{
    const float* tokens = (const float*)d_in[0];
    const float* depth  = (const float*)d_in[1];
    const float* intr   = (const float*)d_in[2];
    const float* c2w    = (const float*)d_in[3];
    const float* l2w    = (const float*)d_in[4];
    const float* ln_g   = (const float*)d_in[5];
    const float* ln_b   = (const float*)d_in[6];
    const float* w1     = (const float*)d_in[7];
    const float* b1     = (const float*)d_in[8];
    const float* w2     = (const float*)d_in[9];
    const float* b2     = (const float*)d_in[10];
    const float* cv1w   = (const float*)d_in[11];
    const float* cv1b   = (const float*)d_in[12];
    const float* bn1g   = (const float*)d_in[13];
    const float* bn1b   = (const float*)d_in[14];
    const float* cv2w   = (const float*)d_in[15];
    const float* cv2b   = (const float*)d_in[16];
    const float* bn2g   = (const float*)d_in[17];
    const float* bn2b   = (const float*)d_in[18];
    const float* cv3w   = (const float*)d_in[19];
    const float* cv3b   = (const float*)d_in[20];

    if (ws_size < WS_FLOATS * sizeof(float)) return;

    float* ws   = (float*)d_ws;
    float* volf = ws + OFF_VOL;
    float* cntp = ws + OFF_CNT;
    float* st1  = ws + OFF_ST1;
    float* st2s = ws + OFF_ST2;
    float* mats = ws + OFF_MATS;
    __hip_bfloat16* wGm  = (__hip_bfloat16*)(ws + OFF_WGM);
    __hip_bfloat16* wA2  = (__hip_bfloat16*)(ws + OFF_WA2);
    float* c12  = ws + OFF_C12;
    __hip_bfloat16* wB1a = (__hip_bfloat16*)(ws + OFF_WB1A);
    __hip_bfloat16* wB1m = (__hip_bfloat16*)(ws + OFF_WB1M);
    __hip_bfloat16* wB2  = (__hip_bfloat16*)(ws + OFF_WB2);
    float* bnp1 = ws + OFF_BN1;
    float* bnp2 = ws + OFF_BN2;

    __hip_bfloat16* ob      = (__hip_bfloat16*)d_out;
    __hip_bfloat16* staged2 = ob + DO_ST2;      // padded conv1 out (raw, pre-BN)
    float* dmean            = (float*)(ob + DO_DM);
    __hip_bfloat16* staged3 = (__hip_bfloat16*)(ws + OFF_VOL);  // unpadded conv2 out
    float* outp = (float*)d_out;

    // zero only cnt + BN-stat accumulators (5.1 MB)
    hipMemsetAsync(ws + OFF_CNT, 0, (ZERO_F - OFF_CNT) * sizeof(float), stream);

    occ_prep_kernel<<<1, 256, 0, stream>>>(intr, c2w, l2w, w1, ln_g, ln_b, b1, w2,
                                           cv1w, cv2w, mats, wGm, wA2, c12,
                                           wB1a, wB1m, wB2);

    occ_depth_kernel<<<NT / 4, 256, 0, stream>>>(depth, dmean);

    occ_zerovol_kernel<<<(NT + 255) / 256, 256, 0, stream>>>(dmean, mats, volf);

    const int TGBLK = (NT / 16 + 4) / 4;   // 257 blocks (4 waves x 16 tokens each)
    occ_tokgemm_kernel<<<TGBLK, 256, 0, stream>>>(
        tokens, dmean, wGm, wA2, c12, b2, mats, volf, cntp);

    const int CGRID = NB * (GX / 4) * (GY / 8);   // 2500
    // conv1: fused normalize+mask staging; raw output (pre-BN) to padded staged2
    occ_conv_kernel<0><<<CGRID, 256, 0, stream>>>(volf, cntp, nullptr, nullptr,
                                                  wB1a, wB1m, cv1b, staged2, st1);
    occ_bnfin_kernel<<<1, 16, 0, stream>>>(st1, bn1g, bn1b, bnp1);
    // conv2: fused gelu(bn1(x)) staging with interior zero-pad; out to staged3
    occ_conv_kernel<1><<<CGRID, 256, 0, stream>>>(nullptr, nullptr, staged2, bnp1,
                                                  wB2, nullptr, cv2b, staged3, st2s);
    occ_bnfin_kernel<<<1, 16, 0, stream>>>(st2s, bn2g, bn2b, bnp2);

    occ_conv3_kernel<<<5000, 256, 0, stream>>>(staged3, bnp2, cv3w, cv3b, outp);
}

// Round 9
// 153.471 us; speedup vs baseline: 15.8510x; 1.0077x over previous
//
#include <hip/hip_runtime.h>
#include <hip/hip_bf16.h>
#include <math.h>

// ---------------- problem constants ----------------
#define PATCH 14
#define HID   16
#define NCLS  20
#define GX    200
#define GY    200
#define GZ    16
#define NB    2
#define NCAM  6
#define PH    37
#define PW    37
#define NP    (PH*PW)
#define NT    (NB*NCAM*NP)         // 16428 tokens
#define TD    768
#define IMH   518
#define IMW   518
#define PL    ((size_t)GX*GY*GZ)   // 640000 voxels per batch
#define EPSF  1e-5f

// padded conv layout: [b][px 0..201][py 0..201][pz 0..17] rows of 16 ch
#define PX 202
#define PY 202
#define PZ 18

// ---------------- workspace layout (float units) ----------------
#define OFF_VOL   ((size_t)0)            // volf [b][sp][16] fp32 (aliased as staged3 bf16)
#define OFF_CNT   ((size_t)20480000)
#define OFF_ST1   ((size_t)21760000)
#define OFF_ST2   ((size_t)21762048)
#define ZERO_F    ((size_t)21764096)     // zero kernel covers OFF_CNT..ZERO_F
#define OFF_MATS  ((size_t)21764096)     // 144
#define OFF_WGM   ((size_t)21764240)     // 24*64*8 bf16 = 6,144 f
#define OFF_WA2   ((size_t)21770384)     // 64*8 bf16 = 256 f
#define OFF_C12   ((size_t)21770640)     // 32
#define OFF_WB1A  ((size_t)21770672)     // 3,584
#define OFF_WB1M  ((size_t)21774256)     // 256
#define OFF_WB2   ((size_t)21774512)     // 3,584
#define OFF_BN1   ((size_t)21778096)     // 32
#define OFF_BN2   ((size_t)21778128)     // 32
#define WS_FLOATS ((size_t)21778160)

#define ZERO_N4   ((int)((ZERO_F - OFF_CNT) / 4))   // 321,024 float4s

// ---------------- d_out staging (bf16 units; dead before conv3 writes) ----------
#define DO_ST2  ((size_t)0)                       // padded conv1 out, 23,503,104
#define DO_DM   ((size_t)23503104)                // dmean fp32[NT] = 32,856 bf16
                                                  // end 23,535,960 <= 51,200,000

typedef __attribute__((ext_vector_type(8))) short short8;
typedef __attribute__((ext_vector_type(4))) float floatx4;

__device__ __forceinline__ float gelu_exact(float x) {
    return 0.5f * x * (1.0f + erff(x * 0.70710678118654752f));
}
__device__ __forceinline__ unsigned short f2bf(float f) {
    __hip_bfloat16 h = __float2bfloat16(f);
    return __builtin_bit_cast(unsigned short, h);
}
__device__ __forceinline__ float bf2f(short u) {
    unsigned int b = ((unsigned int)(unsigned short)u) << 16;
    return __builtin_bit_cast(float, b);
}
__device__ __forceinline__ short8 zero8() {
    short8 z = {0,0,0,0,0,0,0,0};
    return z;
}

// shared geometry: token -> voxel (must match EXACTLY between zero-pass and tokgemm)
__device__ __forceinline__ bool tok_voxel(int tk, float dmr, const float* __restrict__ mats,
                                          int& b, size_t& sp)
{
    int bc = tk / NP;
    int p  = tk - bc * NP;
    b = bc / NCAM;
    int gy = p / PW, gx = p - gy * PW;
    const float* M = mats + bc * 12;
    float dm = fmaxf(dmr, 0.f);
    float u = (gx + 0.5f) * (float)PATCH;
    float v = (gy + 0.5f) * (float)PATCH;
    float lx = (M[0] * u + M[1] * v + M[2]) * dm + M[9];
    float ly = (M[3] * u + M[4] * v + M[5]) * dm + M[10];
    float lz = (M[6] * u + M[7] * v + M[8]) * dm + M[11];
    int cx = (int)floorf((lx + 40.0f) / 0.4f);
    int cy = (int)floorf((ly + 40.0f) / 0.4f);
    int cz = (int)floorf((lz + 1.0f) / 0.4f);
    bool valid = (dmr > 0.001f) &&
                 (unsigned)cx < (unsigned)GX &&
                 (unsigned)cy < (unsigned)GY &&
                 (unsigned)cz < (unsigned)GZ;
    sp = ((size_t)cx * GY + cy) * GZ + cz;
    return valid;
}

// ---------------- 3x3 / 4x4 inverse in double ----------------
__device__ void inv3d(const double* m, double* o) {
    double a=m[0],b=m[1],c=m[2],d=m[3],e=m[4],f=m[5],g=m[6],h=m[7],i=m[8];
    double A=e*i-f*h, B=-(d*i-f*g), C=d*h-e*g;
    double det=a*A+b*B+c*C, id=1.0/det;
    o[0]=A*id;            o[1]=-(b*i-c*h)*id;   o[2]=(b*f-c*e)*id;
    o[3]=B*id;            o[4]=(a*i-c*g)*id;    o[5]=-(a*f-c*d)*id;
    o[6]=C*id;            o[7]=-(a*h-b*g)*id;   o[8]=(a*e-b*d)*id;
}

__device__ void inv4d(const double* m, double* o) {
    double i0  =  m[5]*m[10]*m[15]-m[5]*m[11]*m[14]-m[9]*m[6]*m[15]+m[9]*m[7]*m[14]+m[13]*m[6]*m[11]-m[13]*m[7]*m[10];
    double i4  = -m[4]*m[10]*m[15]+m[4]*m[11]*m[14]+m[8]*m[6]*m[15]-m[8]*m[7]*m[14]-m[12]*m[6]*m[11]+m[12]*m[7]*m[10];
    double i8  =  m[4]*m[9]*m[15]-m[4]*m[11]*m[13]-m[8]*m[5]*m[15]+m[8]*m[7]*m[13]+m[12]*m[5]*m[11]-m[12]*m[7]*m[9];
    double i12 = -m[4]*m[9]*m[14]+m[4]*m[10]*m[13]+m[8]*m[5]*m[14]-m[8]*m[6]*m[13]-m[12]*m[5]*m[10]+m[12]*m[6]*m[9];
    double i1  = -m[1]*m[10]*m[15]+m[1]*m[11]*m[14]+m[9]*m[2]*m[15]-m[9]*m[3]*m[14]-m[13]*m[2]*m[11]+m[13]*m[3]*m[10];
    double i5  =  m[0]*m[10]*m[15]-m[0]*m[11]*m[14]-m[8]*m[2]*m[15]+m[8]*m[3]*m[14]+m[12]*m[2]*m[11]-m[12]*m[3]*m[10];
    double i9  = -m[0]*m[9]*m[15]+m[0]*m[11]*m[13]+m[8]*m[1]*m[15]-m[8]*m[3]*m[13]-m[12]*m[1]*m[11]+m[12]*m[3]*m[9];
    double i13 =  m[0]*m[9]*m[14]-m[0]*m[10]*m[13]-m[8]*m[1]*m[14]+m[8]*m[2]*m[13]+m[12]*m[1]*m[10]-m[12]*m[2]*m[9];
    double i2  =  m[1]*m[6]*m[15]-m[1]*m[7]*m[14]-m[5]*m[2]*m[15]+m[5]*m[3]*m[14]+m[13]*m[2]*m[7]-m[13]*m[3]*m[6];
    double i6  = -m[0]*m[6]*m[15]+m[0]*m[7]*m[14]+m[4]*m[2]*m[15]-m[4]*m[3]*m[14]-m[12]*m[2]*m[7]+m[12]*m[3]*m[6];
    double i10 =  m[0]*m[5]*m[15]-m[0]*m[7]*m[13]-m[4]*m[1]*m[15]+m[4]*m[3]*m[13]+m[12]*m[1]*m[7]-m[12]*m[3]*m[5];
    double i14 = -m[0]*m[5]*m[14]+m[0]*m[6]*m[13]+m[4]*m[1]*m[14]-m[4]*m[2]*m[13]-m[12]*m[1]*m[6]+m[12]*m[2]*m[5];
    double i3  = -m[1]*m[6]*m[11]+m[1]*m[7]*m[10]+m[5]*m[2]*m[11]-m[5]*m[3]*m[10]-m[9]*m[2]*m[7]+m[9]*m[3]*m[6];
    double i7  =  m[0]*m[6]*m[11]-m[0]*m[7]*m[10]-m[4]*m[2]*m[11]+m[4]*m[3]*m[10]+m[8]*m[2]*m[7]-m[8]*m[3]*m[6];
    double i11 = -m[0]*m[5]*m[11]+m[0]*m[7]*m[9]+m[4]*m[1]*m[11]-m[4]*m[3]*m[9]-m[8]*m[1]*m[7]+m[8]*m[3]*m[5];
    double i15 =  m[0]*m[5]*m[10]-m[0]*m[6]*m[9]-m[4]*m[1]*m[10]+m[4]*m[2]*m[9]+m[8]*m[1]*m[6]-m[8]*m[2]*m[5];
    double det = m[0]*i0+m[1]*i4+m[2]*i8+m[3]*i12;
    double id = 1.0/det;
    o[0]=i0*id; o[1]=i1*id; o[2]=i2*id; o[3]=i3*id;
    o[4]=i4*id; o[5]=i5*id; o[6]=i6*id; o[7]=i7*id;
    o[8]=i8*id; o[9]=i9*id; o[10]=i10*id; o[11]=i11*id;
    o[12]=i12*id; o[13]=i13*id; o[14]=i14*id; o[15]=i15*id;
}

// ---------------- zero cnt + stats (replaces pathological runtime fill) --------
__global__ __launch_bounds__(256) void occ_zero_kernel(float4* __restrict__ p)
{
    int i = blockIdx.x * 256 + threadIdx.x;
    if (i < ZERO_N4) {
        float4 z = {0.f, 0.f, 0.f, 0.f};
        p[i] = z;
    }
}

// ---------------- precompute (c12 parallelized across 256 threads) ----------------
__global__ void occ_prep_kernel(const float* __restrict__ intr, const float* __restrict__ c2w,
                                const float* __restrict__ l2w, const float* __restrict__ w1,
                                const float* __restrict__ ln_g, const float* __restrict__ ln_b,
                                const float* __restrict__ b1, const float* __restrict__ w2,
                                const float* __restrict__ cw1, const float* __restrict__ cw2,
                                float* __restrict__ mats, __hip_bfloat16* __restrict__ wGm,
                                __hip_bfloat16* __restrict__ wA2, float* __restrict__ c12,
                                __hip_bfloat16* __restrict__ wB1a, __hip_bfloat16* __restrict__ wB1m,
                                __hip_bfloat16* __restrict__ wB2)
{
    __shared__ float sc1[256], sc2[256];
    int t = threadIdx.x;

    // parallel c12 partials: thread (j = t&15, chunk = t>>4) covers 48 d's, coalesced
    {
        int j = t & 15, ck = t >> 4;
        float c1 = 0.f, c2p = 0.f;
        #pragma unroll 4
        for (int dd = 0; dd < TD / 16; ++dd) {
            int d = ck * (TD / 16) + dd;
            c1  += bf2f((short)f2bf(ln_g[d] * w1[d * 16 + j]));
            c2p += ln_b[d] * w1[d * 16 + j];
        }
        sc1[t] = c1; sc2[t] = c2p;
    }
    __syncthreads();
    if (t < 16) {
        float a1 = 0.f, a2 = 0.f;
        #pragma unroll
        for (int k = 0; k < 16; ++k) { a1 += sc1[k * 16 + t]; a2 += sc2[k * 16 + t]; }
        c12[t] = a1;
        c12[16 + t] = a2 + b1[t];
    }

    if (t < NB * NCAM) {
        int b = t / NCAM;
        double K[9], Ki[9], L[16], Li[16], C[16], M[16], A[9];
        #pragma unroll
        for (int i = 0; i < 9; ++i) K[i] = (double)intr[t * 9 + i];
        inv3d(K, Ki);
        #pragma unroll
        for (int i = 0; i < 16; ++i) L[i] = (double)l2w[b * 16 + i];
        inv4d(L, Li);
        #pragma unroll
        for (int i = 0; i < 16; ++i) C[i] = (double)c2w[t * 16 + i];
        #pragma unroll
        for (int r = 0; r < 4; ++r)
            #pragma unroll
            for (int c = 0; c < 4; ++c) {
                double s = 0.0;
                #pragma unroll
                for (int k = 0; k < 4; ++k) s += Li[r * 4 + k] * C[k * 4 + c];
                M[r * 4 + c] = s;
            }
        #pragma unroll
        for (int r = 0; r < 3; ++r)
            #pragma unroll
            for (int c = 0; c < 3; ++c) {
                double s = 0.0;
                #pragma unroll
                for (int k = 0; k < 3; ++k) s += M[r * 4 + k] * Ki[k * 3 + c];
                A[r * 3 + c] = s;
            }
        #pragma unroll
        for (int i = 0; i < 9; ++i) mats[t * 12 + i] = (float)A[i];
        mats[t * 12 + 9]  = (float)M[3];
        mats[t * 12 + 10] = (float)M[7];
        mats[t * 12 + 11] = (float)M[11];
    }
    // token GEMM1 B-fragments: wGm[step][lane][8], k = d = step*32 + 8*kg + e, col j = lane&15
    for (int i = t; i < 24 * 64 * 8; i += 256) {
        int st = i >> 9; int ln = (i >> 3) & 63; int e = i & 7;
        int kg = ln >> 4, j = ln & 15;
        int d = st * 32 + kg * 8 + e;
        wGm[i] = __float2bfloat16(ln_g[d] * w1[d * 16 + j]);
    }
    // token GEMM2 A-fragment: w2^T, m = ch = lane&15, k = hid = 8*kg+e (valid k<16)
    for (int i = t; i < 64 * 8; i += 256) {
        int ln = i >> 3; int e = i & 7;
        int kg = ln >> 4, ch = ln & 15;
        int k = kg * 8 + e;
        wA2[i] = __float2bfloat16((k < 16) ? w2[k * 16 + ch] : 0.f);
    }
    // conv1 main (16 vol channels): wB1a[t2][lane][8]; K packs 2 taps x 16 ch
    for (int i = t; i < 14 * 64 * 8; i += 256) {
        int t2 = i >> 9; int r = i & 511; int ln = r >> 3; int e = r & 7;
        int kg = ln >> 4;
        int tt = 2 * t2 + (kg >> 1);
        int ci = ((kg & 1) << 3) + e;
        int o = ln & 15;
        float val = (tt < 27) ? cw1[(o * 17 + ci) * 27 + tt] : 0.f;
        wB1a[i] = __float2bfloat16(val);
    }
    // conv1 mask channel (ci=16): wB1m[lane][8]; K slot = tap index
    for (int i = t; i < 64 * 8; i += 256) {
        int ln = i >> 3; int e = i & 7;
        int k = ((ln >> 4) << 3) + e;
        int o = ln & 15;
        float val = (k < 27) ? cw1[(o * 17 + 16) * 27 + k] : 0.f;
        wB1m[i] = __float2bfloat16(val);
    }
    // conv2: wB2[t2][lane][8]
    for (int i = t; i < 14 * 64 * 8; i += 256) {
        int t2 = i >> 9; int r = i & 511; int ln = r >> 3; int e = r & 7;
        int kg = ln >> 4;
        int tt = 2 * t2 + (kg >> 1);
        int ci = ((kg & 1) << 3) + e;
        int o = ln & 15;
        float val = (tt < 27) ? cw2[(o * 16 + ci) * 27 + tt] : 0.f;
        wB2[i] = __float2bfloat16(val);
    }
}

// ------- depth patch means + scatter-zero of target vol rows (fused) -------
__global__ __launch_bounds__(256) void occ_depth_kernel(const float* __restrict__ depth,
                                                        const float* __restrict__ mats,
                                                        float* __restrict__ dmean,
                                                        float* __restrict__ vol)
{
    int tid = threadIdx.x;
    int l = tid & 63;
    int g = blockIdx.x * 4 + (tid >> 6);     // 4107 blocks * 4 = 16428 exactly
    int bc = g / NP;
    int p  = g - bc * NP;
    int gy = p / PW, gx = p - gy * PW;
    const float* dbase = depth + (size_t)bc * (IMH * IMW);
    int rbase = gy * PATCH, cb = gx * PATCH;
    float dsum = 0.f;
    #pragma unroll
    for (int i = 0; i < 3; ++i) {
        int idx = l + 64 * i;
        int py = idx / 14;
        int px = idx - py * 14;
        dsum += dbase[(size_t)(rbase + py) * IMW + (cb + px)];
    }
    if (l < 4)
        dsum += dbase[(size_t)(rbase + 13) * IMW + (cb + 10 + l)];
    #pragma unroll
    for (int m = 1; m <= 32; m <<= 1) dsum += __shfl_xor(dsum, m);
    float dmr = dsum * (1.0f / 196.0f);
    if (l == 0) dmean[g] = dmr;
    // lanes 0-3: zero the 16-float vol row this token will scatter into
    if (l < 4) {
        int b; size_t sp;
        if (tok_voxel(g, dmr, mats, b, sp)) {
            float4 z = {0.f, 0.f, 0.f, 0.f};
            *(float4*)(vol + ((size_t)b * PL + sp) * 16 + l * 4) = z;
        }
    }
}

// ------- token GEMM: LN folded into epilogue; 16 tokens per wave; MFMA -------
__global__ __launch_bounds__(256) void occ_tokgemm_kernel(
    const float* __restrict__ tokens, const float* __restrict__ dmean,
    const __hip_bfloat16* __restrict__ wGm, const __hip_bfloat16* __restrict__ wA2,
    const float* __restrict__ c12, const float* __restrict__ b2,
    const float* __restrict__ mats, float* __restrict__ vol, float* __restrict__ cnt)
{
    int tid = threadIdx.x;
    int w = tid >> 6, lane = tid & 63;
    int tile = (blockIdx.x * 4 + w) * 16;
    int j16 = lane & 15, kg = lane >> 4;

    __shared__ __hip_bfloat16 sH[4][16][16];

    int tka  = tile + j16;
    int tkac = min(tka, NT - 1);

    const float* tokp = tokens + (size_t)tkac * TD + (kg << 3);
    const short8* wg8 = (const short8*)wGm;

    floatx4 acc = {0.f, 0.f, 0.f, 0.f};
    float s = 0.f, sq = 0.f;
    #pragma unroll
    for (int st = 0; st < 24; ++st) {
        float4 xa = *(const float4*)(tokp + st * 32);
        float4 xb = *(const float4*)(tokp + st * 32 + 4);
        s += xa.x + xa.y + xa.z + xa.w + xb.x + xb.y + xb.z + xb.w;
        sq = fmaf(xa.x, xa.x, sq); sq = fmaf(xa.y, xa.y, sq);
        sq = fmaf(xa.z, xa.z, sq); sq = fmaf(xa.w, xa.w, sq);
        sq = fmaf(xb.x, xb.x, sq); sq = fmaf(xb.y, xb.y, sq);
        sq = fmaf(xb.z, xb.z, sq); sq = fmaf(xb.w, xb.w, sq);
        short8 a;
        a[0] = (short)f2bf(xa.x); a[1] = (short)f2bf(xa.y);
        a[2] = (short)f2bf(xa.z); a[3] = (short)f2bf(xa.w);
        a[4] = (short)f2bf(xb.x); a[5] = (short)f2bf(xb.y);
        a[6] = (short)f2bf(xb.z); a[7] = (short)f2bf(xb.w);
        acc = __builtin_amdgcn_mfma_f32_16x16x32_bf16(a, wg8[st * 64 + lane], acc, 0, 0, 0);
    }
    // stats for token j16 (dims split across kg groups)
    s  += __shfl_xor(s, 16);  s  += __shfl_xor(s, 32);
    sq += __shfl_xor(sq, 16); sq += __shfl_xor(sq, 32);
    float mu = s * (1.0f / (float)TD);
    float rs = rsqrtf(sq * (1.0f / (float)TD) - mu * mu + EPSF);

    // epilogue: h_j = rs*(acc - mu*c1_j) + c2'_j ; gelu ; stash h1 in LDS
    float c1  = c12[j16];
    float c2p = c12[16 + j16];
    #pragma unroll
    for (int r = 0; r < 4; ++r) {
        int srcl = kg * 4 + r;                 // row token within the 16-group
        float mur = __shfl(mu, srcl, 16);
        float rsr = __shfl(rs, srcl, 16);
        float h = rsr * (acc[r] - mur * c1) + c2p;
        sH[w][srcl][j16] = __float2bfloat16(gelu_exact(h));
    }
    __syncthreads();

    // GEMM2: D2[ch][token] = w2^T @ h1^T + b2
    short8 hb = zero8();
    if (kg < 2) hb = *(const short8*)&sH[w][j16][kg * 8];
    floatx4 acc2;
    acc2[0] = b2[kg * 4 + 0]; acc2[1] = b2[kg * 4 + 1];
    acc2[2] = b2[kg * 4 + 2]; acc2[3] = b2[kg * 4 + 3];
    short8 a2 = ((const short8*)wA2)[lane];
    acc2 = __builtin_amdgcn_mfma_f32_16x16x32_bf16(a2, hb, acc2, 0, 0, 0);

    // geometry + scatter: lane owns token tile+j16, channels kg*4 .. kg*4+3
    int b; size_t sp;
    bool valid = tok_voxel(tkac, dmean[tkac], mats, b, sp) && (tka < NT);
    if (valid) {
        float* base = vol + ((size_t)b * PL + sp) * 16 + kg * 4;
        atomicAdd(base + 0, acc2[0]);
        atomicAdd(base + 1, acc2[1]);
        atomicAdd(base + 2, acc2[2]);
        atomicAdd(base + 3, acc2[3]);
        if (kg == 0) atomicAdd(cnt + (size_t)b * PL + sp, 1.0f);
    }
}

// ------- conv3d 3x3x3 via MFMA, LDS-staged 4x8 tile -------
// MODE 0 (conv1): stage = normalize vol/cnt on the fly (+mask), OUTPAD store
// MODE 1 (conv2): stage = gelu(bn1(x)) on the fly with interior zero-pad, flat store
template <int MODE>
__global__ __launch_bounds__(256, 4) void occ_conv_kernel(
    const float* __restrict__ volf, const float* __restrict__ cnt,
    const __hip_bfloat16* __restrict__ inbf, const float* __restrict__ bnp,
    const __hip_bfloat16* __restrict__ wBa, const __hip_bfloat16* __restrict__ wBm,
    const float* __restrict__ bias, __hip_bfloat16* __restrict__ out,
    float* __restrict__ stats)
{
    // 2500 blocks = NB * (GX/4) * (GY/8); bijective XCD swizzle (2500 = 4*313 + 4*312)
    int bid = blockIdx.x;
    int xcd = bid & 7, off = bid >> 3;
    int blk = (xcd < 4 ? xcd * 313 : 4 * 313 + (xcd - 4) * 312) + off;
    int b   = blk / 1250;
    int rem = blk % 1250;
    int x0  = (rem / 25) * 4;
    int y0  = (rem % 25) * 8;
    int tid = threadIdx.x;

    __shared__ __hip_bfloat16 sA[1080 * 16];    // 6x10x18 rows of 16ch = 34,560 B
    __shared__ unsigned short sM[1080];
    __shared__ float sred[4][32];
    __shared__ float sbn[32];

    if constexpr (MODE == 1) {
        if (tid < 32) sbn[tid] = bnp[tid];
        __syncthreads();
    }

    // cooperative stage with fused normalize (MODE 0) or fused bn+gelu (MODE 1)
    {
        short8* sa8 = (short8*)sA;
        const short8* gin = (const short8*)inbf;
        for (int ii = tid; ii < 1080; ii += 256) {
            int dx = ii / 180;
            int r2 = ii - dx * 180;
            int dy = r2 / 18, dz = r2 - dy * 18;
            int px = x0 + dx, py = y0 + dy, pz = dz;
            bool interior = ((unsigned)(px - 1) < (unsigned)GX) &&
                            ((unsigned)(py - 1) < (unsigned)GY) &&
                            ((unsigned)(pz - 1) < (unsigned)GZ);
            short8 o0 = zero8(), o1 = zero8();
            if constexpr (MODE == 0) {
                unsigned short m = 0;
                if (interior) {
                    size_t vi = (size_t)b * PL +
                                (((size_t)(px - 1) * GY + (py - 1)) * GZ + (pz - 1));
                    float cn = cnt[vi];
                    if (cn > 0.f) {
                        float inv = 1.0f / cn;
                        const float4* vp = (const float4*)(volf + vi * 16);
                        float4 f0 = vp[0], f1 = vp[1], f2 = vp[2], f3 = vp[3];
                        o0[0] = (short)f2bf(f0.x * inv); o0[1] = (short)f2bf(f0.y * inv);
                        o0[2] = (short)f2bf(f0.z * inv); o0[3] = (short)f2bf(f0.w * inv);
                        o0[4] = (short)f2bf(f1.x * inv); o0[5] = (short)f2bf(f1.y * inv);
                        o0[6] = (short)f2bf(f1.z * inv); o0[7] = (short)f2bf(f1.w * inv);
                        o1[0] = (short)f2bf(f2.x * inv); o1[1] = (short)f2bf(f2.y * inv);
                        o1[2] = (short)f2bf(f2.z * inv); o1[3] = (short)f2bf(f2.w * inv);
                        o1[4] = (short)f2bf(f3.x * inv); o1[5] = (short)f2bf(f3.y * inv);
                        o1[6] = (short)f2bf(f3.z * inv); o1[7] = (short)f2bf(f3.w * inv);
                        m = f2bf(1.0f);
                    }
                }
                sM[ii] = m;
            } else {
                if (interior) {
                    size_t grow = ((size_t)((b * PX + px) * PY + py) * PZ) + pz;
                    short8 v0 = gin[grow * 2], v1 = gin[grow * 2 + 1];
                    #pragma unroll
                    for (int e = 0; e < 8; ++e) {
                        o0[e] = (short)f2bf(gelu_exact(fmaf(bf2f(v0[e]), sbn[e],     sbn[16 + e])));
                        o1[e] = (short)f2bf(gelu_exact(fmaf(bf2f(v1[e]), sbn[8 + e], sbn[24 + e])));
                    }
                }
            }
            sa8[ii * 2] = o0; sa8[ii * 2 + 1] = o1;
        }
    }
    __syncthreads();

    int w = tid >> 6, lane = tid & 63;
    int z = lane & 15, kg = lane >> 4;
    int ci0 = (kg & 1) << 3;
    bool halfsel = kg >= 2;

    // preload weight fragments (loop-invariant)
    const short8* wp = (const short8*)wBa;
    short8 wreg[14];
    #pragma unroll
    for (int t2 = 0; t2 < 14; ++t2) wreg[t2] = wp[t2 * 64 + lane];

    float bo = bias[lane & 15];
    floatx4 acc[8];
    #pragma unroll
    for (int j = 0; j < 8; ++j) { acc[j][0]=bo; acc[j][1]=bo; acc[j][2]=bo; acc[j][3]=bo; }

    #pragma unroll
    for (int t2 = 0; t2 < 14; ++t2) {
        const int ta = 2 * t2;
        const int tb = (2 * t2 + 1 > 26) ? 26 : 2 * t2 + 1;
        const int kda = ta / 9, kha = (ta / 3) % 3, kwa = ta % 3;
        const int kdb = tb / 9, khb = (tb / 3) % 3, kwb = tb % 3;
        int rowA = (w + kda) * 180 + kha * 18 + (z + kwa);
        int rowB = (w + kdb) * 180 + khb * 18 + (z + kwb);
        int row = halfsel ? rowB : rowA;
        const __hip_bfloat16* ap = sA + row * 16 + ci0;
        #pragma unroll
        for (int j = 0; j < 8; ++j) {
            short8 a = *(const short8*)(ap + j * (18 * 16));   // +576B per y-col
            acc[j] = __builtin_amdgcn_mfma_f32_16x16x32_bf16(a, wreg[t2], acc[j], 0, 0, 0);
        }
    }

    if constexpr (MODE == 0) {
        int base8[8];
        #pragma unroll
        for (int e = 0; e < 8; ++e) {
            int tap = kg * 8 + e;
            int kd = tap / 9;
            int rm = tap - kd * 9;
            int kh = rm / 3;
            int kw = rm - kh * 3;
            int idx = (w + kd) * 180 + kh * 18 + z + kw;
            base8[e] = (tap < 27) ? idx : 0;    // weight is 0 for tap>=27
        }
        short8 wm = ((const short8*)wBm)[lane];
        #pragma unroll
        for (int j = 0; j < 8; ++j) {
            short8 am;
            #pragma unroll
            for (int e = 0; e < 8; ++e) am[e] = (short)sM[base8[e] + j * 18];
            acc[j] = __builtin_amdgcn_mfma_f32_16x16x32_bf16(am, wm, acc[j], 0, 0, 0);
        }
    }

    // store; D: row z' = kg*4+r, col o = lane&15
    int o = lane & 15;
    int wx = x0 + w;
    #pragma unroll
    for (int j = 0; j < 8; ++j) {
        int wy = y0 + j;
        size_t rowbase;
        if constexpr (MODE == 0)
            rowbase = (size_t)(((b * PX + wx + 1) * PY) + (wy + 1)) * PZ + 1;
        else
            rowbase = (size_t)b * PL + ((size_t)wx * GY + wy) * GZ;
        #pragma unroll
        for (int r = 0; r < 4; ++r)
            out[(rowbase + kg * 4 + r) * 16 + o] = __float2bfloat16(acc[j][r]);
    }

    // fused BN stats (per-channel sum / sumsq)
    float s = 0.f, sq = 0.f;
    #pragma unroll
    for (int j = 0; j < 8; ++j)
        #pragma unroll
        for (int r = 0; r < 4; ++r) { float v = acc[j][r]; s += v; sq += v * v; }
    s  += __shfl_xor(s, 16);  s  += __shfl_xor(s, 32);
    sq += __shfl_xor(sq, 16); sq += __shfl_xor(sq, 32);
    if (lane < 16) { sred[w][lane] = s; sred[w][16 + lane] = sq; }
    __syncthreads();
    if (tid < 32) {
        float v2 = sred[0][tid] + sred[1][tid] + sred[2][tid] + sred[3][tid];
        atomicAdd(&stats[(size_t)(blockIdx.x & 63) * 32 + tid], v2);
    }
}

// ---------------- BN finalize ----------------
__global__ void occ_bnfin_kernel(const float* __restrict__ stats, const float* __restrict__ g,
                                 const float* __restrict__ bb, float* __restrict__ bn)
{
    int c = threadIdx.x;
    if (c >= 16) return;
    float s = 0.f, sq = 0.f;
    for (int k = 0; k < 64; ++k) { s += stats[k * 32 + c]; sq += stats[k * 32 + 16 + c]; }
    const float N = (float)(NB * PL);
    float mean = s / N;
    float var = sq / N - mean * mean;
    float scale = g[c] * rsqrtf(var + EPSF);
    bn[c] = scale;
    bn[16 + c] = bb[c] - mean * scale;
}

// ---------------- conv3 1x1x1 (16 -> 20) with fused bn2+GELU ----------------
__global__ __launch_bounds__(256) void occ_conv3_kernel(const __hip_bfloat16* __restrict__ act,
                                                        const float* __restrict__ bn,
                                                        const float* __restrict__ w3,
                                                        const float* __restrict__ b3,
                                                        float* __restrict__ out)
{
    __shared__ float w[NCLS * 16];
    __shared__ float bb[NCLS];
    __shared__ float sc[16], sh[16];
    int t = threadIdx.x;
    for (int i = t; i < NCLS * 16; i += 256) w[i] = w3[i];
    if (t < NCLS) bb[t] = b3[t];
    if (t >= 32 && t < 48) sc[t - 32] = bn[t - 32];
    if (t >= 48 && t < 64) sh[t - 48] = bn[t - 32];
    __syncthreads();
    size_t i = (size_t)blockIdx.x * 256 + t;      // < NB*PL
    size_t b = i / PL, sp = i % PL;
    const short8* p = (const short8*)(act + i * 16);
    short8 v0 = p[0], v1 = p[1];
    float vi[16];
    #pragma unroll
    for (int e = 0; e < 8; ++e) {
        vi[e]     = gelu_exact(fmaf(bf2f(v0[e]), sc[e],     sh[e]));
        vi[8 + e] = gelu_exact(fmaf(bf2f(v1[e]), sc[8 + e], sh[8 + e]));
    }
    float* op = out + b * NCLS * PL + sp;
    #pragma unroll
    for (int cls = 0; cls < NCLS; ++cls) {
        float a = bb[cls];
        #pragma unroll
        for (int ci = 0; ci < 16; ++ci) a = fmaf(vi[ci], w[cls * 16 + ci], a);
        op[(size_t)cls * PL] = a;
    }
}

// ---------------- launch ----------------
extern "C" void kernel_launch(void* const* d_in, const int* in_sizes, int n_in,
                              void* d_out, int out_size, void* d_ws, size_t ws_size,
                              hipStream_t stream)
{
    const float* tokens = (const float*)d_in[0];
    const float* depth  = (const float*)d_in[1];
    const float* intr   = (const float*)d_in[2];
    const float* c2w    = (const float*)d_in[3];
    const float* l2w    = (const float*)d_in[4];
    const float* ln_g   = (const float*)d_in[5];
    const float* ln_b   = (const float*)d_in[6];
    const float* w1     = (const float*)d_in[7];
    const float* b1     = (const float*)d_in[8];
    const float* w2     = (const float*)d_in[9];
    const float* b2     = (const float*)d_in[10];
    const float* cv1w   = (const float*)d_in[11];
    const float* cv1b   = (const float*)d_in[12];
    const float* bn1g   = (const float*)d_in[13];
    const float* bn1b   = (const float*)d_in[14];
    const float* cv2w   = (const float*)d_in[15];
    const float* cv2b   = (const float*)d_in[16];
    const float* bn2g   = (const float*)d_in[17];
    const float* bn2b   = (const float*)d_in[18];
    const float* cv3w   = (const float*)d_in[19];
    const float* cv3b   = (const float*)d_in[20];

    if (ws_size < WS_FLOATS * sizeof(float)) return;

    float* ws   = (float*)d_ws;
    float* volf = ws + OFF_VOL;
    float* cntp = ws + OFF_CNT;
    float* st1  = ws + OFF_ST1;
    float* st2s = ws + OFF_ST2;
    float* mats = ws + OFF_MATS;
    __hip_bfloat16* wGm  = (__hip_bfloat16*)(ws + OFF_WGM);
    __hip_bfloat16* wA2  = (__hip_bfloat16*)(ws + OFF_WA2);
    float* c12  = ws + OFF_C12;
    __hip_bfloat16* wB1a = (__hip_bfloat16*)(ws + OFF_WB1A);
    __hip_bfloat16* wB1m = (__hip_bfloat16*)(ws + OFF_WB1M);
    __hip_bfloat16* wB2  = (__hip_bfloat16*)(ws + OFF_WB2);
    float* bnp1 = ws + OFF_BN1;
    float* bnp2 = ws + OFF_BN2;

    __hip_bfloat16* ob      = (__hip_bfloat16*)d_out;
    __hip_bfloat16* staged2 = ob + DO_ST2;      // padded conv1 out (raw, pre-BN)
    float* dmean            = (float*)(ob + DO_DM);
    __hip_bfloat16* staged3 = (__hip_bfloat16*)(ws + OFF_VOL);  // unpadded conv2 out
    float* outp = (float*)d_out;

    // zero cnt + BN-stat accumulators ourselves (runtime fill kernel is ~88 GB/s)
    occ_zero_kernel<<<(ZERO_N4 + 255) / 256, 256, 0, stream>>>((float4*)(ws + OFF_CNT));

    occ_prep_kernel<<<1, 256, 0, stream>>>(intr, c2w, l2w, w1, ln_g, ln_b, b1, w2,
                                           cv1w, cv2w, mats, wGm, wA2, c12,
                                           wB1a, wB1m, wB2);

    // depth means + fused scatter-zero of vol target rows
    occ_depth_kernel<<<NT / 4, 256, 0, stream>>>(depth, mats, dmean, volf);

    const int TGBLK = (NT / 16 + 4) / 4;   // 257 blocks (4 waves x 16 tokens each)
    occ_tokgemm_kernel<<<TGBLK, 256, 0, stream>>>(
        tokens, dmean, wGm, wA2, c12, b2, mats, volf, cntp);

    const int CGRID = NB * (GX / 4) * (GY / 8);   // 2500
    // conv1: fused normalize+mask staging; raw output (pre-BN) to padded staged2
    occ_conv_kernel<0><<<CGRID, 256, 0, stream>>>(volf, cntp, nullptr, nullptr,
                                                  wB1a, wB1m, cv1b, staged2, st1);
    occ_bnfin_kernel<<<1, 16, 0, stream>>>(st1, bn1g, bn1b, bnp1);
    // conv2: fused gelu(bn1(x)) staging with interior zero-pad; out to staged3
    occ_conv_kernel<1><<<CGRID, 256, 0, stream>>>(nullptr, nullptr, staged2, bnp1,
                                                  wB2, nullptr, cv2b, staged3, st2s);
    occ_bnfin_kernel<<<1, 16, 0, stream>>>(st2s, bn2g, bn2b, bnp2);

    occ_conv3_kernel<<<5000, 256, 0, stream>>>(staged3, bnp2, cv3w, cv3b, outp);
}

// Round 10
// 141.078 us; speedup vs baseline: 17.2434x; 1.0878x over previous
//
#include <hip/hip_runtime.h>
#include <hip/hip_bf16.h>
#include <math.h>

// ---------------- problem constants ----------------
#define PATCH 14
#define HID   16
#define NCLS  20
#define GX    200
#define GY    200
#define GZ    16
#define NB    2
#define NCAM  6
#define PH    37
#define PW    37
#define NP    (PH*PW)
#define NT    (NB*NCAM*NP)         // 16428 tokens
#define TD    768
#define IMH   518
#define IMW   518
#define PL    ((size_t)GX*GY*GZ)   // 640000 voxels per batch
#define EPSF  1e-5f

// padded conv layout: [b][px 0..201][py 0..201][pz 0..17] rows of 16 ch
#define PX 202
#define PY 202
#define PZ 18

// ---------------- workspace layout (float units) ----------------
#define OFF_VOL   ((size_t)0)            // volf [b][sp][16] fp32 (aliased as staged3 bf16)
#define OFF_CNT   ((size_t)20480000)
#define OFF_ST1   ((size_t)21760000)
#define OFF_ST2   ((size_t)21762048)
#define ZERO_F    ((size_t)21764096)     // zeroing covers OFF_CNT..ZERO_F (done in depth kernel)
#define OFF_MATS  ((size_t)21764096)     // 144
#define OFF_WGM   ((size_t)21764240)     // 24*64*8 bf16 = 6,144 f
#define OFF_WA2   ((size_t)21770384)     // 64*8 bf16 = 256 f
#define OFF_C12   ((size_t)21770640)     // 32
#define OFF_WB1A  ((size_t)21770672)     // 3,584
#define OFF_WB1M  ((size_t)21774256)     // 256
#define OFF_WB2   ((size_t)21774512)     // 3,584
#define OFF_BN1   ((size_t)21778096)     // 32
#define OFF_BN2   ((size_t)21778128)     // 32
#define WS_FLOATS ((size_t)21778160)

#define ZERO_N4   ((int)((ZERO_F - OFF_CNT) / 4))   // 321,024 float4s

// ---------------- d_out staging (bf16 units; dead before conv3 writes) ----------
#define DO_ST2  ((size_t)0)                       // padded conv1 out, 23,503,104
#define DO_DM   ((size_t)23503104)                // dmean fp32[NT] = 32,856 bf16
                                                  // end 23,535,960 <= 51,200,000

typedef __attribute__((ext_vector_type(8))) short short8;
typedef __attribute__((ext_vector_type(4))) float floatx4;

__device__ __forceinline__ float gelu_exact(float x) {
    return 0.5f * x * (1.0f + erff(x * 0.70710678118654752f));
}
__device__ __forceinline__ unsigned short f2bf(float f) {
    __hip_bfloat16 h = __float2bfloat16(f);
    return __builtin_bit_cast(unsigned short, h);
}
__device__ __forceinline__ float bf2f(short u) {
    unsigned int b = ((unsigned int)(unsigned short)u) << 16;
    return __builtin_bit_cast(float, b);
}
__device__ __forceinline__ short8 zero8() {
    short8 z = {0,0,0,0,0,0,0,0};
    return z;
}

// shared geometry: token -> voxel (must match EXACTLY between zero-pass and tokgemm)
__device__ __forceinline__ bool tok_voxel(int tk, float dmr, const float* __restrict__ mats,
                                          int& b, size_t& sp)
{
    int bc = tk / NP;
    int p  = tk - bc * NP;
    b = bc / NCAM;
    int gy = p / PW, gx = p - gy * PW;
    const float* M = mats + bc * 12;
    float dm = fmaxf(dmr, 0.f);
    float u = (gx + 0.5f) * (float)PATCH;
    float v = (gy + 0.5f) * (float)PATCH;
    float lx = (M[0] * u + M[1] * v + M[2]) * dm + M[9];
    float ly = (M[3] * u + M[4] * v + M[5]) * dm + M[10];
    float lz = (M[6] * u + M[7] * v + M[8]) * dm + M[11];
    int cx = (int)floorf((lx + 40.0f) / 0.4f);
    int cy = (int)floorf((ly + 40.0f) / 0.4f);
    int cz = (int)floorf((lz + 1.0f) / 0.4f);
    bool valid = (dmr > 0.001f) &&
                 (unsigned)cx < (unsigned)GX &&
                 (unsigned)cy < (unsigned)GY &&
                 (unsigned)cz < (unsigned)GZ;
    sp = ((size_t)cx * GY + cy) * GZ + cz;
    return valid;
}

// ---------------- 3x3 / 4x4 inverse in double ----------------
__device__ void inv3d(const double* m, double* o) {
    double a=m[0],b=m[1],c=m[2],d=m[3],e=m[4],f=m[5],g=m[6],h=m[7],i=m[8];
    double A=e*i-f*h, B=-(d*i-f*g), C=d*h-e*g;
    double det=a*A+b*B+c*C, id=1.0/det;
    o[0]=A*id;            o[1]=-(b*i-c*h)*id;   o[2]=(b*f-c*e)*id;
    o[3]=B*id;            o[4]=(a*i-c*g)*id;    o[5]=-(a*f-c*d)*id;
    o[6]=C*id;            o[7]=-(a*h-b*g)*id;   o[8]=(a*e-b*d)*id;
}

__device__ void inv4d(const double* m, double* o) {
    double i0  =  m[5]*m[10]*m[15]-m[5]*m[11]*m[14]-m[9]*m[6]*m[15]+m[9]*m[7]*m[14]+m[13]*m[6]*m[11]-m[13]*m[7]*m[10];
    double i4  = -m[4]*m[10]*m[15]+m[4]*m[11]*m[14]+m[8]*m[6]*m[15]-m[8]*m[7]*m[14]-m[12]*m[6]*m[11]+m[12]*m[7]*m[10];
    double i8  =  m[4]*m[9]*m[15]-m[4]*m[11]*m[13]-m[8]*m[5]*m[15]+m[8]*m[7]*m[13]+m[12]*m[5]*m[11]-m[12]*m[7]*m[9];
    double i12 = -m[4]*m[9]*m[14]+m[4]*m[10]*m[13]+m[8]*m[5]*m[14]-m[8]*m[6]*m[13]-m[12]*m[5]*m[10]+m[12]*m[6]*m[9];
    double i1  = -m[1]*m[10]*m[15]+m[1]*m[11]*m[14]+m[9]*m[2]*m[15]-m[9]*m[3]*m[14]-m[13]*m[2]*m[11]+m[13]*m[3]*m[10];
    double i5  =  m[0]*m[10]*m[15]-m[0]*m[11]*m[14]-m[8]*m[2]*m[15]+m[8]*m[3]*m[14]+m[12]*m[2]*m[11]-m[12]*m[3]*m[10];
    double i9  = -m[0]*m[9]*m[15]+m[0]*m[11]*m[13]+m[8]*m[1]*m[15]-m[8]*m[3]*m[13]-m[12]*m[1]*m[11]+m[12]*m[3]*m[9];
    double i13 =  m[0]*m[9]*m[14]-m[0]*m[10]*m[13]-m[8]*m[1]*m[14]+m[8]*m[2]*m[13]+m[12]*m[1]*m[10]-m[12]*m[2]*m[9];
    double i2  =  m[1]*m[6]*m[15]-m[1]*m[7]*m[14]-m[5]*m[2]*m[15]+m[5]*m[3]*m[14]+m[13]*m[2]*m[7]-m[13]*m[3]*m[6];
    double i6  = -m[0]*m[6]*m[15]+m[0]*m[7]*m[14]+m[4]*m[2]*m[15]-m[4]*m[3]*m[14]-m[12]*m[2]*m[7]+m[12]*m[3]*m[6];
    double i10 =  m[0]*m[5]*m[15]-m[0]*m[7]*m[13]-m[4]*m[1]*m[15]+m[4]*m[3]*m[13]+m[12]*m[1]*m[7]-m[12]*m[3]*m[5];
    double i14 = -m[0]*m[5]*m[14]+m[0]*m[6]*m[13]+m[4]*m[1]*m[14]-m[4]*m[2]*m[13]-m[12]*m[1]*m[6]+m[12]*m[2]*m[5];
    double i3  = -m[1]*m[6]*m[11]+m[1]*m[7]*m[10]+m[5]*m[2]*m[11]-m[5]*m[3]*m[10]-m[9]*m[2]*m[7]+m[9]*m[3]*m[6];
    double i7  =  m[0]*m[6]*m[11]-m[0]*m[7]*m[10]-m[4]*m[2]*m[11]+m[4]*m[3]*m[10]+m[8]*m[2]*m[7]-m[8]*m[3]*m[6];
    double i11 = -m[0]*m[5]*m[11]+m[0]*m[7]*m[9]+m[4]*m[1]*m[11]-m[4]*m[3]*m[9]-m[8]*m[1]*m[7]+m[8]*m[3]*m[5];
    double i15 =  m[0]*m[5]*m[10]-m[0]*m[6]*m[9]-m[4]*m[1]*m[10]+m[4]*m[2]*m[9]+m[8]*m[1]*m[6]-m[8]*m[2]*m[5];
    double det = m[0]*i0+m[1]*i4+m[2]*i8+m[3]*i12;
    double id = 1.0/det;
    o[0]=i0*id; o[1]=i1*id; o[2]=i2*id; o[3]=i3*id;
    o[4]=i4*id; o[5]=i5*id; o[6]=i6*id; o[7]=i7*id;
    o[8]=i8*id; o[9]=i9*id; o[10]=i10*id; o[11]=i11*id;
    o[12]=i12*id; o[13]=i13*id; o[14]=i14*id; o[15]=i15*id;
}

#define PREP_BLOCKS 16
#define PREP_STRIDE (PREP_BLOCKS * 256)

// ---------------- precompute (multi-block; mats+c12 on block 0) ----------------
__global__ void occ_prep_kernel(const float* __restrict__ intr, const float* __restrict__ c2w,
                                const float* __restrict__ l2w, const float* __restrict__ w1,
                                const float* __restrict__ ln_g, const float* __restrict__ ln_b,
                                const float* __restrict__ b1, const float* __restrict__ w2,
                                const float* __restrict__ cw1, const float* __restrict__ cw2,
                                float* __restrict__ mats, __hip_bfloat16* __restrict__ wGm,
                                __hip_bfloat16* __restrict__ wA2, float* __restrict__ c12,
                                __hip_bfloat16* __restrict__ wB1a, __hip_bfloat16* __restrict__ wB1m,
                                __hip_bfloat16* __restrict__ wB2)
{
    int t = threadIdx.x;
    int bid = blockIdx.x;
    int gt = bid * 256 + t;

    if (bid == 0) {
        __shared__ float sc1[256], sc2[256];
        // parallel c12 partials: thread (j = t&15, chunk = t>>4) covers 48 d's
        {
            int j = t & 15, ck = t >> 4;
            float c1 = 0.f, c2p = 0.f;
            #pragma unroll 4
            for (int dd = 0; dd < TD / 16; ++dd) {
                int d = ck * (TD / 16) + dd;
                c1  += bf2f((short)f2bf(ln_g[d] * w1[d * 16 + j]));
                c2p += ln_b[d] * w1[d * 16 + j];
            }
            sc1[t] = c1; sc2[t] = c2p;
        }
        __syncthreads();
        if (t < 16) {
            float a1 = 0.f, a2 = 0.f;
            #pragma unroll
            for (int k = 0; k < 16; ++k) { a1 += sc1[k * 16 + t]; a2 += sc2[k * 16 + t]; }
            c12[t] = a1;
            c12[16 + t] = a2 + b1[t];
        }
        if (t < NB * NCAM) {
            int b = t / NCAM;
            double K[9], Ki[9], L[16], Li[16], C[16], M[16], A[9];
            #pragma unroll
            for (int i = 0; i < 9; ++i) K[i] = (double)intr[t * 9 + i];
            inv3d(K, Ki);
            #pragma unroll
            for (int i = 0; i < 16; ++i) L[i] = (double)l2w[b * 16 + i];
            inv4d(L, Li);
            #pragma unroll
            for (int i = 0; i < 16; ++i) C[i] = (double)c2w[t * 16 + i];
            #pragma unroll
            for (int r = 0; r < 4; ++r)
                #pragma unroll
                for (int c = 0; c < 4; ++c) {
                    double s = 0.0;
                    #pragma unroll
                    for (int k = 0; k < 4; ++k) s += Li[r * 4 + k] * C[k * 4 + c];
                    M[r * 4 + c] = s;
                }
            #pragma unroll
            for (int r = 0; r < 3; ++r)
                #pragma unroll
                for (int c = 0; c < 3; ++c) {
                    double s = 0.0;
                    #pragma unroll
                    for (int k = 0; k < 3; ++k) s += M[r * 4 + k] * Ki[k * 3 + c];
                    A[r * 3 + c] = s;
                }
            #pragma unroll
            for (int i = 0; i < 9; ++i) mats[t * 12 + i] = (float)A[i];
            mats[t * 12 + 9]  = (float)M[3];
            mats[t * 12 + 10] = (float)M[7];
            mats[t * 12 + 11] = (float)M[11];
        }
    }

    // token GEMM1 B-fragments: wGm[step][lane][8], k = d = step*32 + 8*kg + e, col j = lane&15
    for (int i = gt; i < 24 * 64 * 8; i += PREP_STRIDE) {
        int st = i >> 9; int ln = (i >> 3) & 63; int e = i & 7;
        int kg = ln >> 4, j = ln & 15;
        int d = st * 32 + kg * 8 + e;
        wGm[i] = __float2bfloat16(ln_g[d] * w1[d * 16 + j]);
    }
    // token GEMM2 A-fragment: w2^T, m = ch = lane&15, k = hid = 8*kg+e (valid k<16)
    for (int i = gt; i < 64 * 8; i += PREP_STRIDE) {
        int ln = i >> 3; int e = i & 7;
        int kg = ln >> 4, ch = ln & 15;
        int k = kg * 8 + e;
        wA2[i] = __float2bfloat16((k < 16) ? w2[k * 16 + ch] : 0.f);
    }
    // conv1 main: wB1a[t2][lane][8]; K packs 2 taps x 16 ch
    for (int i = gt; i < 14 * 64 * 8; i += PREP_STRIDE) {
        int t2 = i >> 9; int r = i & 511; int ln = r >> 3; int e = r & 7;
        int kg = ln >> 4;
        int tt = 2 * t2 + (kg >> 1);
        int ci = ((kg & 1) << 3) + e;
        int o = ln & 15;
        float val = (tt < 27) ? cw1[(o * 17 + ci) * 27 + tt] : 0.f;
        wB1a[i] = __float2bfloat16(val);
    }
    // conv1 mask channel (ci=16): wB1m[lane][8]; K slot = tap index
    for (int i = gt; i < 64 * 8; i += PREP_STRIDE) {
        int ln = i >> 3; int e = i & 7;
        int k = ((ln >> 4) << 3) + e;
        int o = ln & 15;
        float val = (k < 27) ? cw1[(o * 17 + 16) * 27 + k] : 0.f;
        wB1m[i] = __float2bfloat16(val);
    }
    // conv2: wB2[t2][lane][8]
    for (int i = gt; i < 14 * 64 * 8; i += PREP_STRIDE) {
        int t2 = i >> 9; int r = i & 511; int ln = r >> 3; int e = r & 7;
        int kg = ln >> 4;
        int tt = 2 * t2 + (kg >> 1);
        int ci = ((kg & 1) << 3) + e;
        int o = ln & 15;
        float val = (tt < 27) ? cw2[(o * 16 + ci) * 27 + tt] : 0.f;
        wB2[i] = __float2bfloat16(val);
    }
}

// ------- depth patch means + scatter-zero of vol rows + cnt/stats zeroing -------
__global__ __launch_bounds__(256) void occ_depth_kernel(const float* __restrict__ depth,
                                                        const float* __restrict__ mats,
                                                        float* __restrict__ dmean,
                                                        float* __restrict__ vol,
                                                        float4* __restrict__ zbase)
{
    int tid = threadIdx.x;
    // fused zeroing of cnt + BN-stat accumulators (1M threads cover 321k float4s)
    int gid = blockIdx.x * 256 + tid;
    if (gid < ZERO_N4) {
        float4 z = {0.f, 0.f, 0.f, 0.f};
        zbase[gid] = z;
    }

    int l = tid & 63;
    int g = blockIdx.x * 4 + (tid >> 6);     // 4107 blocks * 4 = 16428 exactly
    int bc = g / NP;
    int p  = g - bc * NP;
    int gy = p / PW, gx = p - gy * PW;
    const float* dbase = depth + (size_t)bc * (IMH * IMW);
    int rbase = gy * PATCH, cb = gx * PATCH;
    float dsum = 0.f;
    #pragma unroll
    for (int i = 0; i < 3; ++i) {
        int idx = l + 64 * i;
        int py = idx / 14;
        int px = idx - py * 14;
        dsum += dbase[(size_t)(rbase + py) * IMW + (cb + px)];
    }
    if (l < 4)
        dsum += dbase[(size_t)(rbase + 13) * IMW + (cb + 10 + l)];
    #pragma unroll
    for (int m = 1; m <= 32; m <<= 1) dsum += __shfl_xor(dsum, m);
    float dmr = dsum * (1.0f / 196.0f);
    if (l == 0) dmean[g] = dmr;
    // lanes 0-3: zero the 16-float vol row this token will scatter into
    if (l < 4) {
        int b; size_t sp;
        if (tok_voxel(g, dmr, mats, b, sp)) {
            float4 z = {0.f, 0.f, 0.f, 0.f};
            *(float4*)(vol + ((size_t)b * PL + sp) * 16 + l * 4) = z;
        }
    }
}

// ------- token GEMM: LN folded into epilogue; 16 tokens per wave; 8 waves/block -------
__global__ __launch_bounds__(512) void occ_tokgemm_kernel(
    const float* __restrict__ tokens, const float* __restrict__ dmean,
    const __hip_bfloat16* __restrict__ wGm, const __hip_bfloat16* __restrict__ wA2,
    const float* __restrict__ c12, const float* __restrict__ b2,
    const float* __restrict__ mats, float* __restrict__ vol, float* __restrict__ cnt)
{
    int tid = threadIdx.x;
    int w = tid >> 6, lane = tid & 63;
    int tile = (blockIdx.x * 8 + w) * 16;
    int j16 = lane & 15, kg = lane >> 4;

    __shared__ __hip_bfloat16 sH[8][16][16];

    int tka  = tile + j16;
    int tkac = min(tka, NT - 1);

    const float* tokp = tokens + (size_t)tkac * TD + (kg << 3);
    const short8* wg8 = (const short8*)wGm;

    floatx4 acc = {0.f, 0.f, 0.f, 0.f};
    float s = 0.f, sq = 0.f;
    #pragma unroll
    for (int st = 0; st < 24; ++st) {
        float4 xa = *(const float4*)(tokp + st * 32);
        float4 xb = *(const float4*)(tokp + st * 32 + 4);
        s += xa.x + xa.y + xa.z + xa.w + xb.x + xb.y + xb.z + xb.w;
        sq = fmaf(xa.x, xa.x, sq); sq = fmaf(xa.y, xa.y, sq);
        sq = fmaf(xa.z, xa.z, sq); sq = fmaf(xa.w, xa.w, sq);
        sq = fmaf(xb.x, xb.x, sq); sq = fmaf(xb.y, xb.y, sq);
        sq = fmaf(xb.z, xb.z, sq); sq = fmaf(xb.w, xb.w, sq);
        short8 a;
        a[0] = (short)f2bf(xa.x); a[1] = (short)f2bf(xa.y);
        a[2] = (short)f2bf(xa.z); a[3] = (short)f2bf(xa.w);
        a[4] = (short)f2bf(xb.x); a[5] = (short)f2bf(xb.y);
        a[6] = (short)f2bf(xb.z); a[7] = (short)f2bf(xb.w);
        acc = __builtin_amdgcn_mfma_f32_16x16x32_bf16(a, wg8[st * 64 + lane], acc, 0, 0, 0);
    }
    // stats for token j16 (dims split across kg groups)
    s  += __shfl_xor(s, 16);  s  += __shfl_xor(s, 32);
    sq += __shfl_xor(sq, 16); sq += __shfl_xor(sq, 32);
    float mu = s * (1.0f / (float)TD);
    float rs = rsqrtf(sq * (1.0f / (float)TD) - mu * mu + EPSF);

    // epilogue: h_j = rs*(acc - mu*c1_j) + c2'_j ; gelu ; stash h1 in LDS
    float c1  = c12[j16];
    float c2p = c12[16 + j16];
    #pragma unroll
    for (int r = 0; r < 4; ++r) {
        int srcl = kg * 4 + r;                 // row token within the 16-group
        float mur = __shfl(mu, srcl, 16);
        float rsr = __shfl(rs, srcl, 16);
        float h = rsr * (acc[r] - mur * c1) + c2p;
        sH[w][srcl][j16] = __float2bfloat16(gelu_exact(h));
    }
    __syncthreads();

    // GEMM2: D2[ch][token] = w2^T @ h1^T + b2
    short8 hb = zero8();
    if (kg < 2) hb = *(const short8*)&sH[w][j16][kg * 8];
    floatx4 acc2;
    acc2[0] = b2[kg * 4 + 0]; acc2[1] = b2[kg * 4 + 1];
    acc2[2] = b2[kg * 4 + 2]; acc2[3] = b2[kg * 4 + 3];
    short8 a2 = ((const short8*)wA2)[lane];
    acc2 = __builtin_amdgcn_mfma_f32_16x16x32_bf16(a2, hb, acc2, 0, 0, 0);

    // geometry + scatter: lane owns token tile+j16, channels kg*4 .. kg*4+3
    int b; size_t sp;
    bool valid = tok_voxel(tkac, dmean[tkac], mats, b, sp) && (tka < NT);
    if (valid) {
        float* base = vol + ((size_t)b * PL + sp) * 16 + kg * 4;
        atomicAdd(base + 0, acc2[0]);
        atomicAdd(base + 1, acc2[1]);
        atomicAdd(base + 2, acc2[2]);
        atomicAdd(base + 3, acc2[3]);
        if (kg == 0) atomicAdd(cnt + (size_t)b * PL + sp, 1.0f);
    }
}

// ------- conv3d 3x3x3 via MFMA, LDS-staged 4x8 tile -------
// MODE 0 (conv1): stage = normalize vol/cnt on the fly (+mask), OUTPAD store
// MODE 1 (conv2): stage = gelu(bn1(x)) on the fly with interior zero-pad, flat store
template <int MODE>
__global__ __launch_bounds__(256, 4) void occ_conv_kernel(
    const float* __restrict__ volf, const float* __restrict__ cnt,
    const __hip_bfloat16* __restrict__ inbf, const float* __restrict__ bnp,
    const __hip_bfloat16* __restrict__ wBa, const __hip_bfloat16* __restrict__ wBm,
    const float* __restrict__ bias, __hip_bfloat16* __restrict__ out,
    float* __restrict__ stats)
{
    // 2500 blocks = NB * (GX/4) * (GY/8); bijective XCD swizzle (2500 = 4*313 + 4*312)
    int bid = blockIdx.x;
    int xcd = bid & 7, off = bid >> 3;
    int blk = (xcd < 4 ? xcd * 313 : 4 * 313 + (xcd - 4) * 312) + off;
    int b   = blk / 1250;
    int rem = blk % 1250;
    int x0  = (rem / 25) * 4;
    int y0  = (rem % 25) * 8;
    int tid = threadIdx.x;

    __shared__ __hip_bfloat16 sA[1080 * 16];    // 6x10x18 rows of 16ch = 34,560 B
    __shared__ unsigned short sM[1080];
    __shared__ float sred[4][32];
    __shared__ float sbn[32];

    if constexpr (MODE == 1) {
        if (tid < 32) sbn[tid] = bnp[tid];
        __syncthreads();
    }

    // cooperative stage with fused normalize (MODE 0) or fused bn+gelu (MODE 1)
    {
        short8* sa8 = (short8*)sA;
        const short8* gin = (const short8*)inbf;
        for (int ii = tid; ii < 1080; ii += 256) {
            int dx = ii / 180;
            int r2 = ii - dx * 180;
            int dy = r2 / 18, dz = r2 - dy * 18;
            int px = x0 + dx, py = y0 + dy, pz = dz;
            bool interior = ((unsigned)(px - 1) < (unsigned)GX) &&
                            ((unsigned)(py - 1) < (unsigned)GY) &&
                            ((unsigned)(pz - 1) < (unsigned)GZ);
            short8 o0 = zero8(), o1 = zero8();
            if constexpr (MODE == 0) {
                unsigned short m = 0;
                if (interior) {
                    size_t vi = (size_t)b * PL +
                                (((size_t)(px - 1) * GY + (py - 1)) * GZ + (pz - 1));
                    float cn = cnt[vi];
                    if (cn > 0.f) {
                        float inv = 1.0f / cn;
                        const float4* vp = (const float4*)(volf + vi * 16);
                        float4 f0 = vp[0], f1 = vp[1], f2 = vp[2], f3 = vp[3];
                        o0[0] = (short)f2bf(f0.x * inv); o0[1] = (short)f2bf(f0.y * inv);
                        o0[2] = (short)f2bf(f0.z * inv); o0[3] = (short)f2bf(f0.w * inv);
                        o0[4] = (short)f2bf(f1.x * inv); o0[5] = (short)f2bf(f1.y * inv);
                        o0[6] = (short)f2bf(f1.z * inv); o0[7] = (short)f2bf(f1.w * inv);
                        o1[0] = (short)f2bf(f2.x * inv); o1[1] = (short)f2bf(f2.y * inv);
                        o1[2] = (short)f2bf(f2.z * inv); o1[3] = (short)f2bf(f2.w * inv);
                        o1[4] = (short)f2bf(f3.x * inv); o1[5] = (short)f2bf(f3.y * inv);
                        o1[6] = (short)f2bf(f3.z * inv); o1[7] = (short)f2bf(f3.w * inv);
                        m = f2bf(1.0f);
                    }
                }
                sM[ii] = m;
            } else {
                if (interior) {
                    size_t grow = ((size_t)((b * PX + px) * PY + py) * PZ) + pz;
                    short8 v0 = gin[grow * 2], v1 = gin[grow * 2 + 1];
                    #pragma unroll
                    for (int e = 0; e < 8; ++e) {
                        o0[e] = (short)f2bf(gelu_exact(fmaf(bf2f(v0[e]), sbn[e],     sbn[16 + e])));
                        o1[e] = (short)f2bf(gelu_exact(fmaf(bf2f(v1[e]), sbn[8 + e], sbn[24 + e])));
                    }
                }
            }
            sa8[ii * 2] = o0; sa8[ii * 2 + 1] = o1;
        }
    }
    __syncthreads();

    int w = tid >> 6, lane = tid & 63;
    int z = lane & 15, kg = lane >> 4;
    int ci0 = (kg & 1) << 3;
    bool halfsel = kg >= 2;

    // preload weight fragments (loop-invariant)
    const short8* wp = (const short8*)wBa;
    short8 wreg[14];
    #pragma unroll
    for (int t2 = 0; t2 < 14; ++t2) wreg[t2] = wp[t2 * 64 + lane];

    float bo = bias[lane & 15];
    floatx4 acc[8];
    #pragma unroll
    for (int j = 0; j < 8; ++j) { acc[j][0]=bo; acc[j][1]=bo; acc[j][2]=bo; acc[j][3]=bo; }

    #pragma unroll
    for (int t2 = 0; t2 < 14; ++t2) {
        const int ta = 2 * t2;
        const int tb = (2 * t2 + 1 > 26) ? 26 : 2 * t2 + 1;
        const int kda = ta / 9, kha = (ta / 3) % 3, kwa = ta % 3;
        const int kdb = tb / 9, khb = (tb / 3) % 3, kwb = tb % 3;
        int rowA = (w + kda) * 180 + kha * 18 + (z + kwa);
        int rowB = (w + kdb) * 180 + khb * 18 + (z + kwb);
        int row = halfsel ? rowB : rowA;
        const __hip_bfloat16* ap = sA + row * 16 + ci0;
        #pragma unroll
        for (int j = 0; j < 8; ++j) {
            short8 a = *(const short8*)(ap + j * (18 * 16));   // +576B per y-col
            acc[j] = __builtin_amdgcn_mfma_f32_16x16x32_bf16(a, wreg[t2], acc[j], 0, 0, 0);
        }
    }

    if constexpr (MODE == 0) {
        int base8[8];
        #pragma unroll
        for (int e = 0; e < 8; ++e) {
            int tap = kg * 8 + e;
            int kd = tap / 9;
            int rm = tap - kd * 9;
            int kh = rm / 3;
            int kw = rm - kh * 3;
            int idx = (w + kd) * 180 + kh * 18 + z + kw;
            base8[e] = (tap < 27) ? idx : 0;    // weight is 0 for tap>=27
        }
        short8 wm = ((const short8*)wBm)[lane];
        #pragma unroll
        for (int j = 0; j < 8; ++j) {
            short8 am;
            #pragma unroll
            for (int e = 0; e < 8; ++e) am[e] = (short)sM[base8[e] + j * 18];
            acc[j] = __builtin_amdgcn_mfma_f32_16x16x32_bf16(am, wm, acc[j], 0, 0, 0);
        }
    }

    // store; D: row z' = kg*4+r, col o = lane&15
    int o = lane & 15;
    int wx = x0 + w;
    #pragma unroll
    for (int j = 0; j < 8; ++j) {
        int wy = y0 + j;
        size_t rowbase;
        if constexpr (MODE == 0)
            rowbase = (size_t)(((b * PX + wx + 1) * PY) + (wy + 1)) * PZ + 1;
        else
            rowbase = (size_t)b * PL + ((size_t)wx * GY + wy) * GZ;
        #pragma unroll
        for (int r = 0; r < 4; ++r)
            out[(rowbase + kg * 4 + r) * 16 + o] = __float2bfloat16(acc[j][r]);
    }

    // fused BN stats (per-channel sum / sumsq)
    float s = 0.f, sq = 0.f;
    #pragma unroll
    for (int j = 0; j < 8; ++j)
        #pragma unroll
        for (int r = 0; r < 4; ++r) { float v = acc[j][r]; s += v; sq += v * v; }
    s  += __shfl_xor(s, 16);  s  += __shfl_xor(s, 32);
    sq += __shfl_xor(sq, 16); sq += __shfl_xor(sq, 32);
    if (lane < 16) { sred[w][lane] = s; sred[w][16 + lane] = sq; }
    __syncthreads();
    if (tid < 32) {
        float v2 = sred[0][tid] + sred[1][tid] + sred[2][tid] + sred[3][tid];
        atomicAdd(&stats[(size_t)(blockIdx.x & 63) * 32 + tid], v2);
    }
}

// ---------------- BN finalize (256 threads, bucketed parallel reduce) ----------------
__global__ __launch_bounds__(256) void occ_bnfin_kernel(const float* __restrict__ stats,
                                                        const float* __restrict__ g,
                                                        const float* __restrict__ bb,
                                                        float* __restrict__ bn)
{
    __shared__ float red[8][32];
    int t = threadIdx.x;
    int c = t & 31, k = t >> 5;           // 8 bucket-groups x 32 stat-slots
    float s = 0.f;
    #pragma unroll
    for (int i = 0; i < 8; ++i) s += stats[(size_t)(k * 8 + i) * 32 + c];
    red[k][c] = s;
    __syncthreads();
    if (t < 32) {
        float a = 0.f;
        #pragma unroll
        for (int i = 0; i < 8; ++i) a += red[i][t];
        red[0][t] = a;
    }
    __syncthreads();
    if (t < 16) {
        const float N = (float)(NB * PL);
        float mean = red[0][t] / N;
        float var = red[0][16 + t] / N - mean * mean;
        float scale = g[t] * rsqrtf(var + EPSF);
        bn[t] = scale;
        bn[16 + t] = bb[t] - mean * scale;
    }
}

// ---------------- conv3 1x1x1 (16 -> 20) with fused bn2+GELU ----------------
__global__ __launch_bounds__(256) void occ_conv3_kernel(const __hip_bfloat16* __restrict__ act,
                                                        const float* __restrict__ bn,
                                                        const float* __restrict__ w3,
                                                        const float* __restrict__ b3,
                                                        float* __restrict__ out)
{
    __shared__ float w[NCLS * 16];
    __shared__ float bb[NCLS];
    __shared__ float sc[16], sh[16];
    int t = threadIdx.x;
    for (int i = t; i < NCLS * 16; i += 256) w[i] = w3[i];
    if (t < NCLS) bb[t] = b3[t];
    if (t >= 32 && t < 48) sc[t - 32] = bn[t - 32];
    if (t >= 48 && t < 64) sh[t - 48] = bn[t - 32];
    __syncthreads();
    size_t i = (size_t)blockIdx.x * 256 + t;      // < NB*PL
    size_t b = i / PL, sp = i % PL;
    const short8* p = (const short8*)(act + i * 16);
    short8 v0 = p[0], v1 = p[1];
    float vi[16];
    #pragma unroll
    for (int e = 0; e < 8; ++e) {
        vi[e]     = gelu_exact(fmaf(bf2f(v0[e]), sc[e],     sh[e]));
        vi[8 + e] = gelu_exact(fmaf(bf2f(v1[e]), sc[8 + e], sh[8 + e]));
    }
    float* op = out + b * NCLS * PL + sp;
    #pragma unroll
    for (int cls = 0; cls < NCLS; ++cls) {
        float a = bb[cls];
        #pragma unroll
        for (int ci = 0; ci < 16; ++ci) a = fmaf(vi[ci], w[cls * 16 + ci], a);
        op[(size_t)cls * PL] = a;
    }
}

// ---------------- launch ----------------
extern "C" void kernel_launch(void* const* d_in, const int* in_sizes, int n_in,
                              void* d_out, int out_size, void* d_ws, size_t ws_size,
                              hipStream_t stream)
{
    const float* tokens = (const float*)d_in[0];
    const float* depth  = (const float*)d_in[1];
    const float* intr   = (const float*)d_in[2];
    const float* c2w    = (const float*)d_in[3];
    const float* l2w    = (const float*)d_in[4];
    const float* ln_g   = (const float*)d_in[5];
    const float* ln_b   = (const float*)d_in[6];
    const float* w1     = (const float*)d_in[7];
    const float* b1     = (const float*)d_in[8];
    const float* w2     = (const float*)d_in[9];
    const float* b2     = (const float*)d_in[10];
    const float* cv1w   = (const float*)d_in[11];
    const float* cv1b   = (const float*)d_in[12];
    const float* bn1g   = (const float*)d_in[13];
    const float* bn1b   = (const float*)d_in[14];
    const float* cv2w   = (const float*)d_in[15];
    const float* cv2b   = (const float*)d_in[16];
    const float* bn2g   = (const float*)d_in[17];
    const float* bn2b   = (const float*)d_in[18];
    const float* cv3w   = (const float*)d_in[19];
    const float* cv3b   = (const float*)d_in[20];

    if (ws_size < WS_FLOATS * sizeof(float)) return;

    float* ws   = (float*)d_ws;
    float* volf = ws + OFF_VOL;
    float* cntp = ws + OFF_CNT;
    float* st1  = ws + OFF_ST1;
    float* st2s = ws + OFF_ST2;
    float* mats = ws + OFF_MATS;
    __hip_bfloat16* wGm  = (__hip_bfloat16*)(ws + OFF_WGM);
    __hip_bfloat16* wA2  = (__hip_bfloat16*)(ws + OFF_WA2);
    float* c12  = ws + OFF_C12;
    __hip_bfloat16* wB1a = (__hip_bfloat16*)(ws + OFF_WB1A);
    __hip_bfloat16* wB1m = (__hip_bfloat16*)(ws + OFF_WB1M);
    __hip_bfloat16* wB2  = (__hip_bfloat16*)(ws + OFF_WB2);
    float* bnp1 = ws + OFF_BN1;
    float* bnp2 = ws + OFF_BN2;

    __hip_bfloat16* ob      = (__hip_bfloat16*)d_out;
    __hip_bfloat16* staged2 = ob + DO_ST2;      // padded conv1 out (raw, pre-BN)
    float* dmean            = (float*)(ob + DO_DM);
    __hip_bfloat16* staged3 = (__hip_bfloat16*)(ws + OFF_VOL);  // unpadded conv2 out
    float* outp = (float*)d_out;

    occ_prep_kernel<<<PREP_BLOCKS, 256, 0, stream>>>(intr, c2w, l2w, w1, ln_g, ln_b, b1, w2,
                                                     cv1w, cv2w, mats, wGm, wA2, c12,
                                                     wB1a, wB1m, wB2);

    // depth means + fused scatter-zero of vol target rows + cnt/stats zeroing
    occ_depth_kernel<<<NT / 4, 256, 0, stream>>>(depth, mats, dmean, volf,
                                                 (float4*)(ws + OFF_CNT));

    const int TGBLK = (NT / 16 + 1 + 7) / 8;   // 129 blocks x 8 waves x 16 tokens
    occ_tokgemm_kernel<<<TGBLK, 512, 0, stream>>>(
        tokens, dmean, wGm, wA2, c12, b2, mats, volf, cntp);

    const int CGRID = NB * (GX / 4) * (GY / 8);   // 2500
    // conv1: fused normalize+mask staging; raw output (pre-BN) to padded staged2
    occ_conv_kernel<0><<<CGRID, 256, 0, stream>>>(volf, cntp, nullptr, nullptr,
                                                  wB1a, wB1m, cv1b, staged2, st1);
    occ_bnfin_kernel<<<1, 256, 0, stream>>>(st1, bn1g, bn1b, bnp1);
    // conv2: fused gelu(bn1(x)) staging with interior zero-pad; out to staged3
    occ_conv_kernel<1><<<CGRID, 256, 0, stream>>>(nullptr, nullptr, staged2, bnp1,
                                                  wB2, nullptr, cv2b, staged3, st2s);
    occ_bnfin_kernel<<<1, 256, 0, stream>>>(st2s, bn2g, bn2b, bnp2);

    occ_conv3_kernel<<<5000, 256, 0, stream>>>(staged3, bnp2, cv3w, cv3b, outp);
}